// Round 3
// baseline (2257.183 us; speedup 1.0000x reference)
//
#include <hip/hip_runtime.h>

// Problem constants
#define NB    16
#define NT    3
#define NCTX  2048
#define NLAT  512
#define DIMV  512
#define HALFD 256
#define NFEAT 51
#define NBT   48
#define MROWS 24576    // NBT*NLAT
#define GRP   6        // bt per context group
#define NGRP  8
#define GROWS 12288    // GRP*NCTX

typedef unsigned short bfu;   // bf16 storage as raw bits
typedef short bf16x8 __attribute__((ext_vector_type(8)));   // 8 bf16 = 4 VGPR
typedef float f32x4  __attribute__((ext_vector_type(4)));   // MFMA 16x16 acc
typedef float f32x2  __attribute__((ext_vector_type(2)));   // packed fp32 pair

__device__ __forceinline__ float bf2f(bfu u){ return __uint_as_float(((unsigned int)u) << 16); }
__device__ __forceinline__ bfu f2bf(float f){
  unsigned int u = __float_as_uint(f);
  u += 0x7FFFu + ((u >> 16) & 1u);          // RNE
  return (bfu)(u >> 16);
}
__device__ __forceinline__ float loadE(const float* p){ return *p; }
__device__ __forceinline__ float loadE(const bfu* p){ return bf2f(*p); }
__device__ __forceinline__ void storeE(float* p, float v){ *p = v; }
__device__ __forceinline__ void storeE(bfu* p, float v){ *p = f2bf(v); }
__device__ __forceinline__ bfu to_bfu(float f){ return f2bf(f); }
__device__ __forceinline__ bfu to_bfu(bfu u){ return u; }

// ---------------------------------------------------------------------------
// FPS: ONE wave per batch, all 2048 points register-resident (32/lane as 16
// f32x2). Per step: uniform LDS broadcast of last point's coords -> packed
// dist update -> adjacent-pair in-lane argmax tree (index-ordered merges, so
// strict > preserves numpy first-max tie-break) -> proven 6-stage DPP wave
// argmax -> v_readlane broadcast. No barriers, no cross-wave merge in the
// serial loop. Arithmetic (contract off, op order, fminf, 1e10f) identical
// to the previous bit-exact version.
// amdgpu_waves_per_eu(1,1): hard occupancy bound of 1 wave/EU -> full
// 512-VGPR budget. R1/R2 counters proved the default heuristic caps the
// kernel at 88 VGPRs (needs >=160) and spills the point arrays to scratch;
// __launch_bounds__'s 2nd arg could not lift it (min-waves default is
// already 1).
// ---------------------------------------------------------------------------
#define DPP_ARGMAX_STAGE(CTRL)                                                \
  {                                                                           \
    const int svb = __builtin_amdgcn_update_dpp(vb, vb, CTRL, 0xF, 0xF, false); \
    const int sib = __builtin_amdgcn_update_dpp(ib, ib, CTRL, 0xF, 0xF, false); \
    const float sv = __int_as_float(svb);                                     \
    const float cv = __int_as_float(vb);                                      \
    if (sv > cv || (sv == cv && sib < ib)){ vb = svb; ib = sib; }             \
  }

__global__ __attribute__((amdgpu_waves_per_eu(1, 1)))
__launch_bounds__(64) void fps_kernel(const float* __restrict__ pc,
                                      int* __restrict__ idx_out){
#pragma clang fp contract(off)
  __shared__ float4 pts[NCTX];            // broadcast copy for "last" coords
  const int lane = threadIdx.x;           // 0..63, single wave
  const int b = blockIdx.x;
  const float* src = pc + (size_t)b * (NT * NCTX * 3);

  // Register-resident points: slot s (0..31) = global point p = (s<<6)|lane.
  // Packed as f32x2 pairs: pair j holds slots 2j (lo) and 2j+1 (hi).
  f32x2 x2[16], y2[16], z2[16], d2[16];
  #pragma unroll
  for (int j = 0; j < 16; ++j){
    #pragma unroll
    for (int h = 0; h < 2; ++h){
      const int p = ((2 * j + h) << 6) + lane;
      const float xx = src[p * 3 + 0];
      const float yy = src[p * 3 + 1];
      const float zz = src[p * 3 + 2];
      x2[j][h] = xx; y2[j][h] = yy; z2[j][h] = zz; d2[j][h] = 1e10f;
      pts[p] = make_float4(xx, yy, zz, 0.f);
    }
  }
  if (lane == 0) idx_out[b * NLAT] = 0;
  __syncthreads();                        // drain LDS writes (single wave)

  int last = 0;
  for (int step = 1; step < NLAT; ++step){
    const float4 lp = pts[last];          // uniform addr -> LDS broadcast

    // distance update (identical op order to previous bit-exact version)
    #pragma unroll
    for (int j = 0; j < 16; ++j){
      const f32x2 dx = x2[j] - lp.x;
      const f32x2 dy = y2[j] - lp.y;
      const f32x2 dz = z2[j] - lp.z;
      const f32x2 dd = (dx * dx + dy * dy) + dz * dz;
      f32x2 nd;
      nd[0] = fminf(d2[j][0], dd[0]);
      nd[1] = fminf(d2[j][1], dd[1]);
      d2[j] = nd;
    }

    // in-lane argmax over 32 slots, adjacent-pair tree.
    // Every merge is (left range) vs (right range) with all left slot
    // indices < all right slot indices, so strict > keeps the lowest index
    // on ties (numpy argmax semantics).
    float av[16]; int as_[16];
    #pragma unroll
    for (int j = 0; j < 16; ++j){
      const float lo = d2[j][0], hi = d2[j][1];
      const bool t = hi > lo;
      av[j]  = t ? hi : lo;
      as_[j] = t ? 2 * j + 1 : 2 * j;
    }
    #pragma unroll
    for (int wdt = 8; wdt; wdt >>= 1){
      #pragma unroll
      for (int j = 0; j < wdt; ++j){
        const float lv = av[2 * j], rv = av[2 * j + 1];
        const int   li = as_[2 * j], ri = as_[2 * j + 1];
        const bool t = rv > lv;
        av[j]  = t ? rv : lv;
        as_[j] = t ? ri : li;
      }
    }

    // cross-lane argmax on (value, global index); ties -> lower global index
    int vb = __float_as_int(av[0]);
    int ib = (as_[0] << 6) + lane;
    DPP_ARGMAX_STAGE(0x111)   // row_shr:1
    DPP_ARGMAX_STAGE(0x112)   // row_shr:2
    DPP_ARGMAX_STAGE(0x114)   // row_shr:4
    DPP_ARGMAX_STAGE(0x118)   // row_shr:8
    DPP_ARGMAX_STAGE(0x142)   // row_bcast:15
    DPP_ARGMAX_STAGE(0x143)   // row_bcast:31

    last = __builtin_amdgcn_readlane(ib, 63);   // lane 63 holds the winner
    if (lane == 0) idx_out[b * NLAT + step] = last;
  }
}

// ---------------------------------------------------------------------------
// Fused (gather) + point_embed x2 + layernorm -> bf16. 16 points / block.
// ---------------------------------------------------------------------------
template<bool GATHER, bool WRITE_EMB>
__global__ __launch_bounds__(256) void embed_kernel(
    const float* __restrict__ pc, const float* __restrict__ pc2,
    const int* __restrict__ idx,
    const float* __restrict__ basis, const float* __restrict__ pe_w,
    const float* __restrict__ pe_b,
    const float* __restrict__ ln_g, const float* __restrict__ ln_b,
    bfu* __restrict__ emb, bfu* __restrict__ lnout, int nppbt)
{
  __shared__ float feat[2][16][NFEAT + 1];
  __shared__ float outb[16][DIMV];
  const int tid = threadIdx.x;
  const int p0 = blockIdx.x << 4;

  if (tid < 32){
    const int s = tid >> 4, p = tid & 15;
    const int gp = p0 + p;
    const int bt = gp / nppbt;
    const int n  = gp - bt * nppbt;
    const int bb = bt / NT;
    const int srcn = GATHER ? idx[bb * NLAT + n] : n;
    const float* sp = (s ? pc2 : pc) + ((size_t)bt * NCTX + srcn) * 3;
    const float x0 = sp[0], x1 = sp[1], x2 = sp[2];
    #pragma unroll
    for (int e = 0; e < 24; ++e){
      const float pr = __fadd_rn(__fadd_rn(__fmul_rn(x0, basis[e]),
                                           __fmul_rn(x1, basis[24 + e])),
                                 __fmul_rn(x2, basis[48 + e]));
      feat[s][p][e]      = sinf(pr);
      feat[s][p][24 + e] = cosf(pr);
    }
    feat[s][p][48] = x0; feat[s][p][49] = x1; feat[s][p][50] = x2;
  }
  __syncthreads();

  {
    float w[NFEAT];
    #pragma unroll
    for (int k = 0; k < NFEAT; ++k) w[k] = pe_w[k * HALFD + tid];
    const float bv = pe_b[tid];
    #pragma unroll
    for (int half = 0; half < 2; ++half){
      for (int p = 0; p < 16; ++p){
        float acc = bv;
        #pragma unroll
        for (int k = 0; k < NFEAT; ++k) acc = fmaf(feat[half][p][k], w[k], acc);
        outb[p][half * HALFD + tid] = acc;
      }
    }
  }
  __syncthreads();

  const int lane = tid & 63, wv = tid >> 6;
  for (int pp = 0; pp < 4; ++pp){
    const int p = (wv << 2) + pp;
    const size_t gp = (size_t)p0 + p;
    float x[8];
    #pragma unroll
    for (int j = 0; j < 8; ++j) x[j] = outb[p][lane + (j << 6)];
    float s = 0.f;
    #pragma unroll
    for (int j = 0; j < 8; ++j) s += x[j];
    for (int o = 32; o; o >>= 1) s += __shfl_xor(s, o, 64);
    const float m = s * (1.0f / 512.0f);
    float s2 = 0.f;
    #pragma unroll
    for (int j = 0; j < 8; ++j){ const float d = x[j] - m; s2 = fmaf(d, d, s2); }
    for (int o = 32; o; o >>= 1) s2 += __shfl_xor(s2, o, 64);
    const float inv = 1.0f / sqrtf(s2 * (1.0f / 512.0f) + 1e-5f);
    #pragma unroll
    for (int j = 0; j < 8; ++j){
      const int c = lane + (j << 6);
      const float r = (x[j] - m) * inv * ln_g[c] + ln_b[c];
      const size_t o2 = gp * DIMV + c;
      if (WRITE_EMB) emb[o2] = f2bf(x[j]);
      lnout[o2] = f2bf(r);
    }
  }
}

// ---------------------------------------------------------------------------
// Tiled transpose: in [R][C] (fp32 or bf16) -> out bf16 [C][R]. 32x32 tiles.
// ---------------------------------------------------------------------------
template<typename TIN>
__global__ __launch_bounds__(256) void transp_kernel(
    const TIN* __restrict__ in, bfu* __restrict__ out, int R, int C,
    long long sIn, long long sOut)
{
  __shared__ bfu t[32][33];
  in  += (size_t)blockIdx.z * sIn;
  out += (size_t)blockIdx.z * sOut;
  const int c0 = blockIdx.x * 32, r0 = blockIdx.y * 32;
  const int tx = threadIdx.x & 31, ty = threadIdx.x >> 5;
  #pragma unroll
  for (int rr = ty; rr < 32; rr += 8)
    t[rr][tx] = to_bfu(in[(size_t)(r0 + rr) * C + c0 + tx]);
  __syncthreads();
  #pragma unroll
  for (int rr = ty; rr < 32; rr += 8)
    out[(size_t)(c0 + rr) * R + r0 + tx] = t[tx][rr];
}

// ---------------------------------------------------------------------------
// MFMA GEMM: C[M][N] = A[M][K] * B[N][K]^T, bf16 inputs.
// Tile = (FH*32) x (FH*32): FH=4 -> 128x128 (4x4 frags/wave), FH=2 -> 64x64
// (2x2 frags/wave, for low-M/N batched GEMMs needing block-count occupancy).
// 4 waves in 2x2 grid. LDS rows padded to 40 shorts (2-way max conflicts).
// ---------------------------------------------------------------------------
#define EPI_NONE     0
#define EPI_SPLIT    1
#define EPI_SCALE    2
#define EPI_BIAS_RES 3
#define LDST 40

template<int FH, typename TC, typename TR, int EPI>
__global__ __launch_bounds__(256, 2) void gemm_mfma(
    const bfu* __restrict__ A, const bfu* __restrict__ B,
    TC* __restrict__ C, TC* __restrict__ C2,
    const float* __restrict__ bias, const TR* __restrict__ res,
    float scale, int N, int K, int lda, int ldb, int ldc,
    long long sA, long long sB, long long sC)
{
  constexpr int BT = FH * 32;              // block tile edge
  const int bz = blockIdx.z;
  A += (size_t)bz * sA;
  B += (size_t)bz * sB;
  const size_t coff = (size_t)bz * sC;

  __shared__ __align__(16) short As[BT * LDST];
  __shared__ __align__(16) short Bs[BT * LDST];

  const int tid = threadIdx.x;
  const int lane = tid & 63, w = tid >> 6;
  const int m0 = blockIdx.y * BT, n0 = blockIdx.x * BT;
  const int wm = (w & 1) * (FH * 16), wn = (w >> 1) * (FH * 16);
  const int fr = lane & 15, quad = lane >> 4;

  f32x4 acc[FH][FH];
  #pragma unroll
  for (int i = 0; i < FH; ++i)
    #pragma unroll
    for (int j = 0; j < FH; ++j)
      #pragma unroll
      for (int r = 0; r < 4; ++r) acc[i][j][r] = 0.f;

  for (int k0 = 0; k0 < K; k0 += 32){
    #pragma unroll
    for (int ch = tid; ch < BT * 4; ch += 256){   // 16B chunks per tile
      const int r = ch >> 2, c = ch & 3;
      *(uint4*)&As[r * LDST + c * 8] =
          *(const uint4*)(A + (size_t)(m0 + r) * lda + k0 + c * 8);
      *(uint4*)&Bs[r * LDST + c * 8] =
          *(const uint4*)(B + (size_t)(n0 + r) * ldb + k0 + c * 8);
    }
    __syncthreads();
    bf16x8 af[FH], bf[FH];
    #pragma unroll
    for (int i = 0; i < FH; ++i)
      af[i] = *(const bf16x8*)&As[(wm + i * 16 + fr) * LDST + quad * 8];
    #pragma unroll
    for (int j = 0; j < FH; ++j)
      bf[j] = *(const bf16x8*)&Bs[(wn + j * 16 + fr) * LDST + quad * 8];
    #pragma unroll
    for (int i = 0; i < FH; ++i)
      #pragma unroll
      for (int j = 0; j < FH; ++j)
        acc[i][j] = __builtin_amdgcn_mfma_f32_16x16x32_bf16(af[i], bf[j], acc[i][j], 0, 0, 0);
    __syncthreads();
  }

  // C/D layout: col = lane&15, row = quad*4 + reg
  TC* Cp = C + coff;
  #pragma unroll
  for (int i = 0; i < FH; ++i){
    #pragma unroll
    for (int r = 0; r < 4; ++r){
      const int cm = m0 + wm + i * 16 + quad * 4 + r;
      #pragma unroll
      for (int j = 0; j < FH; ++j){
        const int cn = n0 + wn + j * 16 + fr;
        float v = acc[i][j][r];
        if (EPI == EPI_SCALE)    v *= scale;
        if (EPI == EPI_BIAS_RES) v = v + bias[cn] + loadE(&res[coff + (size_t)cm * ldc + cn]);
        if (EPI == EPI_SPLIT){
          const int half = N >> 1;
          if (cn < half) storeE(&C [(size_t)cm * half + cn],          v);
          else           storeE(&C2[(size_t)cm * half + (cn - half)], v);
        } else {
          storeE(&Cp[(size_t)cm * ldc + cn], v);
        }
      }
    }
  }
}

// ---------------------------------------------------------------------------
// Fused MLP1 + exact GeLU (MFMA): act = (A@w1T[a]+b1a) * gelu(A@w1T[g]+b1g).
// ---------------------------------------------------------------------------
__global__ __launch_bounds__(256, 1) void mlp1_mfma(
    const bfu* __restrict__ A, const bfu* __restrict__ B,  // B = w1T [4096][512]
    const float* __restrict__ b1, bfu* __restrict__ act)
{
  __shared__ __align__(16) short As[128 * LDST];
  __shared__ __align__(16) short Ba[128 * LDST];
  __shared__ __align__(16) short Bg[128 * LDST];

  const int tid = threadIdx.x;
  const int lane = tid & 63, w = tid >> 6;
  const int m0 = blockIdx.y * 128, n0 = blockIdx.x * 128;
  const int wm = (w & 1) * 64, wn = (w >> 1) * 64;
  const int fr = lane & 15, quad = lane >> 4;

  f32x4 acca[4][4], accg[4][4];
  #pragma unroll
  for (int i = 0; i < 4; ++i)
    #pragma unroll
    for (int j = 0; j < 4; ++j)
      #pragma unroll
      for (int r = 0; r < 4; ++r){ acca[i][j][r] = 0.f; accg[i][j][r] = 0.f; }

  for (int k0 = 0; k0 < 512; k0 += 32){
    #pragma unroll
    for (int i = 0; i < 2; ++i){
      const int ch = tid + 256 * i;
      const int r = ch >> 2, c = ch & 3;
      *(uint4*)&As[r * LDST + c * 8] =
          *(const uint4*)(A + (size_t)(m0 + r) * 512 + k0 + c * 8);
      *(uint4*)&Ba[r * LDST + c * 8] =
          *(const uint4*)(B + (size_t)(n0 + r) * 512 + k0 + c * 8);
      *(uint4*)&Bg[r * LDST + c * 8] =
          *(const uint4*)(B + (size_t)(n0 + 2048 + r) * 512 + k0 + c * 8);
    }
    __syncthreads();
    bf16x8 af[4], ba[4], bg[4];
    #pragma unroll
    for (int i = 0; i < 4; ++i)
      af[i] = *(const bf16x8*)&As[(wm + i * 16 + fr) * LDST + quad * 8];
    #pragma unroll
    for (int j = 0; j < 4; ++j){
      ba[j] = *(const bf16x8*)&Ba[(wn + j * 16 + fr) * LDST + quad * 8];
      bg[j] = *(const bf16x8*)&Bg[(wn + j * 16 + fr) * LDST + quad * 8];
    }
    #pragma unroll
    for (int i = 0; i < 4; ++i)
      #pragma unroll
      for (int j = 0; j < 4; ++j){
        acca[i][j] = __builtin_amdgcn_mfma_f32_16x16x32_bf16(af[i], ba[j], acca[i][j], 0, 0, 0);
        accg[i][j] = __builtin_amdgcn_mfma_f32_16x16x32_bf16(af[i], bg[j], accg[i][j], 0, 0, 0);
      }
    __syncthreads();
  }

  #pragma unroll
  for (int i = 0; i < 4; ++i){
    #pragma unroll
    for (int r = 0; r < 4; ++r){
      const int cm = m0 + wm + i * 16 + quad * 4 + r;
      #pragma unroll
      for (int j = 0; j < 4; ++j){
        const int cn = n0 + wn + j * 16 + fr;
        const float a = acca[i][j][r] + b1[cn];
        const float g = accg[i][j][r] + b1[cn + 2048];
        const float ge = g * 0.5f * (1.0f + erff(g * 0.70710678118654752f));
        act[(size_t)cm * 2048 + cn] = f2bf(a * ge);
      }
    }
  }
}

// ---------------------------------------------------------------------------
// Row softmax over 2048 bf16 logits, in place.
// ---------------------------------------------------------------------------
__global__ __launch_bounds__(256) void softmax_kernel(bfu* __restrict__ sc){
  __shared__ float red[4];
  const int tid = threadIdx.x;
  const int lane = tid & 63, wv = tid >> 6;
  bfu* rp = sc + (size_t)blockIdx.x * NCTX;
  float x[8];
  #pragma unroll
  for (int j = 0; j < 8; ++j) x[j] = bf2f(rp[tid + (j << 8)]);
  float mx = x[0];
  #pragma unroll
  for (int j = 1; j < 8; ++j) mx = fmaxf(mx, x[j]);
  for (int o = 32; o; o >>= 1) mx = fmaxf(mx, __shfl_xor(mx, o, 64));
  if (lane == 0) red[wv] = mx;
  __syncthreads();
  mx = fmaxf(fmaxf(red[0], red[1]), fmaxf(red[2], red[3]));
  float sum = 0.f;
  #pragma unroll
  for (int j = 0; j < 8; ++j){ x[j] = __expf(x[j] - mx); sum += x[j]; }
  for (int o = 32; o; o >>= 1) sum += __shfl_xor(sum, o, 64);
  __syncthreads();
  if (lane == 0) red[wv] = sum;
  __syncthreads();
  sum = red[0] + red[1] + red[2] + red[3];
  const float inv = 1.0f / sum;
  #pragma unroll
  for (int j = 0; j < 8; ++j) rp[tid + (j << 8)] = f2bf(x[j] * inv);
}

// ---------------------------------------------------------------------------
// LayerNorm rows of 512 fp32 -> bf16.
// ---------------------------------------------------------------------------
__global__ __launch_bounds__(256) void ln_kernel(const float* __restrict__ in,
                                                 const float* __restrict__ g,
                                                 const float* __restrict__ b,
                                                 bfu* __restrict__ out){
  const int tid = threadIdx.x, lane = tid & 63, wv = tid >> 6;
  const size_t row = (size_t)blockIdx.x * 4 + wv;
  const float* rp = in + row * DIMV;
  float x[8];
  #pragma unroll
  for (int j = 0; j < 8; ++j) x[j] = rp[lane + (j << 6)];
  float s = 0.f;
  #pragma unroll
  for (int j = 0; j < 8; ++j) s += x[j];
  for (int o = 32; o; o >>= 1) s += __shfl_xor(s, o, 64);
  const float m = s * (1.0f / 512.0f);
  float s2 = 0.f;
  #pragma unroll
  for (int j = 0; j < 8; ++j){ const float d = x[j] - m; s2 = fmaf(d, d, s2); }
  for (int o = 32; o; o >>= 1) s2 += __shfl_xor(s2, o, 64);
  const float inv = 1.0f / sqrtf(s2 * (1.0f / 512.0f) + 1e-5f);
  bfu* op = out + row * DIMV;
  #pragma unroll
  for (int j = 0; j < 8; ++j){
    const int c = lane + (j << 6);
    op[c] = f2bf((x[j] - m) * inv * g[c] + b[c]);
  }
}

// ---------------------------------------------------------------------------
// Workspace (peak 121,667,584 B < proven 125,861,888):
//   idx    @ 0          (32 KB)
//   emb_s  @ 32768      (25,165,824) \  act half (50,331,648) aliases
//   q_in   @ 25198592   (25,165,824) /  emb_s+q_in (both dead at MLP)
//          q_in -> attnout after q GEMM
//   c_grp  @ 50364416   (12,582,912) -> scores (GRP=6)
//   k_grp  @ 62947328   (12,582,912) -> vT (k dead after scores; group loop
//                                          order: ...scores, softmax, transp, pv)
//   v_grp  @ 75530240   (12,582,912)
//   qbuf   @ 88113152   (25,165,824) -> lnx
//   wT     @ 113278976  (8,388,608): wqT|wkvT|woT|w1T|w2T
// ---------------------------------------------------------------------------
extern "C" void kernel_launch(void* const* d_in, const int* in_sizes, int n_in,
                              void* d_out, int out_size, void* d_ws, size_t ws_size,
                              hipStream_t stream)
{
  (void)in_sizes; (void)n_in; (void)out_size;
  if (ws_size < 121667584ull) return;

  const float* pc    = (const float*)d_in[0];
  const float* pc2   = (const float*)d_in[1];
  const float* basis = (const float*)d_in[2];
  const float* pe_w  = (const float*)d_in[3];
  const float* pe_b  = (const float*)d_in[4];
  const float* lnq_g = (const float*)d_in[5];
  const float* lnq_b = (const float*)d_in[6];
  const float* lnc_g = (const float*)d_in[7];
  const float* lnc_b = (const float*)d_in[8];
  const float* wq    = (const float*)d_in[9];
  const float* wkv   = (const float*)d_in[10];
  const float* wo    = (const float*)d_in[11];
  const float* bo    = (const float*)d_in[12];
  const float* lnf_g = (const float*)d_in[13];
  const float* lnf_b = (const float*)d_in[14];
  const float* w1    = (const float*)d_in[15];
  const float* b1    = (const float*)d_in[16];
  const float* w2    = (const float*)d_in[17];
  const float* b2    = (const float*)d_in[18];
  float* xout = (float*)d_out;

  char* ws = (char*)d_ws;
  int* idxb   = (int*)(ws);
  bfu* emb_s  = (bfu*)(ws + 32768);
  bfu* q_in   = (bfu*)(ws + 25198592);
  bfu* c_grp  = (bfu*)(ws + 50364416);
  bfu* k_grp  = (bfu*)(ws + 62947328);
  bfu* v_grp  = (bfu*)(ws + 75530240);
  bfu* qbuf   = (bfu*)(ws + 88113152);
  bfu* wqT    = (bfu*)(ws + 113278976);
  bfu* wkvT   = (bfu*)(ws + 113803264);
  bfu* woT    = (bfu*)(ws + 114851840);
  bfu* w1T    = (bfu*)(ws + 115376128);
  bfu* w2T    = (bfu*)(ws + 119570432);
  bfu* scores  = c_grp;     // after c consumed by kv
  bfu* vT      = k_grp;     // after k consumed by scores
  bfu* attnout = q_in;      // after q GEMM consumed q_in
  bfu* lnx     = qbuf;      // after attention consumed q
  bfu* actb    = emb_s;     // spans emb_s+q_in (one MLP half at a time)

  // 0. weight transposes (fp32 [K][N] -> bf16 [N][K])
  transp_kernel<float><<<dim3(16, 16, 1),  256, 0, stream>>>(wq,  wqT,  512,  512, 0, 0);
  transp_kernel<float><<<dim3(32, 16, 1),  256, 0, stream>>>(wkv, wkvT, 512, 1024, 0, 0);
  transp_kernel<float><<<dim3(16, 16, 1),  256, 0, stream>>>(wo,  woT,  512,  512, 0, 0);
  transp_kernel<float><<<dim3(128, 16, 1), 256, 0, stream>>>(w1,  w1T,  512, 4096, 0, 0);
  transp_kernel<float><<<dim3(16, 64, 1),  256, 0, stream>>>(w2,  w2T, 2048,  512, 0, 0);

  // 1. FPS (1 wave per batch, register-resident points)
  fps_kernel<<<NB, 64, 0, stream>>>(pc, idxb);

  // 2. latent embed -> emb_s (raw) + q_in (LN'd)
  embed_kernel<true, true><<<MROWS/16, 256, 0, stream>>>(
      pc, pc2, idxb, basis, pe_w, pe_b, lnq_g, lnq_b, emb_s, q_in, NLAT);

  // 3. q = q_in @ wq
  gemm_mfma<4, bfu, float, EPI_NONE><<<dim3(4, 192, 1), 256, 0, stream>>>(
      q_in, wqT, qbuf, nullptr, nullptr, nullptr, 1.0f,
      512, 512, 512, 512, 512, 0, 0, 0);

  // 4. per-group context pipeline (GRP=6, 8 groups)
  for (int g = 0; g < NGRP; ++g){
    const int bt0 = g * GRP;
    embed_kernel<false, false><<<GROWS/16, 256, 0, stream>>>(
        pc + (size_t)bt0 * NCTX * 3, pc2 + (size_t)bt0 * NCTX * 3, nullptr,
        basis, pe_w, pe_b, lnc_g, lnc_b, nullptr, c_grp, NCTX);

    // kv = c @ wkv -> split k | v
    gemm_mfma<4, bfu, float, EPI_SPLIT><<<dim3(8, 96, 1), 256, 0, stream>>>(
        c_grp, wkvT, k_grp, v_grp, nullptr, nullptr, 1.0f,
        1024, 512, 512, 512, 512, 0, 0, 0);

    // scores = (q @ k^T) * scale (overwrites c_grp region)
    gemm_mfma<4, bfu, float, EPI_SCALE><<<dim3(16, 4, GRP), 256, 0, stream>>>(
        qbuf + (size_t)bt0 * 262144, k_grp, scores, nullptr, nullptr, nullptr,
        0.044194173824159216f,
        2048, 512, 512, 512, 2048, 262144, 1048576, 1048576);

    softmax_kernel<<<GRP * 512, 256, 0, stream>>>(scores);

    // vT = transpose(v) per bt (overwrites k_grp; k dead after scores)
    transp_kernel<bfu><<<dim3(16, 64, GRP), 256, 0, stream>>>(
        v_grp, vT, 2048, 512, 2048*512, 2048*512);

    // attnout = P @ V : 64x64 tiles -> (8,8,GRP) blocks for occupancy
    gemm_mfma<2, bfu, float, EPI_NONE><<<dim3(8, 8, GRP), 256, 0, stream>>>(
        scores, vT, attnout + (size_t)bt0 * 262144, nullptr, nullptr, nullptr, 1.0f,
        512, 2048, 2048, 2048, 512, 1048576, 1048576, 262144);
  }

  // 5. x = attnout @ wo + bo + emb_s -> d_out (fp32)
  gemm_mfma<4, float, bfu, EPI_BIAS_RES><<<dim3(4, 192, 1), 256, 0, stream>>>(
      attnout, woT, xout, nullptr, bo, emb_s, 1.0f,
      512, 512, 512, 512, 512, 0, 0, 0);

  // 6. lnx = LN(x)
  ln_kernel<<<MROWS/4, 256, 0, stream>>>(xout, lnf_g, lnf_b, lnx);

  // 7/8. MLP in two row-halves (act buffer holds one half)
  for (int h = 0; h < 2; ++h){
    const size_t ro = (size_t)h * 12288;
    mlp1_mfma<<<dim3(16, 96, 1), 256, 0, stream>>>(
        lnx + ro * 512, w1T, b1, actb);
    gemm_mfma<4, float, float, EPI_BIAS_RES><<<dim3(4, 96, 1), 256, 0, stream>>>(
        actb, w2T, xout + ro * 512, nullptr, b2, xout + ro * 512, 1.0f,
        512, 2048, 2048, 2048, 512, 0, 0, 0);
  }
}

// Round 4
// 2137.038 us; speedup vs baseline: 1.0562x; 1.0562x over previous
//
#include <hip/hip_runtime.h>

// Problem constants
#define NB    16
#define NT    3
#define NCTX  2048
#define NLAT  512
#define DIMV  512
#define HALFD 256
#define NFEAT 51
#define NBT   48
#define MROWS 24576    // NBT*NLAT
#define GRP   6        // bt per context group
#define NGRP  8
#define GROWS 12288    // GRP*NCTX

typedef unsigned short bfu;   // bf16 storage as raw bits
typedef short bf16x8 __attribute__((ext_vector_type(8)));   // 8 bf16 = 4 VGPR
typedef float f32x4  __attribute__((ext_vector_type(4)));   // MFMA 16x16 acc
typedef float f32x2  __attribute__((ext_vector_type(2)));   // packed fp32 pair

__device__ __forceinline__ float bf2f(bfu u){ return __uint_as_float(((unsigned int)u) << 16); }
__device__ __forceinline__ bfu f2bf(float f){
  unsigned int u = __float_as_uint(f);
  u += 0x7FFFu + ((u >> 16) & 1u);          // RNE
  return (bfu)(u >> 16);
}
__device__ __forceinline__ float loadE(const float* p){ return *p; }
__device__ __forceinline__ float loadE(const bfu* p){ return bf2f(*p); }
__device__ __forceinline__ void storeE(float* p, float v){ *p = v; }
__device__ __forceinline__ void storeE(bfu* p, float v){ *p = f2bf(v); }
__device__ __forceinline__ bfu to_bfu(float f){ return f2bf(f); }
__device__ __forceinline__ bfu to_bfu(bfu u){ return u; }

// ---------------------------------------------------------------------------
// FPS: ONE wave per batch. Coords live in LDS (pts[] float4, the same array
// used for the "last"-point broadcast); ONLY the running min-distances stay
// in registers (16 f32x2 = 32 VGPRs). R1-R3 proved the register allocator
// will not grant this kernel enough VGPRs for register-resident coords
// (88 -> 132 despite waves_per_eu(1,1); needs >=160) and silently spills
// them to scratch -- ~500cy L2 round-trips in the serial chain. LDS reads
// at 16B/lane stride are the canonical conflict-free ds_read_b128 pattern
// (~12cy/instr), and d2 fits registers by construction.
// Per step: uniform LDS broadcast of last coords -> 32x ds_read_b128 +
// packed dist update -> adjacent-pair in-lane argmax tree (index-ordered
// merges: strict > preserves numpy first-max tie-break) -> 6-stage DPP wave
// argmax -> readlane broadcast. No barriers in the serial loop. Arithmetic
// (contract off, op order, fminf, 1e10f) identical to the proven bit-exact
// version.
// ---------------------------------------------------------------------------
#define DPP_ARGMAX_STAGE(CTRL)                                                \
  {                                                                           \
    const int svb = __builtin_amdgcn_update_dpp(vb, vb, CTRL, 0xF, 0xF, false); \
    const int sib = __builtin_amdgcn_update_dpp(ib, ib, CTRL, 0xF, 0xF, false); \
    const float sv = __int_as_float(svb);                                     \
    const float cv = __int_as_float(vb);                                      \
    if (sv > cv || (sv == cv && sib < ib)){ vb = svb; ib = sib; }             \
  }

__global__ __attribute__((amdgpu_waves_per_eu(1, 1)))
__launch_bounds__(64) void fps_kernel(const float* __restrict__ pc,
                                      int* __restrict__ idx_out){
#pragma clang fp contract(off)
  __shared__ float4 pts[NCTX];            // coords home + broadcast source
  const int lane = threadIdx.x;           // 0..63, single wave
  const int b = blockIdx.x;
  const float* src = pc + (size_t)b * (NT * NCTX * 3);

  // Slot s (0..31) = global point p = (s<<6)|lane. Only d2 is register-
  // resident: pair j holds slots 2j (lo) and 2j+1 (hi).
  f32x2 d2[16];
  #pragma unroll
  for (int j = 0; j < 16; ++j){
    #pragma unroll
    for (int h = 0; h < 2; ++h){
      const int p = ((2 * j + h) << 6) + lane;
      const float xx = src[p * 3 + 0];
      const float yy = src[p * 3 + 1];
      const float zz = src[p * 3 + 2];
      pts[p] = make_float4(xx, yy, zz, 0.f);
    }
    d2[j][0] = 1e10f; d2[j][1] = 1e10f;
  }
  if (lane == 0) idx_out[b * NLAT] = 0;
  __syncthreads();                        // drain LDS writes (single wave)

  int last = 0;
  for (int step = 1; step < NLAT; ++step){
    const float4 lp = pts[last];          // uniform addr -> LDS broadcast

    // distance update: coords streamed from LDS (conflict-free b128),
    // identical op order to the previous bit-exact version.
    #pragma unroll
    for (int j = 0; j < 16; ++j){
      const float4 a0 = pts[((2 * j + 0) << 6) + lane];
      const float4 a1 = pts[((2 * j + 1) << 6) + lane];
      f32x2 xx; xx[0] = a0.x; xx[1] = a1.x;
      f32x2 yy; yy[0] = a0.y; yy[1] = a1.y;
      f32x2 zz; zz[0] = a0.z; zz[1] = a1.z;
      const f32x2 dx = xx - lp.x;
      const f32x2 dy = yy - lp.y;
      const f32x2 dz = zz - lp.z;
      const f32x2 dd = (dx * dx + dy * dy) + dz * dz;
      f32x2 nd;
      nd[0] = fminf(d2[j][0], dd[0]);
      nd[1] = fminf(d2[j][1], dd[1]);
      d2[j] = nd;
    }

    // in-lane argmax over 32 slots, adjacent-pair tree.
    // Every merge is (left range) vs (right range) with all left slot
    // indices < all right slot indices, so strict > keeps the lowest index
    // on ties (numpy argmax semantics).
    float av[16]; int as_[16];
    #pragma unroll
    for (int j = 0; j < 16; ++j){
      const float lo = d2[j][0], hi = d2[j][1];
      const bool t = hi > lo;
      av[j]  = t ? hi : lo;
      as_[j] = t ? 2 * j + 1 : 2 * j;
    }
    #pragma unroll
    for (int wdt = 8; wdt; wdt >>= 1){
      #pragma unroll
      for (int j = 0; j < wdt; ++j){
        const float lv = av[2 * j], rv = av[2 * j + 1];
        const int   li = as_[2 * j], ri = as_[2 * j + 1];
        const bool t = rv > lv;
        av[j]  = t ? rv : lv;
        as_[j] = t ? ri : li;
      }
    }

    // cross-lane argmax on (value, global index); ties -> lower global index
    int vb = __float_as_int(av[0]);
    int ib = (as_[0] << 6) + lane;
    DPP_ARGMAX_STAGE(0x111)   // row_shr:1
    DPP_ARGMAX_STAGE(0x112)   // row_shr:2
    DPP_ARGMAX_STAGE(0x114)   // row_shr:4
    DPP_ARGMAX_STAGE(0x118)   // row_shr:8
    DPP_ARGMAX_STAGE(0x142)   // row_bcast:15
    DPP_ARGMAX_STAGE(0x143)   // row_bcast:31

    last = __builtin_amdgcn_readlane(ib, 63);   // lane 63 holds the winner
    if (lane == 0) idx_out[b * NLAT + step] = last;
  }
}

// ---------------------------------------------------------------------------
// Fused (gather) + point_embed x2 + layernorm -> bf16. 16 points / block.
// ---------------------------------------------------------------------------
template<bool GATHER, bool WRITE_EMB>
__global__ __launch_bounds__(256) void embed_kernel(
    const float* __restrict__ pc, const float* __restrict__ pc2,
    const int* __restrict__ idx,
    const float* __restrict__ basis, const float* __restrict__ pe_w,
    const float* __restrict__ pe_b,
    const float* __restrict__ ln_g, const float* __restrict__ ln_b,
    bfu* __restrict__ emb, bfu* __restrict__ lnout, int nppbt)
{
  __shared__ float feat[2][16][NFEAT + 1];
  __shared__ float outb[16][DIMV];
  const int tid = threadIdx.x;
  const int p0 = blockIdx.x << 4;

  if (tid < 32){
    const int s = tid >> 4, p = tid & 15;
    const int gp = p0 + p;
    const int bt = gp / nppbt;
    const int n  = gp - bt * nppbt;
    const int bb = bt / NT;
    const int srcn = GATHER ? idx[bb * NLAT + n] : n;
    const float* sp = (s ? pc2 : pc) + ((size_t)bt * NCTX + srcn) * 3;
    const float x0 = sp[0], x1 = sp[1], x2 = sp[2];
    #pragma unroll
    for (int e = 0; e < 24; ++e){
      const float pr = __fadd_rn(__fadd_rn(__fmul_rn(x0, basis[e]),
                                           __fmul_rn(x1, basis[24 + e])),
                                 __fmul_rn(x2, basis[48 + e]));
      feat[s][p][e]      = sinf(pr);
      feat[s][p][24 + e] = cosf(pr);
    }
    feat[s][p][48] = x0; feat[s][p][49] = x1; feat[s][p][50] = x2;
  }
  __syncthreads();

  {
    float w[NFEAT];
    #pragma unroll
    for (int k = 0; k < NFEAT; ++k) w[k] = pe_w[k * HALFD + tid];
    const float bv = pe_b[tid];
    #pragma unroll
    for (int half = 0; half < 2; ++half){
      for (int p = 0; p < 16; ++p){
        float acc = bv;
        #pragma unroll
        for (int k = 0; k < NFEAT; ++k) acc = fmaf(feat[half][p][k], w[k], acc);
        outb[p][half * HALFD + tid] = acc;
      }
    }
  }
  __syncthreads();

  const int lane = tid & 63, wv = tid >> 6;
  for (int pp = 0; pp < 4; ++pp){
    const int p = (wv << 2) + pp;
    const size_t gp = (size_t)p0 + p;
    float x[8];
    #pragma unroll
    for (int j = 0; j < 8; ++j) x[j] = outb[p][lane + (j << 6)];
    float s = 0.f;
    #pragma unroll
    for (int j = 0; j < 8; ++j) s += x[j];
    for (int o = 32; o; o >>= 1) s += __shfl_xor(s, o, 64);
    const float m = s * (1.0f / 512.0f);
    float s2 = 0.f;
    #pragma unroll
    for (int j = 0; j < 8; ++j){ const float d = x[j] - m; s2 = fmaf(d, d, s2); }
    for (int o = 32; o; o >>= 1) s2 += __shfl_xor(s2, o, 64);
    const float inv = 1.0f / sqrtf(s2 * (1.0f / 512.0f) + 1e-5f);
    #pragma unroll
    for (int j = 0; j < 8; ++j){
      const int c = lane + (j << 6);
      const float r = (x[j] - m) * inv * ln_g[c] + ln_b[c];
      const size_t o2 = gp * DIMV + c;
      if (WRITE_EMB) emb[o2] = f2bf(x[j]);
      lnout[o2] = f2bf(r);
    }
  }
}

// ---------------------------------------------------------------------------
// Tiled transpose: in [R][C] (fp32 or bf16) -> out bf16 [C][R]. 32x32 tiles.
// ---------------------------------------------------------------------------
template<typename TIN>
__global__ __launch_bounds__(256) void transp_kernel(
    const TIN* __restrict__ in, bfu* __restrict__ out, int R, int C,
    long long sIn, long long sOut)
{
  __shared__ bfu t[32][33];
  in  += (size_t)blockIdx.z * sIn;
  out += (size_t)blockIdx.z * sOut;
  const int c0 = blockIdx.x * 32, r0 = blockIdx.y * 32;
  const int tx = threadIdx.x & 31, ty = threadIdx.x >> 5;
  #pragma unroll
  for (int rr = ty; rr < 32; rr += 8)
    t[rr][tx] = to_bfu(in[(size_t)(r0 + rr) * C + c0 + tx]);
  __syncthreads();
  #pragma unroll
  for (int rr = ty; rr < 32; rr += 8)
    out[(size_t)(c0 + rr) * R + r0 + tx] = t[tx][rr];
}

// ---------------------------------------------------------------------------
// MFMA GEMM: C[M][N] = A[M][K] * B[N][K]^T, bf16 inputs.
// Tile = (FH*32) x (FH*32): FH=4 -> 128x128 (4x4 frags/wave), FH=2 -> 64x64
// (2x2 frags/wave, for low-M/N batched GEMMs needing block-count occupancy).
// 4 waves in 2x2 grid. LDS rows padded to 40 shorts (2-way max conflicts).
// ---------------------------------------------------------------------------
#define EPI_NONE     0
#define EPI_SPLIT    1
#define EPI_SCALE    2
#define EPI_BIAS_RES 3
#define LDST 40

template<int FH, typename TC, typename TR, int EPI>
__global__ __launch_bounds__(256, 2) void gemm_mfma(
    const bfu* __restrict__ A, const bfu* __restrict__ B,
    TC* __restrict__ C, TC* __restrict__ C2,
    const float* __restrict__ bias, const TR* __restrict__ res,
    float scale, int N, int K, int lda, int ldb, int ldc,
    long long sA, long long sB, long long sC)
{
  constexpr int BT = FH * 32;              // block tile edge
  const int bz = blockIdx.z;
  A += (size_t)bz * sA;
  B += (size_t)bz * sB;
  const size_t coff = (size_t)bz * sC;

  __shared__ __align__(16) short As[BT * LDST];
  __shared__ __align__(16) short Bs[BT * LDST];

  const int tid = threadIdx.x;
  const int lane = tid & 63, w = tid >> 6;
  const int m0 = blockIdx.y * BT, n0 = blockIdx.x * BT;
  const int wm = (w & 1) * (FH * 16), wn = (w >> 1) * (FH * 16);
  const int fr = lane & 15, quad = lane >> 4;

  f32x4 acc[FH][FH];
  #pragma unroll
  for (int i = 0; i < FH; ++i)
    #pragma unroll
    for (int j = 0; j < FH; ++j)
      #pragma unroll
      for (int r = 0; r < 4; ++r) acc[i][j][r] = 0.f;

  for (int k0 = 0; k0 < K; k0 += 32){
    #pragma unroll
    for (int ch = tid; ch < BT * 4; ch += 256){   // 16B chunks per tile
      const int r = ch >> 2, c = ch & 3;
      *(uint4*)&As[r * LDST + c * 8] =
          *(const uint4*)(A + (size_t)(m0 + r) * lda + k0 + c * 8);
      *(uint4*)&Bs[r * LDST + c * 8] =
          *(const uint4*)(B + (size_t)(n0 + r) * ldb + k0 + c * 8);
    }
    __syncthreads();
    bf16x8 af[FH], bf[FH];
    #pragma unroll
    for (int i = 0; i < FH; ++i)
      af[i] = *(const bf16x8*)&As[(wm + i * 16 + fr) * LDST + quad * 8];
    #pragma unroll
    for (int j = 0; j < FH; ++j)
      bf[j] = *(const bf16x8*)&Bs[(wn + j * 16 + fr) * LDST + quad * 8];
    #pragma unroll
    for (int i = 0; i < FH; ++i)
      #pragma unroll
      for (int j = 0; j < FH; ++j)
        acc[i][j] = __builtin_amdgcn_mfma_f32_16x16x32_bf16(af[i], bf[j], acc[i][j], 0, 0, 0);
    __syncthreads();
  }

  // C/D layout: col = lane&15, row = quad*4 + reg
  TC* Cp = C + coff;
  #pragma unroll
  for (int i = 0; i < FH; ++i){
    #pragma unroll
    for (int r = 0; r < 4; ++r){
      const int cm = m0 + wm + i * 16 + quad * 4 + r;
      #pragma unroll
      for (int j = 0; j < FH; ++j){
        const int cn = n0 + wn + j * 16 + fr;
        float v = acc[i][j][r];
        if (EPI == EPI_SCALE)    v *= scale;
        if (EPI == EPI_BIAS_RES) v = v + bias[cn] + loadE(&res[coff + (size_t)cm * ldc + cn]);
        if (EPI == EPI_SPLIT){
          const int half = N >> 1;
          if (cn < half) storeE(&C [(size_t)cm * half + cn],          v);
          else           storeE(&C2[(size_t)cm * half + (cn - half)], v);
        } else {
          storeE(&Cp[(size_t)cm * ldc + cn], v);
        }
      }
    }
  }
}

// ---------------------------------------------------------------------------
// Fused MLP1 + exact GeLU (MFMA): act = (A@w1T[a]+b1a) * gelu(A@w1T[g]+b1g).
// ---------------------------------------------------------------------------
__global__ __launch_bounds__(256, 1) void mlp1_mfma(
    const bfu* __restrict__ A, const bfu* __restrict__ B,  // B = w1T [4096][512]
    const float* __restrict__ b1, bfu* __restrict__ act)
{
  __shared__ __align__(16) short As[128 * LDST];
  __shared__ __align__(16) short Ba[128 * LDST];
  __shared__ __align__(16) short Bg[128 * LDST];

  const int tid = threadIdx.x;
  const int lane = tid & 63, w = tid >> 6;
  const int m0 = blockIdx.y * 128, n0 = blockIdx.x * 128;
  const int wm = (w & 1) * 64, wn = (w >> 1) * 64;
  const int fr = lane & 15, quad = lane >> 4;

  f32x4 acca[4][4], accg[4][4];
  #pragma unroll
  for (int i = 0; i < 4; ++i)
    #pragma unroll
    for (int j = 0; j < 4; ++j)
      #pragma unroll
      for (int r = 0; r < 4; ++r){ acca[i][j][r] = 0.f; accg[i][j][r] = 0.f; }

  for (int k0 = 0; k0 < 512; k0 += 32){
    #pragma unroll
    for (int i = 0; i < 2; ++i){
      const int ch = tid + 256 * i;
      const int r = ch >> 2, c = ch & 3;
      *(uint4*)&As[r * LDST + c * 8] =
          *(const uint4*)(A + (size_t)(m0 + r) * 512 + k0 + c * 8);
      *(uint4*)&Ba[r * LDST + c * 8] =
          *(const uint4*)(B + (size_t)(n0 + r) * 512 + k0 + c * 8);
      *(uint4*)&Bg[r * LDST + c * 8] =
          *(const uint4*)(B + (size_t)(n0 + 2048 + r) * 512 + k0 + c * 8);
    }
    __syncthreads();
    bf16x8 af[4], ba[4], bg[4];
    #pragma unroll
    for (int i = 0; i < 4; ++i)
      af[i] = *(const bf16x8*)&As[(wm + i * 16 + fr) * LDST + quad * 8];
    #pragma unroll
    for (int j = 0; j < 4; ++j){
      ba[j] = *(const bf16x8*)&Ba[(wn + j * 16 + fr) * LDST + quad * 8];
      bg[j] = *(const bf16x8*)&Bg[(wn + j * 16 + fr) * LDST + quad * 8];
    }
    #pragma unroll
    for (int i = 0; i < 4; ++i)
      #pragma unroll
      for (int j = 0; j < 4; ++j){
        acca[i][j] = __builtin_amdgcn_mfma_f32_16x16x32_bf16(af[i], ba[j], acca[i][j], 0, 0, 0);
        accg[i][j] = __builtin_amdgcn_mfma_f32_16x16x32_bf16(af[i], bg[j], accg[i][j], 0, 0, 0);
      }
    __syncthreads();
  }

  #pragma unroll
  for (int i = 0; i < 4; ++i){
    #pragma unroll
    for (int r = 0; r < 4; ++r){
      const int cm = m0 + wm + i * 16 + quad * 4 + r;
      #pragma unroll
      for (int j = 0; j < 4; ++j){
        const int cn = n0 + wn + j * 16 + fr;
        const float a = acca[i][j][r] + b1[cn];
        const float g = accg[i][j][r] + b1[cn + 2048];
        const float ge = g * 0.5f * (1.0f + erff(g * 0.70710678118654752f));
        act[(size_t)cm * 2048 + cn] = f2bf(a * ge);
      }
    }
  }
}

// ---------------------------------------------------------------------------
// Row softmax over 2048 bf16 logits, in place.
// ---------------------------------------------------------------------------
__global__ __launch_bounds__(256) void softmax_kernel(bfu* __restrict__ sc){
  __shared__ float red[4];
  const int tid = threadIdx.x;
  const int lane = tid & 63, wv = tid >> 6;
  bfu* rp = sc + (size_t)blockIdx.x * NCTX;
  float x[8];
  #pragma unroll
  for (int j = 0; j < 8; ++j) x[j] = bf2f(rp[tid + (j << 8)]);
  float mx = x[0];
  #pragma unroll
  for (int j = 1; j < 8; ++j) mx = fmaxf(mx, x[j]);
  for (int o = 32; o; o >>= 1) mx = fmaxf(mx, __shfl_xor(mx, o, 64));
  if (lane == 0) red[wv] = mx;
  __syncthreads();
  mx = fmaxf(fmaxf(red[0], red[1]), fmaxf(red[2], red[3]));
  float sum = 0.f;
  #pragma unroll
  for (int j = 0; j < 8; ++j){ x[j] = __expf(x[j] - mx); sum += x[j]; }
  for (int o = 32; o; o >>= 1) sum += __shfl_xor(sum, o, 64);
  __syncthreads();
  if (lane == 0) red[wv] = sum;
  __syncthreads();
  sum = red[0] + red[1] + red[2] + red[3];
  const float inv = 1.0f / sum;
  #pragma unroll
  for (int j = 0; j < 8; ++j) rp[tid + (j << 8)] = f2bf(x[j] * inv);
}

// ---------------------------------------------------------------------------
// LayerNorm rows of 512 fp32 -> bf16.
// ---------------------------------------------------------------------------
__global__ __launch_bounds__(256) void ln_kernel(const float* __restrict__ in,
                                                 const float* __restrict__ g,
                                                 const float* __restrict__ b,
                                                 bfu* __restrict__ out){
  const int tid = threadIdx.x, lane = tid & 63, wv = tid >> 6;
  const size_t row = (size_t)blockIdx.x * 4 + wv;
  const float* rp = in + row * DIMV;
  float x[8];
  #pragma unroll
  for (int j = 0; j < 8; ++j) x[j] = rp[lane + (j << 6)];
  float s = 0.f;
  #pragma unroll
  for (int j = 0; j < 8; ++j) s += x[j];
  for (int o = 32; o; o >>= 1) s += __shfl_xor(s, o, 64);
  const float m = s * (1.0f / 512.0f);
  float s2 = 0.f;
  #pragma unroll
  for (int j = 0; j < 8; ++j){ const float d = x[j] - m; s2 = fmaf(d, d, s2); }
  for (int o = 32; o; o >>= 1) s2 += __shfl_xor(s2, o, 64);
  const float inv = 1.0f / sqrtf(s2 * (1.0f / 512.0f) + 1e-5f);
  bfu* op = out + row * DIMV;
  #pragma unroll
  for (int j = 0; j < 8; ++j){
    const int c = lane + (j << 6);
    op[c] = f2bf((x[j] - m) * inv * g[c] + b[c]);
  }
}

// ---------------------------------------------------------------------------
// Workspace (peak 121,667,584 B < proven 125,861,888):
//   idx    @ 0          (32 KB)
//   emb_s  @ 32768      (25,165,824) \  act half (50,331,648) aliases
//   q_in   @ 25198592   (25,165,824) /  emb_s+q_in (both dead at MLP)
//          q_in -> attnout after q GEMM
//   c_grp  @ 50364416   (12,582,912) -> scores (GRP=6)
//   k_grp  @ 62947328   (12,582,912) -> vT (k dead after scores; group loop
//                                          order: ...scores, softmax, transp, pv)
//   v_grp  @ 75530240   (12,582,912)
//   qbuf   @ 88113152   (25,165,824) -> lnx
//   wT     @ 113278976  (8,388,608): wqT|wkvT|woT|w1T|w2T
// ---------------------------------------------------------------------------
extern "C" void kernel_launch(void* const* d_in, const int* in_sizes, int n_in,
                              void* d_out, int out_size, void* d_ws, size_t ws_size,
                              hipStream_t stream)
{
  (void)in_sizes; (void)n_in; (void)out_size;
  if (ws_size < 121667584ull) return;

  const float* pc    = (const float*)d_in[0];
  const float* pc2   = (const float*)d_in[1];
  const float* basis = (const float*)d_in[2];
  const float* pe_w  = (const float*)d_in[3];
  const float* pe_b  = (const float*)d_in[4];
  const float* lnq_g = (const float*)d_in[5];
  const float* lnq_b = (const float*)d_in[6];
  const float* lnc_g = (const float*)d_in[7];
  const float* lnc_b = (const float*)d_in[8];
  const float* wq    = (const float*)d_in[9];
  const float* wkv   = (const float*)d_in[10];
  const float* wo    = (const float*)d_in[11];
  const float* bo    = (const float*)d_in[12];
  const float* lnf_g = (const float*)d_in[13];
  const float* lnf_b = (const float*)d_in[14];
  const float* w1    = (const float*)d_in[15];
  const float* b1    = (const float*)d_in[16];
  const float* w2    = (const float*)d_in[17];
  const float* b2    = (const float*)d_in[18];
  float* xout = (float*)d_out;

  char* ws = (char*)d_ws;
  int* idxb   = (int*)(ws);
  bfu* emb_s  = (bfu*)(ws + 32768);
  bfu* q_in   = (bfu*)(ws + 25198592);
  bfu* c_grp  = (bfu*)(ws + 50364416);
  bfu* k_grp  = (bfu*)(ws + 62947328);
  bfu* v_grp  = (bfu*)(ws + 75530240);
  bfu* qbuf   = (bfu*)(ws + 88113152);
  bfu* wqT    = (bfu*)(ws + 113278976);
  bfu* wkvT   = (bfu*)(ws + 113803264);
  bfu* woT    = (bfu*)(ws + 114851840);
  bfu* w1T    = (bfu*)(ws + 115376128);
  bfu* w2T    = (bfu*)(ws + 119570432);
  bfu* scores  = c_grp;     // after c consumed by kv
  bfu* vT      = k_grp;     // after k consumed by scores
  bfu* attnout = q_in;      // after q GEMM consumed q_in
  bfu* lnx     = qbuf;      // after attention consumed q
  bfu* actb    = emb_s;     // spans emb_s+q_in (one MLP half at a time)

  // 0. weight transposes (fp32 [K][N] -> bf16 [N][K])
  transp_kernel<float><<<dim3(16, 16, 1),  256, 0, stream>>>(wq,  wqT,  512,  512, 0, 0);
  transp_kernel<float><<<dim3(32, 16, 1),  256, 0, stream>>>(wkv, wkvT, 512, 1024, 0, 0);
  transp_kernel<float><<<dim3(16, 16, 1),  256, 0, stream>>>(wo,  woT,  512,  512, 0, 0);
  transp_kernel<float><<<dim3(128, 16, 1), 256, 0, stream>>>(w1,  w1T,  512, 4096, 0, 0);
  transp_kernel<float><<<dim3(16, 64, 1),  256, 0, stream>>>(w2,  w2T, 2048,  512, 0, 0);

  // 1. FPS (1 wave per batch, LDS-resident coords, register dists)
  fps_kernel<<<NB, 64, 0, stream>>>(pc, idxb);

  // 2. latent embed -> emb_s (raw) + q_in (LN'd)
  embed_kernel<true, true><<<MROWS/16, 256, 0, stream>>>(
      pc, pc2, idxb, basis, pe_w, pe_b, lnq_g, lnq_b, emb_s, q_in, NLAT);

  // 3. q = q_in @ wq
  gemm_mfma<4, bfu, float, EPI_NONE><<<dim3(4, 192, 1), 256, 0, stream>>>(
      q_in, wqT, qbuf, nullptr, nullptr, nullptr, 1.0f,
      512, 512, 512, 512, 512, 0, 0, 0);

  // 4. per-group context pipeline (GRP=6, 8 groups)
  for (int g = 0; g < NGRP; ++g){
    const int bt0 = g * GRP;
    embed_kernel<false, false><<<GROWS/16, 256, 0, stream>>>(
        pc + (size_t)bt0 * NCTX * 3, pc2 + (size_t)bt0 * NCTX * 3, nullptr,
        basis, pe_w, pe_b, lnc_g, lnc_b, nullptr, c_grp, NCTX);

    // kv = c @ wkv -> split k | v
    gemm_mfma<4, bfu, float, EPI_SPLIT><<<dim3(8, 96, 1), 256, 0, stream>>>(
        c_grp, wkvT, k_grp, v_grp, nullptr, nullptr, 1.0f,
        1024, 512, 512, 512, 512, 0, 0, 0);

    // scores = (q @ k^T) * scale (overwrites c_grp region)
    gemm_mfma<4, bfu, float, EPI_SCALE><<<dim3(16, 4, GRP), 256, 0, stream>>>(
        qbuf + (size_t)bt0 * 262144, k_grp, scores, nullptr, nullptr, nullptr,
        0.044194173824159216f,
        2048, 512, 512, 512, 2048, 262144, 1048576, 1048576);

    softmax_kernel<<<GRP * 512, 256, 0, stream>>>(scores);

    // vT = transpose(v) per bt (overwrites k_grp; k dead after scores)
    transp_kernel<bfu><<<dim3(16, 64, GRP), 256, 0, stream>>>(
        v_grp, vT, 2048, 512, 2048*512, 2048*512);

    // attnout = P @ V : 64x64 tiles -> (8,8,GRP) blocks for occupancy
    gemm_mfma<2, bfu, float, EPI_NONE><<<dim3(8, 8, GRP), 256, 0, stream>>>(
        scores, vT, attnout + (size_t)bt0 * 262144, nullptr, nullptr, nullptr, 1.0f,
        512, 2048, 2048, 2048, 512, 1048576, 1048576, 262144);
  }

  // 5. x = attnout @ wo + bo + emb_s -> d_out (fp32)
  gemm_mfma<4, float, bfu, EPI_BIAS_RES><<<dim3(4, 192, 1), 256, 0, stream>>>(
      attnout, woT, xout, nullptr, bo, emb_s, 1.0f,
      512, 512, 512, 512, 512, 0, 0, 0);

  // 6. lnx = LN(x)
  ln_kernel<<<MROWS/4, 256, 0, stream>>>(xout, lnf_g, lnf_b, lnx);

  // 7/8. MLP in two row-halves (act buffer holds one half)
  for (int h = 0; h < 2; ++h){
    const size_t ro = (size_t)h * 12288;
    mlp1_mfma<<<dim3(16, 96, 1), 256, 0, stream>>>(
        lnx + ro * 512, w1T, b1, actb);
    gemm_mfma<4, float, float, EPI_BIAS_RES><<<dim3(4, 96, 1), 256, 0, stream>>>(
        actb, w2T, xout + ro * 512, nullptr, b2, xout + ro * 512, 1.0f,
        512, 2048, 2048, 2048, 512, 0, 0, 0);
  }
}

// Round 5
// 2122.642 us; speedup vs baseline: 1.0634x; 1.0068x over previous
//
#include <hip/hip_runtime.h>

// Problem constants
#define NB    16
#define NT    3
#define NCTX  2048
#define NLAT  512
#define DIMV  512
#define HALFD 256
#define NFEAT 51
#define NBT   48
#define MROWS 24576    // NBT*NLAT
#define GRP   6        // bt per context group
#define NGRP  8
#define GROWS 12288    // GRP*NCTX

typedef unsigned short bfu;   // bf16 storage as raw bits
typedef short bf16x8 __attribute__((ext_vector_type(8)));   // 8 bf16 = 4 VGPR
typedef float f32x4  __attribute__((ext_vector_type(4)));   // MFMA 16x16 acc
typedef float f32x2  __attribute__((ext_vector_type(2)));   // packed fp32 pair

__device__ __forceinline__ float bf2f(bfu u){ return __uint_as_float(((unsigned int)u) << 16); }
__device__ __forceinline__ bfu f2bf(float f){
  unsigned int u = __float_as_uint(f);
  u += 0x7FFFu + ((u >> 16) & 1u);          // RNE
  return (bfu)(u >> 16);
}
__device__ __forceinline__ float loadE(const float* p){ return *p; }
__device__ __forceinline__ float loadE(const bfu* p){ return bf2f(*p); }
__device__ __forceinline__ void storeE(float* p, float v){ *p = v; }
__device__ __forceinline__ void storeE(bfu* p, float v){ *p = f2bf(v); }
__device__ __forceinline__ bfu to_bfu(float f){ return f2bf(f); }
__device__ __forceinline__ bfu to_bfu(bfu u){ return u; }

// ---------------------------------------------------------------------------
// FPS: ONE wave per batch. Coords in LDS, running min-dists in registers.
// R4 theory: R3's per-step cost (2180cy) == ~16 serialized LDS round-trips:
// the scheduler can't hoist 32 ds_read_b128 (128 VGPRs payload > budget), so
// it emits read-wait-read-wait. Fix: EXPLICIT software pipeline in chunks of
// 8 slots with two named buffers (<=16 reads / 64 VGPRs in flight, inside
// the budget). lp broadcast issued first; LDS returns in-order, so waiting
// on chunk0 covers it. Buffers static-indexed after unroll (no scratch).
// Arithmetic (contract off, op order, fminf, 1e10f, tie-breaks) identical
// to the proven bit-exact version.
// ---------------------------------------------------------------------------
#define DPP_ARGMAX_STAGE(CTRL)                                                \
  {                                                                           \
    const int svb = __builtin_amdgcn_update_dpp(vb, vb, CTRL, 0xF, 0xF, false); \
    const int sib = __builtin_amdgcn_update_dpp(ib, ib, CTRL, 0xF, 0xF, false); \
    const float sv = __int_as_float(svb);                                     \
    const float cv = __int_as_float(vb);                                      \
    if (sv > cv || (sv == cv && sib < ib)){ vb = svb; ib = sib; }             \
  }

// load 8 consecutive slots (chunk CBASE) into BUF
#define FPS_LOAD(BUF, CBASE)                                                  \
  _Pragma("unroll")                                                           \
  for (int s = 0; s < 8; ++s) BUF[s] = pts[(((CBASE) * 8 + s) << 6) + lane];

// update d2 pairs j = JBASE..JBASE+3 from BUF (slots 2p, 2p+1)
#define FPS_COMP(BUF, JBASE)                                                  \
  _Pragma("unroll")                                                           \
  for (int p = 0; p < 4; ++p){                                                \
    const int j = (JBASE) + p;                                                \
    const float4 a0 = BUF[2 * p + 0];                                         \
    const float4 a1 = BUF[2 * p + 1];                                         \
    f32x2 xx; xx[0] = a0.x; xx[1] = a1.x;                                     \
    f32x2 yy; yy[0] = a0.y; yy[1] = a1.y;                                     \
    f32x2 zz; zz[0] = a0.z; zz[1] = a1.z;                                     \
    const f32x2 dx = xx - lp.x;                                               \
    const f32x2 dy = yy - lp.y;                                               \
    const f32x2 dz = zz - lp.z;                                               \
    const f32x2 dd = (dx * dx + dy * dy) + dz * dz;                           \
    f32x2 nd;                                                                 \
    nd[0] = fminf(d2[j][0], dd[0]);                                           \
    nd[1] = fminf(d2[j][1], dd[1]);                                           \
    d2[j] = nd;                                                               \
  }

__global__ __attribute__((amdgpu_waves_per_eu(1, 1)))
__launch_bounds__(64) void fps_kernel(const float* __restrict__ pc,
                                      int* __restrict__ idx_out){
#pragma clang fp contract(off)
  __shared__ float4 pts[NCTX];            // coords home + broadcast source
  const int lane = threadIdx.x;           // 0..63, single wave
  const int b = blockIdx.x;
  const float* src = pc + (size_t)b * (NT * NCTX * 3);

  // Slot s (0..31) = global point p = (s<<6)|lane. d2 pair j holds slots
  // 2j (lo) and 2j+1 (hi).
  f32x2 d2[16];
  #pragma unroll
  for (int j = 0; j < 16; ++j){
    #pragma unroll
    for (int h = 0; h < 2; ++h){
      const int p = ((2 * j + h) << 6) + lane;
      const float xx = src[p * 3 + 0];
      const float yy = src[p * 3 + 1];
      const float zz = src[p * 3 + 2];
      pts[p] = make_float4(xx, yy, zz, 0.f);
    }
    d2[j][0] = 1e10f; d2[j][1] = 1e10f;
  }
  if (lane == 0) idx_out[b * NLAT] = 0;
  __syncthreads();                        // drain LDS writes (single wave)

  int last = 0;
  for (int step = 1; step < NLAT; ++step){
    const float4 lp = pts[last];          // uniform addr; covered by chunk0 wait

    float4 bufA[8], bufB[8];
    FPS_LOAD(bufA, 0)                     // 8 reads in flight
    FPS_LOAD(bufB, 1)                     // 16 reads in flight
    FPS_COMP(bufA, 0)                     // wait chunk0 (lp + c1 outstanding)
    FPS_LOAD(bufA, 2)
    FPS_COMP(bufB, 4)
    FPS_LOAD(bufB, 3)
    FPS_COMP(bufA, 8)
    FPS_COMP(bufB, 12)

    // in-lane argmax over 32 slots, adjacent-pair tree.
    // Every merge is (left range) vs (right range) with all left slot
    // indices < all right slot indices, so strict > keeps the lowest index
    // on ties (numpy argmax semantics).
    float av[16]; int as_[16];
    #pragma unroll
    for (int j = 0; j < 16; ++j){
      const float lo = d2[j][0], hi = d2[j][1];
      const bool t = hi > lo;
      av[j]  = t ? hi : lo;
      as_[j] = t ? 2 * j + 1 : 2 * j;
    }
    #pragma unroll
    for (int wdt = 8; wdt; wdt >>= 1){
      #pragma unroll
      for (int j = 0; j < wdt; ++j){
        const float lv = av[2 * j], rv = av[2 * j + 1];
        const int   li = as_[2 * j], ri = as_[2 * j + 1];
        const bool t = rv > lv;
        av[j]  = t ? rv : lv;
        as_[j] = t ? ri : li;
      }
    }

    // cross-lane argmax on (value, global index); ties -> lower global index
    int vb = __float_as_int(av[0]);
    int ib = (as_[0] << 6) + lane;
    DPP_ARGMAX_STAGE(0x111)   // row_shr:1
    DPP_ARGMAX_STAGE(0x112)   // row_shr:2
    DPP_ARGMAX_STAGE(0x114)   // row_shr:4
    DPP_ARGMAX_STAGE(0x118)   // row_shr:8
    DPP_ARGMAX_STAGE(0x142)   // row_bcast:15
    DPP_ARGMAX_STAGE(0x143)   // row_bcast:31

    last = __builtin_amdgcn_readlane(ib, 63);   // lane 63 holds the winner
    if (lane == 0) idx_out[b * NLAT + step] = last;
  }
}

// ---------------------------------------------------------------------------
// Fused (gather) + point_embed x2 + layernorm -> bf16. 16 points / block.
// ---------------------------------------------------------------------------
template<bool GATHER, bool WRITE_EMB>
__global__ __launch_bounds__(256) void embed_kernel(
    const float* __restrict__ pc, const float* __restrict__ pc2,
    const int* __restrict__ idx,
    const float* __restrict__ basis, const float* __restrict__ pe_w,
    const float* __restrict__ pe_b,
    const float* __restrict__ ln_g, const float* __restrict__ ln_b,
    bfu* __restrict__ emb, bfu* __restrict__ lnout, int nppbt)
{
  __shared__ float feat[2][16][NFEAT + 1];
  __shared__ float outb[16][DIMV];
  const int tid = threadIdx.x;
  const int p0 = blockIdx.x << 4;

  if (tid < 32){
    const int s = tid >> 4, p = tid & 15;
    const int gp = p0 + p;
    const int bt = gp / nppbt;
    const int n  = gp - bt * nppbt;
    const int bb = bt / NT;
    const int srcn = GATHER ? idx[bb * NLAT + n] : n;
    const float* sp = (s ? pc2 : pc) + ((size_t)bt * NCTX + srcn) * 3;
    const float x0 = sp[0], x1 = sp[1], x2 = sp[2];
    #pragma unroll
    for (int e = 0; e < 24; ++e){
      const float pr = __fadd_rn(__fadd_rn(__fmul_rn(x0, basis[e]),
                                           __fmul_rn(x1, basis[24 + e])),
                                 __fmul_rn(x2, basis[48 + e]));
      feat[s][p][e]      = sinf(pr);
      feat[s][p][24 + e] = cosf(pr);
    }
    feat[s][p][48] = x0; feat[s][p][49] = x1; feat[s][p][50] = x2;
  }
  __syncthreads();

  {
    float w[NFEAT];
    #pragma unroll
    for (int k = 0; k < NFEAT; ++k) w[k] = pe_w[k * HALFD + tid];
    const float bv = pe_b[tid];
    #pragma unroll
    for (int half = 0; half < 2; ++half){
      for (int p = 0; p < 16; ++p){
        float acc = bv;
        #pragma unroll
        for (int k = 0; k < NFEAT; ++k) acc = fmaf(feat[half][p][k], w[k], acc);
        outb[p][half * HALFD + tid] = acc;
      }
    }
  }
  __syncthreads();

  const int lane = tid & 63, wv = tid >> 6;
  for (int pp = 0; pp < 4; ++pp){
    const int p = (wv << 2) + pp;
    const size_t gp = (size_t)p0 + p;
    float x[8];
    #pragma unroll
    for (int j = 0; j < 8; ++j) x[j] = outb[p][lane + (j << 6)];
    float s = 0.f;
    #pragma unroll
    for (int j = 0; j < 8; ++j) s += x[j];
    for (int o = 32; o; o >>= 1) s += __shfl_xor(s, o, 64);
    const float m = s * (1.0f / 512.0f);
    float s2 = 0.f;
    #pragma unroll
    for (int j = 0; j < 8; ++j){ const float d = x[j] - m; s2 = fmaf(d, d, s2); }
    for (int o = 32; o; o >>= 1) s2 += __shfl_xor(s2, o, 64);
    const float inv = 1.0f / sqrtf(s2 * (1.0f / 512.0f) + 1e-5f);
    #pragma unroll
    for (int j = 0; j < 8; ++j){
      const int c = lane + (j << 6);
      const float r = (x[j] - m) * inv * ln_g[c] + ln_b[c];
      const size_t o2 = gp * DIMV + c;
      if (WRITE_EMB) emb[o2] = f2bf(x[j]);
      lnout[o2] = f2bf(r);
    }
  }
}

// ---------------------------------------------------------------------------
// Tiled transpose: in [R][C] (fp32 or bf16) -> out bf16 [C][R]. 32x32 tiles.
// ---------------------------------------------------------------------------
template<typename TIN>
__global__ __launch_bounds__(256) void transp_kernel(
    const TIN* __restrict__ in, bfu* __restrict__ out, int R, int C,
    long long sIn, long long sOut)
{
  __shared__ bfu t[32][33];
  in  += (size_t)blockIdx.z * sIn;
  out += (size_t)blockIdx.z * sOut;
  const int c0 = blockIdx.x * 32, r0 = blockIdx.y * 32;
  const int tx = threadIdx.x & 31, ty = threadIdx.x >> 5;
  #pragma unroll
  for (int rr = ty; rr < 32; rr += 8)
    t[rr][tx] = to_bfu(in[(size_t)(r0 + rr) * C + c0 + tx]);
  __syncthreads();
  #pragma unroll
  for (int rr = ty; rr < 32; rr += 8)
    out[(size_t)(c0 + rr) * R + r0 + tx] = t[tx][rr];
}

// ---------------------------------------------------------------------------
// MFMA GEMM: C[M][N] = A[M][K] * B[N][K]^T, bf16 inputs.
// Tile = (FH*32) x (FH*32): FH=4 -> 128x128 (4x4 frags/wave), FH=2 -> 64x64
// (2x2 frags/wave, for low-M/N batched GEMMs needing block-count occupancy).
// 4 waves in 2x2 grid. LDS rows padded to 40 shorts (2-way max conflicts).
// ---------------------------------------------------------------------------
#define EPI_NONE     0
#define EPI_SPLIT    1
#define EPI_SCALE    2
#define EPI_BIAS_RES 3
#define LDST 40

template<int FH, typename TC, typename TR, int EPI>
__global__ __launch_bounds__(256, 2) void gemm_mfma(
    const bfu* __restrict__ A, const bfu* __restrict__ B,
    TC* __restrict__ C, TC* __restrict__ C2,
    const float* __restrict__ bias, const TR* __restrict__ res,
    float scale, int N, int K, int lda, int ldb, int ldc,
    long long sA, long long sB, long long sC)
{
  constexpr int BT = FH * 32;              // block tile edge
  const int bz = blockIdx.z;
  A += (size_t)bz * sA;
  B += (size_t)bz * sB;
  const size_t coff = (size_t)bz * sC;

  __shared__ __align__(16) short As[BT * LDST];
  __shared__ __align__(16) short Bs[BT * LDST];

  const int tid = threadIdx.x;
  const int lane = tid & 63, w = tid >> 6;
  const int m0 = blockIdx.y * BT, n0 = blockIdx.x * BT;
  const int wm = (w & 1) * (FH * 16), wn = (w >> 1) * (FH * 16);
  const int fr = lane & 15, quad = lane >> 4;

  f32x4 acc[FH][FH];
  #pragma unroll
  for (int i = 0; i < FH; ++i)
    #pragma unroll
    for (int j = 0; j < FH; ++j)
      #pragma unroll
      for (int r = 0; r < 4; ++r) acc[i][j][r] = 0.f;

  for (int k0 = 0; k0 < K; k0 += 32){
    #pragma unroll
    for (int ch = tid; ch < BT * 4; ch += 256){   // 16B chunks per tile
      const int r = ch >> 2, c = ch & 3;
      *(uint4*)&As[r * LDST + c * 8] =
          *(const uint4*)(A + (size_t)(m0 + r) * lda + k0 + c * 8);
      *(uint4*)&Bs[r * LDST + c * 8] =
          *(const uint4*)(B + (size_t)(n0 + r) * ldb + k0 + c * 8);
    }
    __syncthreads();
    bf16x8 af[FH], bf[FH];
    #pragma unroll
    for (int i = 0; i < FH; ++i)
      af[i] = *(const bf16x8*)&As[(wm + i * 16 + fr) * LDST + quad * 8];
    #pragma unroll
    for (int j = 0; j < FH; ++j)
      bf[j] = *(const bf16x8*)&Bs[(wn + j * 16 + fr) * LDST + quad * 8];
    #pragma unroll
    for (int i = 0; i < FH; ++i)
      #pragma unroll
      for (int j = 0; j < FH; ++j)
        acc[i][j] = __builtin_amdgcn_mfma_f32_16x16x32_bf16(af[i], bf[j], acc[i][j], 0, 0, 0);
    __syncthreads();
  }

  // C/D layout: col = lane&15, row = quad*4 + reg
  TC* Cp = C + coff;
  #pragma unroll
  for (int i = 0; i < FH; ++i){
    #pragma unroll
    for (int r = 0; r < 4; ++r){
      const int cm = m0 + wm + i * 16 + quad * 4 + r;
      #pragma unroll
      for (int j = 0; j < FH; ++j){
        const int cn = n0 + wn + j * 16 + fr;
        float v = acc[i][j][r];
        if (EPI == EPI_SCALE)    v *= scale;
        if (EPI == EPI_BIAS_RES) v = v + bias[cn] + loadE(&res[coff + (size_t)cm * ldc + cn]);
        if (EPI == EPI_SPLIT){
          const int half = N >> 1;
          if (cn < half) storeE(&C [(size_t)cm * half + cn],          v);
          else           storeE(&C2[(size_t)cm * half + (cn - half)], v);
        } else {
          storeE(&Cp[(size_t)cm * ldc + cn], v);
        }
      }
    }
  }
}

// ---------------------------------------------------------------------------
// Fused MLP1 + exact GeLU (MFMA): act = (A@w1T[a]+b1a) * gelu(A@w1T[g]+b1g).
// ---------------------------------------------------------------------------
__global__ __launch_bounds__(256, 1) void mlp1_mfma(
    const bfu* __restrict__ A, const bfu* __restrict__ B,  // B = w1T [4096][512]
    const float* __restrict__ b1, bfu* __restrict__ act)
{
  __shared__ __align__(16) short As[128 * LDST];
  __shared__ __align__(16) short Ba[128 * LDST];
  __shared__ __align__(16) short Bg[128 * LDST];

  const int tid = threadIdx.x;
  const int lane = tid & 63, w = tid >> 6;
  const int m0 = blockIdx.y * 128, n0 = blockIdx.x * 128;
  const int wm = (w & 1) * 64, wn = (w >> 1) * 64;
  const int fr = lane & 15, quad = lane >> 4;

  f32x4 acca[4][4], accg[4][4];
  #pragma unroll
  for (int i = 0; i < 4; ++i)
    #pragma unroll
    for (int j = 0; j < 4; ++j)
      #pragma unroll
      for (int r = 0; r < 4; ++r){ acca[i][j][r] = 0.f; accg[i][j][r] = 0.f; }

  for (int k0 = 0; k0 < 512; k0 += 32){
    #pragma unroll
    for (int i = 0; i < 2; ++i){
      const int ch = tid + 256 * i;
      const int r = ch >> 2, c = ch & 3;
      *(uint4*)&As[r * LDST + c * 8] =
          *(const uint4*)(A + (size_t)(m0 + r) * 512 + k0 + c * 8);
      *(uint4*)&Ba[r * LDST + c * 8] =
          *(const uint4*)(B + (size_t)(n0 + r) * 512 + k0 + c * 8);
      *(uint4*)&Bg[r * LDST + c * 8] =
          *(const uint4*)(B + (size_t)(n0 + 2048 + r) * 512 + k0 + c * 8);
    }
    __syncthreads();
    bf16x8 af[4], ba[4], bg[4];
    #pragma unroll
    for (int i = 0; i < 4; ++i)
      af[i] = *(const bf16x8*)&As[(wm + i * 16 + fr) * LDST + quad * 8];
    #pragma unroll
    for (int j = 0; j < 4; ++j){
      ba[j] = *(const bf16x8*)&Ba[(wn + j * 16 + fr) * LDST + quad * 8];
      bg[j] = *(const bf16x8*)&Bg[(wn + j * 16 + fr) * LDST + quad * 8];
    }
    #pragma unroll
    for (int i = 0; i < 4; ++i)
      #pragma unroll
      for (int j = 0; j < 4; ++j){
        acca[i][j] = __builtin_amdgcn_mfma_f32_16x16x32_bf16(af[i], ba[j], acca[i][j], 0, 0, 0);
        accg[i][j] = __builtin_amdgcn_mfma_f32_16x16x32_bf16(af[i], bg[j], accg[i][j], 0, 0, 0);
      }
    __syncthreads();
  }

  #pragma unroll
  for (int i = 0; i < 4; ++i){
    #pragma unroll
    for (int r = 0; r < 4; ++r){
      const int cm = m0 + wm + i * 16 + quad * 4 + r;
      #pragma unroll
      for (int j = 0; j < 4; ++j){
        const int cn = n0 + wn + j * 16 + fr;
        const float a = acca[i][j][r] + b1[cn];
        const float g = accg[i][j][r] + b1[cn + 2048];
        const float ge = g * 0.5f * (1.0f + erff(g * 0.70710678118654752f));
        act[(size_t)cm * 2048 + cn] = f2bf(a * ge);
      }
    }
  }
}

// ---------------------------------------------------------------------------
// Row softmax over 2048 bf16 logits, in place.
// ---------------------------------------------------------------------------
__global__ __launch_bounds__(256) void softmax_kernel(bfu* __restrict__ sc){
  __shared__ float red[4];
  const int tid = threadIdx.x;
  const int lane = tid & 63, wv = tid >> 6;
  bfu* rp = sc + (size_t)blockIdx.x * NCTX;
  float x[8];
  #pragma unroll
  for (int j = 0; j < 8; ++j) x[j] = bf2f(rp[tid + (j << 8)]);
  float mx = x[0];
  #pragma unroll
  for (int j = 1; j < 8; ++j) mx = fmaxf(mx, x[j]);
  for (int o = 32; o; o >>= 1) mx = fmaxf(mx, __shfl_xor(mx, o, 64));
  if (lane == 0) red[wv] = mx;
  __syncthreads();
  mx = fmaxf(fmaxf(red[0], red[1]), fmaxf(red[2], red[3]));
  float sum = 0.f;
  #pragma unroll
  for (int j = 0; j < 8; ++j){ x[j] = __expf(x[j] - mx); sum += x[j]; }
  for (int o = 32; o; o >>= 1) sum += __shfl_xor(sum, o, 64);
  __syncthreads();
  if (lane == 0) red[wv] = sum;
  __syncthreads();
  sum = red[0] + red[1] + red[2] + red[3];
  const float inv = 1.0f / sum;
  #pragma unroll
  for (int j = 0; j < 8; ++j) rp[tid + (j << 8)] = f2bf(x[j] * inv);
}

// ---------------------------------------------------------------------------
// LayerNorm rows of 512 fp32 -> bf16.
// ---------------------------------------------------------------------------
__global__ __launch_bounds__(256) void ln_kernel(const float* __restrict__ in,
                                                 const float* __restrict__ g,
                                                 const float* __restrict__ b,
                                                 bfu* __restrict__ out){
  const int tid = threadIdx.x, lane = tid & 63, wv = tid >> 6;
  const size_t row = (size_t)blockIdx.x * 4 + wv;
  const float* rp = in + row * DIMV;
  float x[8];
  #pragma unroll
  for (int j = 0; j < 8; ++j) x[j] = rp[lane + (j << 6)];
  float s = 0.f;
  #pragma unroll
  for (int j = 0; j < 8; ++j) s += x[j];
  for (int o = 32; o; o >>= 1) s += __shfl_xor(s, o, 64);
  const float m = s * (1.0f / 512.0f);
  float s2 = 0.f;
  #pragma unroll
  for (int j = 0; j < 8; ++j){ const float d = x[j] - m; s2 = fmaf(d, d, s2); }
  for (int o = 32; o; o >>= 1) s2 += __shfl_xor(s2, o, 64);
  const float inv = 1.0f / sqrtf(s2 * (1.0f / 512.0f) + 1e-5f);
  bfu* op = out + row * DIMV;
  #pragma unroll
  for (int j = 0; j < 8; ++j){
    const int c = lane + (j << 6);
    op[c] = f2bf((x[j] - m) * inv * g[c] + b[c]);
  }
}

// ---------------------------------------------------------------------------
// Workspace (peak 121,667,584 B < proven 125,861,888):
//   idx    @ 0          (32 KB)
//   emb_s  @ 32768      (25,165,824) \  act half (50,331,648) aliases
//   q_in   @ 25198592   (25,165,824) /  emb_s+q_in (both dead at MLP)
//          q_in -> attnout after q GEMM
//   c_grp  @ 50364416   (12,582,912) -> scores (GRP=6)
//   k_grp  @ 62947328   (12,582,912) -> vT (k dead after scores; group loop
//                                          order: ...scores, softmax, transp, pv)
//   v_grp  @ 75530240   (12,582,912)
//   qbuf   @ 88113152   (25,165,824) -> lnx
//   wT     @ 113278976  (8,388,608): wqT|wkvT|woT|w1T|w2T
// ---------------------------------------------------------------------------
extern "C" void kernel_launch(void* const* d_in, const int* in_sizes, int n_in,
                              void* d_out, int out_size, void* d_ws, size_t ws_size,
                              hipStream_t stream)
{
  (void)in_sizes; (void)n_in; (void)out_size;
  if (ws_size < 121667584ull) return;

  const float* pc    = (const float*)d_in[0];
  const float* pc2   = (const float*)d_in[1];
  const float* basis = (const float*)d_in[2];
  const float* pe_w  = (const float*)d_in[3];
  const float* pe_b  = (const float*)d_in[4];
  const float* lnq_g = (const float*)d_in[5];
  const float* lnq_b = (const float*)d_in[6];
  const float* lnc_g = (const float*)d_in[7];
  const float* lnc_b = (const float*)d_in[8];
  const float* wq    = (const float*)d_in[9];
  const float* wkv   = (const float*)d_in[10];
  const float* wo    = (const float*)d_in[11];
  const float* bo    = (const float*)d_in[12];
  const float* lnf_g = (const float*)d_in[13];
  const float* lnf_b = (const float*)d_in[14];
  const float* w1    = (const float*)d_in[15];
  const float* b1    = (const float*)d_in[16];
  const float* w2    = (const float*)d_in[17];
  const float* b2    = (const float*)d_in[18];
  float* xout = (float*)d_out;

  char* ws = (char*)d_ws;
  int* idxb   = (int*)(ws);
  bfu* emb_s  = (bfu*)(ws + 32768);
  bfu* q_in   = (bfu*)(ws + 25198592);
  bfu* c_grp  = (bfu*)(ws + 50364416);
  bfu* k_grp  = (bfu*)(ws + 62947328);
  bfu* v_grp  = (bfu*)(ws + 75530240);
  bfu* qbuf   = (bfu*)(ws + 88113152);
  bfu* wqT    = (bfu*)(ws + 113278976);
  bfu* wkvT   = (bfu*)(ws + 113803264);
  bfu* woT    = (bfu*)(ws + 114851840);
  bfu* w1T    = (bfu*)(ws + 115376128);
  bfu* w2T    = (bfu*)(ws + 119570432);
  bfu* scores  = c_grp;     // after c consumed by kv
  bfu* vT      = k_grp;     // after k consumed by scores
  bfu* attnout = q_in;      // after q GEMM consumed q_in
  bfu* lnx     = qbuf;      // after attention consumed q
  bfu* actb    = emb_s;     // spans emb_s+q_in (one MLP half at a time)

  // 0. weight transposes (fp32 [K][N] -> bf16 [N][K])
  transp_kernel<float><<<dim3(16, 16, 1),  256, 0, stream>>>(wq,  wqT,  512,  512, 0, 0);
  transp_kernel<float><<<dim3(32, 16, 1),  256, 0, stream>>>(wkv, wkvT, 512, 1024, 0, 0);
  transp_kernel<float><<<dim3(16, 16, 1),  256, 0, stream>>>(wo,  woT,  512,  512, 0, 0);
  transp_kernel<float><<<dim3(128, 16, 1), 256, 0, stream>>>(w1,  w1T,  512, 4096, 0, 0);
  transp_kernel<float><<<dim3(16, 64, 1),  256, 0, stream>>>(w2,  w2T, 2048,  512, 0, 0);

  // 1. FPS (1 wave per batch, LDS coords, software-pipelined chunk loads)
  fps_kernel<<<NB, 64, 0, stream>>>(pc, idxb);

  // 2. latent embed -> emb_s (raw) + q_in (LN'd)
  embed_kernel<true, true><<<MROWS/16, 256, 0, stream>>>(
      pc, pc2, idxb, basis, pe_w, pe_b, lnq_g, lnq_b, emb_s, q_in, NLAT);

  // 3. q = q_in @ wq
  gemm_mfma<4, bfu, float, EPI_NONE><<<dim3(4, 192, 1), 256, 0, stream>>>(
      q_in, wqT, qbuf, nullptr, nullptr, nullptr, 1.0f,
      512, 512, 512, 512, 512, 0, 0, 0);

  // 4. per-group context pipeline (GRP=6, 8 groups)
  for (int g = 0; g < NGRP; ++g){
    const int bt0 = g * GRP;
    embed_kernel<false, false><<<GROWS/16, 256, 0, stream>>>(
        pc + (size_t)bt0 * NCTX * 3, pc2 + (size_t)bt0 * NCTX * 3, nullptr,
        basis, pe_w, pe_b, lnc_g, lnc_b, nullptr, c_grp, NCTX);

    // kv = c @ wkv -> split k | v
    gemm_mfma<4, bfu, float, EPI_SPLIT><<<dim3(8, 96, 1), 256, 0, stream>>>(
        c_grp, wkvT, k_grp, v_grp, nullptr, nullptr, 1.0f,
        1024, 512, 512, 512, 512, 0, 0, 0);

    // scores = (q @ k^T) * scale (overwrites c_grp region)
    gemm_mfma<4, bfu, float, EPI_SCALE><<<dim3(16, 4, GRP), 256, 0, stream>>>(
        qbuf + (size_t)bt0 * 262144, k_grp, scores, nullptr, nullptr, nullptr,
        0.044194173824159216f,
        2048, 512, 512, 512, 2048, 262144, 1048576, 1048576);

    softmax_kernel<<<GRP * 512, 256, 0, stream>>>(scores);

    // vT = transpose(v) per bt (overwrites k_grp; k dead after scores)
    transp_kernel<bfu><<<dim3(16, 64, GRP), 256, 0, stream>>>(
        v_grp, vT, 2048, 512, 2048*512, 2048*512);

    // attnout = P @ V : 64x64 tiles -> (8,8,GRP) blocks for occupancy
    gemm_mfma<2, bfu, float, EPI_NONE><<<dim3(8, 8, GRP), 256, 0, stream>>>(
        scores, vT, attnout + (size_t)bt0 * 262144, nullptr, nullptr, nullptr, 1.0f,
        512, 2048, 2048, 2048, 512, 1048576, 1048576, 262144);
  }

  // 5. x = attnout @ wo + bo + emb_s -> d_out (fp32)
  gemm_mfma<4, float, bfu, EPI_BIAS_RES><<<dim3(4, 192, 1), 256, 0, stream>>>(
      attnout, woT, xout, nullptr, bo, emb_s, 1.0f,
      512, 512, 512, 512, 512, 0, 0, 0);

  // 6. lnx = LN(x)
  ln_kernel<<<MROWS/4, 256, 0, stream>>>(xout, lnf_g, lnf_b, lnx);

  // 7/8. MLP in two row-halves (act buffer holds one half)
  for (int h = 0; h < 2; ++h){
    const size_t ro = (size_t)h * 12288;
    mlp1_mfma<<<dim3(16, 96, 1), 256, 0, stream>>>(
        lnx + ro * 512, w1T, b1, actb);
    gemm_mfma<4, float, float, EPI_BIAS_RES><<<dim3(4, 96, 1), 256, 0, stream>>>(
        actb, w2T, xout + ro * 512, nullptr, b2, xout + ro * 512, 1.0f,
        512, 2048, 2048, 2048, 512, 0, 0, 0);
  }
}

// Round 6
// 2063.237 us; speedup vs baseline: 1.0940x; 1.0288x over previous
//
#include <hip/hip_runtime.h>

// Problem constants
#define NB    16
#define NT    3
#define NCTX  2048
#define NLAT  512
#define DIMV  512
#define HALFD 256
#define NFEAT 51
#define NBT   48
#define MROWS 24576    // NBT*NLAT
#define GRP   6        // bt per context group
#define NGRP  8
#define GROWS 12288    // GRP*NCTX

typedef unsigned short bfu;   // bf16 storage as raw bits
typedef short bf16x8 __attribute__((ext_vector_type(8)));   // 8 bf16 = 4 VGPR
typedef float f32x4  __attribute__((ext_vector_type(4)));   // MFMA 16x16 acc
typedef float f32x2  __attribute__((ext_vector_type(2)));   // packed fp32 pair

__device__ __forceinline__ float bf2f(bfu u){ return __uint_as_float(((unsigned int)u) << 16); }
__device__ __forceinline__ bfu f2bf(float f){
  unsigned int u = __float_as_uint(f);
  u += 0x7FFFu + ((u >> 16) & 1u);          // RNE
  return (bfu)(u >> 16);
}
__device__ __forceinline__ float loadE(const float* p){ return *p; }
__device__ __forceinline__ float loadE(const bfu* p){ return bf2f(*p); }
__device__ __forceinline__ void storeE(float* p, float v){ *p = v; }
__device__ __forceinline__ void storeE(bfu* p, float v){ *p = f2bf(v); }
__device__ __forceinline__ bfu to_bfu(float f){ return f2bf(f); }
__device__ __forceinline__ bfu to_bfu(bfu u){ return u; }

// ---------------------------------------------------------------------------
// FPS: TWO waves per batch, coords REGISTER-resident (1024 pts/wave = 48
// VGPRs coords + 16 d2 -- fits the ~132-VGPR budget the allocator actually
// grants, unlike the 1-wave/32-slot layout which needs >=160 and silently
// spills/serializes; R1-R5 all measured ~2130cy/step == ~16 serialized
// memory round-trips regardless of scratch/LDS placement).
// Per step only TWO LDS transactions sit on the critical path:
//   pts[last] float4 broadcast + 16B cross-wave merge read.
// Dist update is pure packed VALU on registers. Cross-wave merge: lane-63
// writes (v,idx) 8B, ONE s_barrier (parity double-buffer avoids the second
// barrier), int4 broadcast read, 1 select.
// Point p = (w<<10)|(s<<6)|lane. In-lane tree merges index-ordered ranges
// (strict > keeps lowest index on ties); DPP comparator carries global idx
// (tie -> lower); cross-wave strict > prefers wave0 (all smaller indices):
// numpy first-max semantics exactly. Distance expression, contract(off),
// fminf, 1e10f identical to the proven bit-exact version.
// ---------------------------------------------------------------------------
#define DPP_ARGMAX_STAGE(CTRL)                                                \
  {                                                                           \
    const int svb = __builtin_amdgcn_update_dpp(vb, vb, CTRL, 0xF, 0xF, false); \
    const int sib = __builtin_amdgcn_update_dpp(ib, ib, CTRL, 0xF, 0xF, false); \
    const float sv = __int_as_float(svb);                                     \
    const float cv = __int_as_float(vb);                                      \
    if (sv > cv || (sv == cv && sib < ib)){ vb = svb; ib = sib; }             \
  }

__global__ __attribute__((amdgpu_waves_per_eu(1, 1)))
__launch_bounds__(128) void fps_kernel(const float* __restrict__ pc,
                                       int* __restrict__ idx_out){
#pragma clang fp contract(off)
  __shared__ float4 pts[NCTX];            // broadcast table for "last" coords
  __shared__ __align__(16) int mbuf[2][4];// [parity][w*2 + {v,idx}]
  const int tid = threadIdx.x;
  const int lane = tid & 63, w = tid >> 6;
  const int wbase = w << 10;              // wave owns [1024w, 1024w+1024)
  const int b = blockIdx.x;
  const float* src = pc + (size_t)b * (NT * NCTX * 3);

  // Slot s (0..15) = point p = wbase + (s<<6) + lane. Coords + running
  // min-dists all register-resident; pair j holds slots 2j (lo), 2j+1 (hi).
  f32x2 x2[8], y2[8], z2[8], d2[8];
  #pragma unroll
  for (int j = 0; j < 8; ++j){
    #pragma unroll
    for (int h = 0; h < 2; ++h){
      const int p = wbase + ((2 * j + h) << 6) + lane;
      const float xx = src[p * 3 + 0];
      const float yy = src[p * 3 + 1];
      const float zz = src[p * 3 + 2];
      x2[j][h] = xx; y2[j][h] = yy; z2[j][h] = zz;
      pts[p] = make_float4(xx, yy, zz, 0.f);
    }
    d2[j][0] = 1e10f; d2[j][1] = 1e10f;
  }
  if (tid == 0) idx_out[b * NLAT] = 0;
  __syncthreads();                        // pts table ready

  int last = 0;
  for (int step = 1; step < NLAT; ++step){
    const float4 lp = pts[last];          // uniform addr -> LDS broadcast

    // distance update: pure packed VALU, identical op order to the proven
    // bit-exact version.
    #pragma unroll
    for (int j = 0; j < 8; ++j){
      const f32x2 dx = x2[j] - lp.x;
      const f32x2 dy = y2[j] - lp.y;
      const f32x2 dz = z2[j] - lp.z;
      const f32x2 dd = (dx * dx + dy * dy) + dz * dz;
      f32x2 nd;
      nd[0] = fminf(d2[j][0], dd[0]);
      nd[1] = fminf(d2[j][1], dd[1]);
      d2[j] = nd;
    }

    // in-lane argmax over 16 slots, adjacent-pair tree (index-ordered
    // merges: strict > keeps the lowest index on ties).
    float av[8]; int as_[8];
    #pragma unroll
    for (int j = 0; j < 8; ++j){
      const float lo = d2[j][0], hi = d2[j][1];
      const bool t = hi > lo;
      av[j]  = t ? hi : lo;
      as_[j] = t ? 2 * j + 1 : 2 * j;
    }
    #pragma unroll
    for (int wdt = 4; wdt; wdt >>= 1){
      #pragma unroll
      for (int j = 0; j < wdt; ++j){
        const float lv = av[2 * j], rv = av[2 * j + 1];
        const int   li = as_[2 * j], ri = as_[2 * j + 1];
        const bool t = rv > lv;
        av[j]  = t ? rv : lv;
        as_[j] = t ? ri : li;
      }
    }

    // cross-lane argmax on (value, GLOBAL index); ties -> lower index
    int vb = __float_as_int(av[0]);
    int ib = wbase + (as_[0] << 6) + lane;
    DPP_ARGMAX_STAGE(0x111)   // row_shr:1
    DPP_ARGMAX_STAGE(0x112)   // row_shr:2
    DPP_ARGMAX_STAGE(0x114)   // row_shr:4
    DPP_ARGMAX_STAGE(0x118)   // row_shr:8
    DPP_ARGMAX_STAGE(0x142)   // row_bcast:15
    DPP_ARGMAX_STAGE(0x143)   // row_bcast:31

    // cross-wave merge: 8B write (lane 63), one barrier, 16B broadcast read.
    // Parity buffer -> no second barrier needed (writes of step k+1 go to
    // the other 16B region, cannot clobber step k's values).
    const int par = step & 1;
    if (lane == 63){ mbuf[par][w * 2] = vb; mbuf[par][w * 2 + 1] = ib; }
    __syncthreads();
    const int4 q = *(const int4*)&mbuf[par][0];
    const float f0 = __int_as_float(q.x), f1 = __int_as_float(q.z);
    last = (f1 > f0) ? q.w : q.y;         // wave0 indices all smaller: strict >
    if (tid == 0) idx_out[b * NLAT + step] = last;
  }
}

// ---------------------------------------------------------------------------
// Fused (gather) + point_embed x2 + layernorm -> bf16. 16 points / block.
// ---------------------------------------------------------------------------
template<bool GATHER, bool WRITE_EMB>
__global__ __launch_bounds__(256) void embed_kernel(
    const float* __restrict__ pc, const float* __restrict__ pc2,
    const int* __restrict__ idx,
    const float* __restrict__ basis, const float* __restrict__ pe_w,
    const float* __restrict__ pe_b,
    const float* __restrict__ ln_g, const float* __restrict__ ln_b,
    bfu* __restrict__ emb, bfu* __restrict__ lnout, int nppbt)
{
  __shared__ float feat[2][16][NFEAT + 1];
  __shared__ float outb[16][DIMV];
  const int tid = threadIdx.x;
  const int p0 = blockIdx.x << 4;

  if (tid < 32){
    const int s = tid >> 4, p = tid & 15;
    const int gp = p0 + p;
    const int bt = gp / nppbt;
    const int n  = gp - bt * nppbt;
    const int bb = bt / NT;
    const int srcn = GATHER ? idx[bb * NLAT + n] : n;
    const float* sp = (s ? pc2 : pc) + ((size_t)bt * NCTX + srcn) * 3;
    const float x0 = sp[0], x1 = sp[1], x2 = sp[2];
    #pragma unroll
    for (int e = 0; e < 24; ++e){
      const float pr = __fadd_rn(__fadd_rn(__fmul_rn(x0, basis[e]),
                                           __fmul_rn(x1, basis[24 + e])),
                                 __fmul_rn(x2, basis[48 + e]));
      feat[s][p][e]      = sinf(pr);
      feat[s][p][24 + e] = cosf(pr);
    }
    feat[s][p][48] = x0; feat[s][p][49] = x1; feat[s][p][50] = x2;
  }
  __syncthreads();

  {
    float w[NFEAT];
    #pragma unroll
    for (int k = 0; k < NFEAT; ++k) w[k] = pe_w[k * HALFD + tid];
    const float bv = pe_b[tid];
    #pragma unroll
    for (int half = 0; half < 2; ++half){
      for (int p = 0; p < 16; ++p){
        float acc = bv;
        #pragma unroll
        for (int k = 0; k < NFEAT; ++k) acc = fmaf(feat[half][p][k], w[k], acc);
        outb[p][half * HALFD + tid] = acc;
      }
    }
  }
  __syncthreads();

  const int lane = tid & 63, wv = tid >> 6;
  for (int pp = 0; pp < 4; ++pp){
    const int p = (wv << 2) + pp;
    const size_t gp = (size_t)p0 + p;
    float x[8];
    #pragma unroll
    for (int j = 0; j < 8; ++j) x[j] = outb[p][lane + (j << 6)];
    float s = 0.f;
    #pragma unroll
    for (int j = 0; j < 8; ++j) s += x[j];
    for (int o = 32; o; o >>= 1) s += __shfl_xor(s, o, 64);
    const float m = s * (1.0f / 512.0f);
    float s2 = 0.f;
    #pragma unroll
    for (int j = 0; j < 8; ++j){ const float d = x[j] - m; s2 = fmaf(d, d, s2); }
    for (int o = 32; o; o >>= 1) s2 += __shfl_xor(s2, o, 64);
    const float inv = 1.0f / sqrtf(s2 * (1.0f / 512.0f) + 1e-5f);
    #pragma unroll
    for (int j = 0; j < 8; ++j){
      const int c = lane + (j << 6);
      const float r = (x[j] - m) * inv * ln_g[c] + ln_b[c];
      const size_t o2 = gp * DIMV + c;
      if (WRITE_EMB) emb[o2] = f2bf(x[j]);
      lnout[o2] = f2bf(r);
    }
  }
}

// ---------------------------------------------------------------------------
// Tiled transpose: in [R][C] (fp32 or bf16) -> out bf16 [C][R]. 32x32 tiles.
// ---------------------------------------------------------------------------
template<typename TIN>
__global__ __launch_bounds__(256) void transp_kernel(
    const TIN* __restrict__ in, bfu* __restrict__ out, int R, int C,
    long long sIn, long long sOut)
{
  __shared__ bfu t[32][33];
  in  += (size_t)blockIdx.z * sIn;
  out += (size_t)blockIdx.z * sOut;
  const int c0 = blockIdx.x * 32, r0 = blockIdx.y * 32;
  const int tx = threadIdx.x & 31, ty = threadIdx.x >> 5;
  #pragma unroll
  for (int rr = ty; rr < 32; rr += 8)
    t[rr][tx] = to_bfu(in[(size_t)(r0 + rr) * C + c0 + tx]);
  __syncthreads();
  #pragma unroll
  for (int rr = ty; rr < 32; rr += 8)
    out[(size_t)(c0 + rr) * R + r0 + tx] = t[tx][rr];
}

// ---------------------------------------------------------------------------
// MFMA GEMM: C[M][N] = A[M][K] * B[N][K]^T, bf16 inputs.
// Tile = (FH*32) x (FH*32): FH=4 -> 128x128 (4x4 frags/wave), FH=2 -> 64x64
// (2x2 frags/wave, for low-M/N batched GEMMs needing block-count occupancy).
// 4 waves in 2x2 grid. LDS rows padded to 40 shorts (2-way max conflicts).
// ---------------------------------------------------------------------------
#define EPI_NONE     0
#define EPI_SPLIT    1
#define EPI_SCALE    2
#define EPI_BIAS_RES 3
#define LDST 40

template<int FH, typename TC, typename TR, int EPI>
__global__ __launch_bounds__(256, 2) void gemm_mfma(
    const bfu* __restrict__ A, const bfu* __restrict__ B,
    TC* __restrict__ C, TC* __restrict__ C2,
    const float* __restrict__ bias, const TR* __restrict__ res,
    float scale, int N, int K, int lda, int ldb, int ldc,
    long long sA, long long sB, long long sC)
{
  constexpr int BT = FH * 32;              // block tile edge
  const int bz = blockIdx.z;
  A += (size_t)bz * sA;
  B += (size_t)bz * sB;
  const size_t coff = (size_t)bz * sC;

  __shared__ __align__(16) short As[BT * LDST];
  __shared__ __align__(16) short Bs[BT * LDST];

  const int tid = threadIdx.x;
  const int lane = tid & 63, w = tid >> 6;
  const int m0 = blockIdx.y * BT, n0 = blockIdx.x * BT;
  const int wm = (w & 1) * (FH * 16), wn = (w >> 1) * (FH * 16);
  const int fr = lane & 15, quad = lane >> 4;

  f32x4 acc[FH][FH];
  #pragma unroll
  for (int i = 0; i < FH; ++i)
    #pragma unroll
    for (int j = 0; j < FH; ++j)
      #pragma unroll
      for (int r = 0; r < 4; ++r) acc[i][j][r] = 0.f;

  for (int k0 = 0; k0 < K; k0 += 32){
    #pragma unroll
    for (int ch = tid; ch < BT * 4; ch += 256){   // 16B chunks per tile
      const int r = ch >> 2, c = ch & 3;
      *(uint4*)&As[r * LDST + c * 8] =
          *(const uint4*)(A + (size_t)(m0 + r) * lda + k0 + c * 8);
      *(uint4*)&Bs[r * LDST + c * 8] =
          *(const uint4*)(B + (size_t)(n0 + r) * ldb + k0 + c * 8);
    }
    __syncthreads();
    bf16x8 af[FH], bf[FH];
    #pragma unroll
    for (int i = 0; i < FH; ++i)
      af[i] = *(const bf16x8*)&As[(wm + i * 16 + fr) * LDST + quad * 8];
    #pragma unroll
    for (int j = 0; j < FH; ++j)
      bf[j] = *(const bf16x8*)&Bs[(wn + j * 16 + fr) * LDST + quad * 8];
    #pragma unroll
    for (int i = 0; i < FH; ++i)
      #pragma unroll
      for (int j = 0; j < FH; ++j)
        acc[i][j] = __builtin_amdgcn_mfma_f32_16x16x32_bf16(af[i], bf[j], acc[i][j], 0, 0, 0);
    __syncthreads();
  }

  // C/D layout: col = lane&15, row = quad*4 + reg
  TC* Cp = C + coff;
  #pragma unroll
  for (int i = 0; i < FH; ++i){
    #pragma unroll
    for (int r = 0; r < 4; ++r){
      const int cm = m0 + wm + i * 16 + quad * 4 + r;
      #pragma unroll
      for (int j = 0; j < FH; ++j){
        const int cn = n0 + wn + j * 16 + fr;
        float v = acc[i][j][r];
        if (EPI == EPI_SCALE)    v *= scale;
        if (EPI == EPI_BIAS_RES) v = v + bias[cn] + loadE(&res[coff + (size_t)cm * ldc + cn]);
        if (EPI == EPI_SPLIT){
          const int half = N >> 1;
          if (cn < half) storeE(&C [(size_t)cm * half + cn],          v);
          else           storeE(&C2[(size_t)cm * half + (cn - half)], v);
        } else {
          storeE(&Cp[(size_t)cm * ldc + cn], v);
        }
      }
    }
  }
}

// ---------------------------------------------------------------------------
// Fused MLP1 + exact GeLU (MFMA): act = (A@w1T[a]+b1a) * gelu(A@w1T[g]+b1g).
// ---------------------------------------------------------------------------
__global__ __launch_bounds__(256, 1) void mlp1_mfma(
    const bfu* __restrict__ A, const bfu* __restrict__ B,  // B = w1T [4096][512]
    const float* __restrict__ b1, bfu* __restrict__ act)
{
  __shared__ __align__(16) short As[128 * LDST];
  __shared__ __align__(16) short Ba[128 * LDST];
  __shared__ __align__(16) short Bg[128 * LDST];

  const int tid = threadIdx.x;
  const int lane = tid & 63, w = tid >> 6;
  const int m0 = blockIdx.y * 128, n0 = blockIdx.x * 128;
  const int wm = (w & 1) * 64, wn = (w >> 1) * 64;
  const int fr = lane & 15, quad = lane >> 4;

  f32x4 acca[4][4], accg[4][4];
  #pragma unroll
  for (int i = 0; i < 4; ++i)
    #pragma unroll
    for (int j = 0; j < 4; ++j)
      #pragma unroll
      for (int r = 0; r < 4; ++r){ acca[i][j][r] = 0.f; accg[i][j][r] = 0.f; }

  for (int k0 = 0; k0 < 512; k0 += 32){
    #pragma unroll
    for (int i = 0; i < 2; ++i){
      const int ch = tid + 256 * i;
      const int r = ch >> 2, c = ch & 3;
      *(uint4*)&As[r * LDST + c * 8] =
          *(const uint4*)(A + (size_t)(m0 + r) * 512 + k0 + c * 8);
      *(uint4*)&Ba[r * LDST + c * 8] =
          *(const uint4*)(B + (size_t)(n0 + r) * 512 + k0 + c * 8);
      *(uint4*)&Bg[r * LDST + c * 8] =
          *(const uint4*)(B + (size_t)(n0 + 2048 + r) * 512 + k0 + c * 8);
    }
    __syncthreads();
    bf16x8 af[4], ba[4], bg[4];
    #pragma unroll
    for (int i = 0; i < 4; ++i)
      af[i] = *(const bf16x8*)&As[(wm + i * 16 + fr) * LDST + quad * 8];
    #pragma unroll
    for (int j = 0; j < 4; ++j){
      ba[j] = *(const bf16x8*)&Ba[(wn + j * 16 + fr) * LDST + quad * 8];
      bg[j] = *(const bf16x8*)&Bg[(wn + j * 16 + fr) * LDST + quad * 8];
    }
    #pragma unroll
    for (int i = 0; i < 4; ++i)
      #pragma unroll
      for (int j = 0; j < 4; ++j){
        acca[i][j] = __builtin_amdgcn_mfma_f32_16x16x32_bf16(af[i], ba[j], acca[i][j], 0, 0, 0);
        accg[i][j] = __builtin_amdgcn_mfma_f32_16x16x32_bf16(af[i], bg[j], accg[i][j], 0, 0, 0);
      }
    __syncthreads();
  }

  #pragma unroll
  for (int i = 0; i < 4; ++i){
    #pragma unroll
    for (int r = 0; r < 4; ++r){
      const int cm = m0 + wm + i * 16 + quad * 4 + r;
      #pragma unroll
      for (int j = 0; j < 4; ++j){
        const int cn = n0 + wn + j * 16 + fr;
        const float a = acca[i][j][r] + b1[cn];
        const float g = accg[i][j][r] + b1[cn + 2048];
        const float ge = g * 0.5f * (1.0f + erff(g * 0.70710678118654752f));
        act[(size_t)cm * 2048 + cn] = f2bf(a * ge);
      }
    }
  }
}

// ---------------------------------------------------------------------------
// Row softmax over 2048 bf16 logits, in place.
// ---------------------------------------------------------------------------
__global__ __launch_bounds__(256) void softmax_kernel(bfu* __restrict__ sc){
  __shared__ float red[4];
  const int tid = threadIdx.x;
  const int lane = tid & 63, wv = tid >> 6;
  bfu* rp = sc + (size_t)blockIdx.x * NCTX;
  float x[8];
  #pragma unroll
  for (int j = 0; j < 8; ++j) x[j] = bf2f(rp[tid + (j << 8)]);
  float mx = x[0];
  #pragma unroll
  for (int j = 1; j < 8; ++j) mx = fmaxf(mx, x[j]);
  for (int o = 32; o; o >>= 1) mx = fmaxf(mx, __shfl_xor(mx, o, 64));
  if (lane == 0) red[wv] = mx;
  __syncthreads();
  mx = fmaxf(fmaxf(red[0], red[1]), fmaxf(red[2], red[3]));
  float sum = 0.f;
  #pragma unroll
  for (int j = 0; j < 8; ++j){ x[j] = __expf(x[j] - mx); sum += x[j]; }
  for (int o = 32; o; o >>= 1) sum += __shfl_xor(sum, o, 64);
  __syncthreads();
  if (lane == 0) red[wv] = sum;
  __syncthreads();
  sum = red[0] + red[1] + red[2] + red[3];
  const float inv = 1.0f / sum;
  #pragma unroll
  for (int j = 0; j < 8; ++j) rp[tid + (j << 8)] = f2bf(x[j] * inv);
}

// ---------------------------------------------------------------------------
// LayerNorm rows of 512 fp32 -> bf16.
// ---------------------------------------------------------------------------
__global__ __launch_bounds__(256) void ln_kernel(const float* __restrict__ in,
                                                 const float* __restrict__ g,
                                                 const float* __restrict__ b,
                                                 bfu* __restrict__ out){
  const int tid = threadIdx.x, lane = tid & 63, wv = tid >> 6;
  const size_t row = (size_t)blockIdx.x * 4 + wv;
  const float* rp = in + row * DIMV;
  float x[8];
  #pragma unroll
  for (int j = 0; j < 8; ++j) x[j] = rp[lane + (j << 6)];
  float s = 0.f;
  #pragma unroll
  for (int j = 0; j < 8; ++j) s += x[j];
  for (int o = 32; o; o >>= 1) s += __shfl_xor(s, o, 64);
  const float m = s * (1.0f / 512.0f);
  float s2 = 0.f;
  #pragma unroll
  for (int j = 0; j < 8; ++j){ const float d = x[j] - m; s2 = fmaf(d, d, s2); }
  for (int o = 32; o; o >>= 1) s2 += __shfl_xor(s2, o, 64);
  const float inv = 1.0f / sqrtf(s2 * (1.0f / 512.0f) + 1e-5f);
  bfu* op = out + row * DIMV;
  #pragma unroll
  for (int j = 0; j < 8; ++j){
    const int c = lane + (j << 6);
    op[c] = f2bf((x[j] - m) * inv * g[c] + b[c]);
  }
}

// ---------------------------------------------------------------------------
// Workspace (peak 121,667,584 B < proven 125,861,888):
//   idx    @ 0          (32 KB)
//   emb_s  @ 32768      (25,165,824) \  act half (50,331,648) aliases
//   q_in   @ 25198592   (25,165,824) /  emb_s+q_in (both dead at MLP)
//          q_in -> attnout after q GEMM
//   c_grp  @ 50364416   (12,582,912) -> scores (GRP=6)
//   k_grp  @ 62947328   (12,582,912) -> vT (k dead after scores; group loop
//                                          order: ...scores, softmax, transp, pv)
//   v_grp  @ 75530240   (12,582,912)
//   qbuf   @ 88113152   (25,165,824) -> lnx
//   wT     @ 113278976  (8,388,608): wqT|wkvT|woT|w1T|w2T
// ---------------------------------------------------------------------------
extern "C" void kernel_launch(void* const* d_in, const int* in_sizes, int n_in,
                              void* d_out, int out_size, void* d_ws, size_t ws_size,
                              hipStream_t stream)
{
  (void)in_sizes; (void)n_in; (void)out_size;
  if (ws_size < 121667584ull) return;

  const float* pc    = (const float*)d_in[0];
  const float* pc2   = (const float*)d_in[1];
  const float* basis = (const float*)d_in[2];
  const float* pe_w  = (const float*)d_in[3];
  const float* pe_b  = (const float*)d_in[4];
  const float* lnq_g = (const float*)d_in[5];
  const float* lnq_b = (const float*)d_in[6];
  const float* lnc_g = (const float*)d_in[7];
  const float* lnc_b = (const float*)d_in[8];
  const float* wq    = (const float*)d_in[9];
  const float* wkv   = (const float*)d_in[10];
  const float* wo    = (const float*)d_in[11];
  const float* bo    = (const float*)d_in[12];
  const float* lnf_g = (const float*)d_in[13];
  const float* lnf_b = (const float*)d_in[14];
  const float* w1    = (const float*)d_in[15];
  const float* b1    = (const float*)d_in[16];
  const float* w2    = (const float*)d_in[17];
  const float* b2    = (const float*)d_in[18];
  float* xout = (float*)d_out;

  char* ws = (char*)d_ws;
  int* idxb   = (int*)(ws);
  bfu* emb_s  = (bfu*)(ws + 32768);
  bfu* q_in   = (bfu*)(ws + 25198592);
  bfu* c_grp  = (bfu*)(ws + 50364416);
  bfu* k_grp  = (bfu*)(ws + 62947328);
  bfu* v_grp  = (bfu*)(ws + 75530240);
  bfu* qbuf   = (bfu*)(ws + 88113152);
  bfu* wqT    = (bfu*)(ws + 113278976);
  bfu* wkvT   = (bfu*)(ws + 113803264);
  bfu* woT    = (bfu*)(ws + 114851840);
  bfu* w1T    = (bfu*)(ws + 115376128);
  bfu* w2T    = (bfu*)(ws + 119570432);
  bfu* scores  = c_grp;     // after c consumed by kv
  bfu* vT      = k_grp;     // after k consumed by scores
  bfu* attnout = q_in;      // after q GEMM consumed q_in
  bfu* lnx     = qbuf;      // after attention consumed q
  bfu* actb    = emb_s;     // spans emb_s+q_in (one MLP half at a time)

  // 0. weight transposes (fp32 [K][N] -> bf16 [N][K])
  transp_kernel<float><<<dim3(16, 16, 1),  256, 0, stream>>>(wq,  wqT,  512,  512, 0, 0);
  transp_kernel<float><<<dim3(32, 16, 1),  256, 0, stream>>>(wkv, wkvT, 512, 1024, 0, 0);
  transp_kernel<float><<<dim3(16, 16, 1),  256, 0, stream>>>(wo,  woT,  512,  512, 0, 0);
  transp_kernel<float><<<dim3(128, 16, 1), 256, 0, stream>>>(w1,  w1T,  512, 4096, 0, 0);
  transp_kernel<float><<<dim3(16, 64, 1),  256, 0, stream>>>(w2,  w2T, 2048,  512, 0, 0);

  // 1. FPS (2 waves per batch, register-resident coords, 1 barrier/step)
  fps_kernel<<<NB, 128, 0, stream>>>(pc, idxb);

  // 2. latent embed -> emb_s (raw) + q_in (LN'd)
  embed_kernel<true, true><<<MROWS/16, 256, 0, stream>>>(
      pc, pc2, idxb, basis, pe_w, pe_b, lnq_g, lnq_b, emb_s, q_in, NLAT);

  // 3. q = q_in @ wq
  gemm_mfma<4, bfu, float, EPI_NONE><<<dim3(4, 192, 1), 256, 0, stream>>>(
      q_in, wqT, qbuf, nullptr, nullptr, nullptr, 1.0f,
      512, 512, 512, 512, 512, 0, 0, 0);

  // 4. per-group context pipeline (GRP=6, 8 groups)
  for (int g = 0; g < NGRP; ++g){
    const int bt0 = g * GRP;
    embed_kernel<false, false><<<GROWS/16, 256, 0, stream>>>(
        pc + (size_t)bt0 * NCTX * 3, pc2 + (size_t)bt0 * NCTX * 3, nullptr,
        basis, pe_w, pe_b, lnc_g, lnc_b, nullptr, c_grp, NCTX);

    // kv = c @ wkv -> split k | v
    gemm_mfma<4, bfu, float, EPI_SPLIT><<<dim3(8, 96, 1), 256, 0, stream>>>(
        c_grp, wkvT, k_grp, v_grp, nullptr, nullptr, 1.0f,
        1024, 512, 512, 512, 512, 0, 0, 0);

    // scores = (q @ k^T) * scale (overwrites c_grp region)
    gemm_mfma<4, bfu, float, EPI_SCALE><<<dim3(16, 4, GRP), 256, 0, stream>>>(
        qbuf + (size_t)bt0 * 262144, k_grp, scores, nullptr, nullptr, nullptr,
        0.044194173824159216f,
        2048, 512, 512, 512, 2048, 262144, 1048576, 1048576);

    softmax_kernel<<<GRP * 512, 256, 0, stream>>>(scores);

    // vT = transpose(v) per bt (overwrites k_grp; k dead after scores)
    transp_kernel<bfu><<<dim3(16, 64, GRP), 256, 0, stream>>>(
        v_grp, vT, 2048, 512, 2048*512, 2048*512);

    // attnout = P @ V : 64x64 tiles -> (8,8,GRP) blocks for occupancy
    gemm_mfma<2, bfu, float, EPI_NONE><<<dim3(8, 8, GRP), 256, 0, stream>>>(
        scores, vT, attnout + (size_t)bt0 * 262144, nullptr, nullptr, nullptr, 1.0f,
        512, 2048, 2048, 2048, 512, 1048576, 1048576, 262144);
  }

  // 5. x = attnout @ wo + bo + emb_s -> d_out (fp32)
  gemm_mfma<4, float, bfu, EPI_BIAS_RES><<<dim3(4, 192, 1), 256, 0, stream>>>(
      attnout, woT, xout, nullptr, bo, emb_s, 1.0f,
      512, 512, 512, 512, 512, 0, 0, 0);

  // 6. lnx = LN(x)
  ln_kernel<<<MROWS/4, 256, 0, stream>>>(xout, lnf_g, lnf_b, lnx);

  // 7/8. MLP in two row-halves (act buffer holds one half)
  for (int h = 0; h < 2; ++h){
    const size_t ro = (size_t)h * 12288;
    mlp1_mfma<<<dim3(16, 96, 1), 256, 0, stream>>>(
        lnx + ro * 512, w1T, b1, actb);
    gemm_mfma<4, float, float, EPI_BIAS_RES><<<dim3(4, 96, 1), 256, 0, stream>>>(
        actb, w2T, xout + ro * 512, nullptr, b2, xout + ro * 512, 1.0f,
        512, 2048, 2048, 2048, 512, 0, 0, 0);
  }
}

// Round 7
// 1870.300 us; speedup vs baseline: 1.2069x; 1.1032x over previous
//
#include <hip/hip_runtime.h>

// Problem constants
#define NB    16
#define NT    3
#define NCTX  2048
#define NLAT  512
#define DIMV  512
#define HALFD 256
#define NFEAT 51
#define NBT   48
#define MROWS 24576    // NBT*NLAT
#define GRP   6        // bt per context group
#define NGRP  8
#define GROWS 12288    // GRP*NCTX

typedef unsigned short bfu;   // bf16 storage as raw bits
typedef short bf16x8 __attribute__((ext_vector_type(8)));   // 8 bf16 = 4 VGPR
typedef float f32x4  __attribute__((ext_vector_type(4)));   // MFMA 16x16 acc
typedef float f32x2  __attribute__((ext_vector_type(2)));   // packed fp32 pair

__device__ __forceinline__ float bf2f(bfu u){ return __uint_as_float(((unsigned int)u) << 16); }
__device__ __forceinline__ bfu f2bf(float f){
  unsigned int u = __float_as_uint(f);
  u += 0x7FFFu + ((u >> 16) & 1u);          // RNE
  return (bfu)(u >> 16);
}
__device__ __forceinline__ float loadE(const float* p){ return *p; }
__device__ __forceinline__ float loadE(const bfu* p){ return bf2f(*p); }
__device__ __forceinline__ void storeE(float* p, float v){ *p = v; }
__device__ __forceinline__ void storeE(bfu* p, float v){ *p = f2bf(v); }
__device__ __forceinline__ bfu to_bfu(float f){ return f2bf(f); }
__device__ __forceinline__ bfu to_bfu(bfu u){ return u; }

// Async 16B global->LDS DMA. LDS dest = wave-uniform base + lane*16 (linear!)
// so swizzled layouts are achieved by pre-swizzling the per-lane GLOBAL
// source address (m173 pattern), never the LDS dest.
#define GLD16(gp, lp) __builtin_amdgcn_global_load_lds(                       \
    (const __attribute__((address_space(1))) unsigned int*)(gp),              \
    (__attribute__((address_space(3))) unsigned int*)(lp), 16, 0, 0)

// ---------------------------------------------------------------------------
// FPS: TWO waves per batch, coords REGISTER-resident (1024 pts/wave = 48
// VGPRs coords + 16 d2). Per step: pts[last] broadcast -> packed VALU dist
// update -> in-lane tree -> DPP wave argmax -> 8B lane-63 write, ONE
// barrier (parity dbuf), 16B merge read. Proven best FPS variant (R6:
// 390us vs 443-464 for 1-wave layouts -- allocator caps VGPRs at 132 so
// 1-wave coord residency always spilled/serialized).
// Tie-breaks: in-lane tree merges index-ordered ranges (strict > -> lowest
// index); DPP comparator carries global idx; cross-wave strict > prefers
// wave0 (smaller indices). numpy first-max semantics exactly. Distance
// expression, contract(off), fminf, 1e10f identical to the proven
// bit-exact version.
// ---------------------------------------------------------------------------
#define DPP_ARGMAX_STAGE(CTRL)                                                \
  {                                                                           \
    const int svb = __builtin_amdgcn_update_dpp(vb, vb, CTRL, 0xF, 0xF, false); \
    const int sib = __builtin_amdgcn_update_dpp(ib, ib, CTRL, 0xF, 0xF, false); \
    const float sv = __int_as_float(svb);                                     \
    const float cv = __int_as_float(vb);                                      \
    if (sv > cv || (sv == cv && sib < ib)){ vb = svb; ib = sib; }             \
  }

__global__ __attribute__((amdgpu_waves_per_eu(1, 1)))
__launch_bounds__(128) void fps_kernel(const float* __restrict__ pc,
                                       int* __restrict__ idx_out){
#pragma clang fp contract(off)
  __shared__ float4 pts[NCTX];            // broadcast table for "last" coords
  __shared__ __align__(16) int mbuf[2][4];// [parity][w*2 + {v,idx}]
  const int tid = threadIdx.x;
  const int lane = tid & 63, w = tid >> 6;
  const int wbase = w << 10;              // wave owns [1024w, 1024w+1024)
  const int b = blockIdx.x;
  const float* src = pc + (size_t)b * (NT * NCTX * 3);

  // Slot s (0..15) = point p = wbase + (s<<6) + lane. Coords + running
  // min-dists all register-resident; pair j holds slots 2j (lo), 2j+1 (hi).
  f32x2 x2[8], y2[8], z2[8], d2[8];
  #pragma unroll
  for (int j = 0; j < 8; ++j){
    #pragma unroll
    for (int h = 0; h < 2; ++h){
      const int p = wbase + ((2 * j + h) << 6) + lane;
      const float xx = src[p * 3 + 0];
      const float yy = src[p * 3 + 1];
      const float zz = src[p * 3 + 2];
      x2[j][h] = xx; y2[j][h] = yy; z2[j][h] = zz;
      pts[p] = make_float4(xx, yy, zz, 0.f);
    }
    d2[j][0] = 1e10f; d2[j][1] = 1e10f;
  }
  if (tid == 0) idx_out[b * NLAT] = 0;
  __syncthreads();                        // pts table ready

  int last = 0;
  for (int step = 1; step < NLAT; ++step){
    const float4 lp = pts[last];          // uniform addr -> LDS broadcast

    // distance update: pure packed VALU, identical op order to the proven
    // bit-exact version.
    #pragma unroll
    for (int j = 0; j < 8; ++j){
      const f32x2 dx = x2[j] - lp.x;
      const f32x2 dy = y2[j] - lp.y;
      const f32x2 dz = z2[j] - lp.z;
      const f32x2 dd = (dx * dx + dy * dy) + dz * dz;
      f32x2 nd;
      nd[0] = fminf(d2[j][0], dd[0]);
      nd[1] = fminf(d2[j][1], dd[1]);
      d2[j] = nd;
    }

    // in-lane argmax over 16 slots, adjacent-pair tree (index-ordered
    // merges: strict > keeps the lowest index on ties).
    float av[8]; int as_[8];
    #pragma unroll
    for (int j = 0; j < 8; ++j){
      const float lo = d2[j][0], hi = d2[j][1];
      const bool t = hi > lo;
      av[j]  = t ? hi : lo;
      as_[j] = t ? 2 * j + 1 : 2 * j;
    }
    #pragma unroll
    for (int wdt = 4; wdt; wdt >>= 1){
      #pragma unroll
      for (int j = 0; j < wdt; ++j){
        const float lv = av[2 * j], rv = av[2 * j + 1];
        const int   li = as_[2 * j], ri = as_[2 * j + 1];
        const bool t = rv > lv;
        av[j]  = t ? rv : lv;
        as_[j] = t ? ri : li;
      }
    }

    // cross-lane argmax on (value, GLOBAL index); ties -> lower index
    int vb = __float_as_int(av[0]);
    int ib = wbase + (as_[0] << 6) + lane;
    DPP_ARGMAX_STAGE(0x111)   // row_shr:1
    DPP_ARGMAX_STAGE(0x112)   // row_shr:2
    DPP_ARGMAX_STAGE(0x114)   // row_shr:4
    DPP_ARGMAX_STAGE(0x118)   // row_shr:8
    DPP_ARGMAX_STAGE(0x142)   // row_bcast:15
    DPP_ARGMAX_STAGE(0x143)   // row_bcast:31

    // cross-wave merge: 8B write (lane 63), one barrier, 16B broadcast read.
    // Parity buffer -> no second barrier needed.
    const int par = step & 1;
    if (lane == 63){ mbuf[par][w * 2] = vb; mbuf[par][w * 2 + 1] = ib; }
    __syncthreads();
    const int4 q = *(const int4*)&mbuf[par][0];
    const float f0 = __int_as_float(q.x), f1 = __int_as_float(q.z);
    last = (f1 > f0) ? q.w : q.y;         // wave0 indices all smaller: strict >
    if (tid == 0) idx_out[b * NLAT + step] = last;
  }
}

// ---------------------------------------------------------------------------
// Fused (gather) + point_embed x2 + layernorm -> bf16. 16 points / block.
// ---------------------------------------------------------------------------
template<bool GATHER, bool WRITE_EMB>
__global__ __launch_bounds__(256) void embed_kernel(
    const float* __restrict__ pc, const float* __restrict__ pc2,
    const int* __restrict__ idx,
    const float* __restrict__ basis, const float* __restrict__ pe_w,
    const float* __restrict__ pe_b,
    const float* __restrict__ ln_g, const float* __restrict__ ln_b,
    bfu* __restrict__ emb, bfu* __restrict__ lnout, int nppbt)
{
  __shared__ float feat[2][16][NFEAT + 1];
  __shared__ float outb[16][DIMV];
  const int tid = threadIdx.x;
  const int p0 = blockIdx.x << 4;

  if (tid < 32){
    const int s = tid >> 4, p = tid & 15;
    const int gp = p0 + p;
    const int bt = gp / nppbt;
    const int n  = gp - bt * nppbt;
    const int bb = bt / NT;
    const int srcn = GATHER ? idx[bb * NLAT + n] : n;
    const float* sp = (s ? pc2 : pc) + ((size_t)bt * NCTX + srcn) * 3;
    const float x0 = sp[0], x1 = sp[1], x2 = sp[2];
    #pragma unroll
    for (int e = 0; e < 24; ++e){
      const float pr = __fadd_rn(__fadd_rn(__fmul_rn(x0, basis[e]),
                                           __fmul_rn(x1, basis[24 + e])),
                                 __fmul_rn(x2, basis[48 + e]));
      feat[s][p][e]      = sinf(pr);
      feat[s][p][24 + e] = cosf(pr);
    }
    feat[s][p][48] = x0; feat[s][p][49] = x1; feat[s][p][50] = x2;
  }
  __syncthreads();

  {
    float w[NFEAT];
    #pragma unroll
    for (int k = 0; k < NFEAT; ++k) w[k] = pe_w[k * HALFD + tid];
    const float bv = pe_b[tid];
    #pragma unroll
    for (int half = 0; half < 2; ++half){
      for (int p = 0; p < 16; ++p){
        float acc = bv;
        #pragma unroll
        for (int k = 0; k < NFEAT; ++k) acc = fmaf(feat[half][p][k], w[k], acc);
        outb[p][half * HALFD + tid] = acc;
      }
    }
  }
  __syncthreads();

  const int lane = tid & 63, wv = tid >> 6;
  for (int pp = 0; pp < 4; ++pp){
    const int p = (wv << 2) + pp;
    const size_t gp = (size_t)p0 + p;
    float x[8];
    #pragma unroll
    for (int j = 0; j < 8; ++j) x[j] = outb[p][lane + (j << 6)];
    float s = 0.f;
    #pragma unroll
    for (int j = 0; j < 8; ++j) s += x[j];
    for (int o = 32; o; o >>= 1) s += __shfl_xor(s, o, 64);
    const float m = s * (1.0f / 512.0f);
    float s2 = 0.f;
    #pragma unroll
    for (int j = 0; j < 8; ++j){ const float d = x[j] - m; s2 = fmaf(d, d, s2); }
    for (int o = 32; o; o >>= 1) s2 += __shfl_xor(s2, o, 64);
    const float inv = 1.0f / sqrtf(s2 * (1.0f / 512.0f) + 1e-5f);
    #pragma unroll
    for (int j = 0; j < 8; ++j){
      const int c = lane + (j << 6);
      const float r = (x[j] - m) * inv * ln_g[c] + ln_b[c];
      const size_t o2 = gp * DIMV + c;
      if (WRITE_EMB) emb[o2] = f2bf(x[j]);
      lnout[o2] = f2bf(r);
    }
  }
}

// ---------------------------------------------------------------------------
// Tiled transpose: in [R][C] (fp32 or bf16) -> out bf16 [C][R]. 32x32 tiles.
// ---------------------------------------------------------------------------
template<typename TIN>
__global__ __launch_bounds__(256) void transp_kernel(
    const TIN* __restrict__ in, bfu* __restrict__ out, int R, int C,
    long long sIn, long long sOut)
{
  __shared__ bfu t[32][33];
  in  += (size_t)blockIdx.z * sIn;
  out += (size_t)blockIdx.z * sOut;
  const int c0 = blockIdx.x * 32, r0 = blockIdx.y * 32;
  const int tx = threadIdx.x & 31, ty = threadIdx.x >> 5;
  #pragma unroll
  for (int rr = ty; rr < 32; rr += 8)
    t[rr][tx] = to_bfu(in[(size_t)(r0 + rr) * C + c0 + tx]);
  __syncthreads();
  #pragma unroll
  for (int rr = ty; rr < 32; rr += 8)
    out[(size_t)(c0 + rr) * R + r0 + tx] = t[tx][rr];
}

// ---------------------------------------------------------------------------
// MFMA GEMM: C[M][N] = A[M][K] * B[N][K]^T, bf16 inputs.
// Tile = (FH*32) x (FH*32): FH=4 -> 128x128, FH=2 -> 64x64. 4 waves 2x2.
// R6: staging via global_load_lds width=16 (async DMA, no reg round-trip --
// guide m151: +35% vs reg-staging at identical 128(2)/2-barrier structure).
// LDS is LINEAR [BT][32] shorts (DMA dest = wave_base + lane*16); bank
// conflicts kept at 2-way (same as the old LDST=40 pad) via XOR chunk
// swizzle c' = c ^ ((row>>1)&3), applied as inverse on the per-lane GLOBAL
// source and identically on the ds_read address (both-sides rule).
// ---------------------------------------------------------------------------
#define EPI_NONE     0
#define EPI_SPLIT    1
#define EPI_SCALE    2
#define EPI_BIAS_RES 3

template<int FH, typename TC, typename TR, int EPI>
__global__ __launch_bounds__(256, 2) void gemm_mfma(
    const bfu* __restrict__ A, const bfu* __restrict__ B,
    TC* __restrict__ C, TC* __restrict__ C2,
    const float* __restrict__ bias, const TR* __restrict__ res,
    float scale, int N, int K, int lda, int ldb, int ldc,
    long long sA, long long sB, long long sC)
{
  constexpr int BT = FH * 32;              // block tile edge
  constexpr int NI = (BT * 4) / 256;       // 16B-chunk issues per wave/matrix
  const int bz = blockIdx.z;
  A += (size_t)bz * sA;
  B += (size_t)bz * sB;
  const size_t coff = (size_t)bz * sC;

  __shared__ __align__(16) short As[BT * 32];
  __shared__ __align__(16) short Bs[BT * 32];

  const int tid = threadIdx.x;
  const int lane = tid & 63, w = tid >> 6;
  const int wl = (w << 6) + lane;
  const int m0 = blockIdx.y * BT, n0 = blockIdx.x * BT;
  const int wm = (w & 1) * (FH * 16), wn = (w >> 1) * (FH * 16);
  const int fr = lane & 15, quad = lane >> 4;

  f32x4 acc[FH][FH];
  #pragma unroll
  for (int i = 0; i < FH; ++i)
    #pragma unroll
    for (int j = 0; j < FH; ++j)
      #pragma unroll
      for (int r = 0; r < 4; ++r) acc[i][j][r] = 0.f;

  for (int k0 = 0; k0 < K; k0 += 32){
    #pragma unroll
    for (int i = 0; i < NI; ++i){
      const int ch = i * 256 + wl;         // stored chunk: row r, slot cs
      const int r  = ch >> 2, cs = ch & 3;
      const int cg = cs ^ ((r >> 1) & 3);  // global chunk (inverse swizzle)
      short* ldst = (short*)As + ((i * 256 + (w << 6)) << 3); // wave-uniform
      GLD16(A + (size_t)(m0 + r) * lda + k0 + cg * 8, ldst);
      short* ldstB = (short*)Bs + ((i * 256 + (w << 6)) << 3);
      GLD16(B + (size_t)(n0 + r) * ldb + k0 + cg * 8, ldstB);
    }
    __syncthreads();
    bf16x8 af[FH], bf[FH];
    #pragma unroll
    for (int i = 0; i < FH; ++i){
      const int row = wm + i * 16 + fr;
      af[i] = *(const bf16x8*)&As[(row << 5) + ((quad ^ ((row >> 1) & 3)) << 3)];
    }
    #pragma unroll
    for (int j = 0; j < FH; ++j){
      const int row = wn + j * 16 + fr;
      bf[j] = *(const bf16x8*)&Bs[(row << 5) + ((quad ^ ((row >> 1) & 3)) << 3)];
    }
    #pragma unroll
    for (int i = 0; i < FH; ++i)
      #pragma unroll
      for (int j = 0; j < FH; ++j)
        acc[i][j] = __builtin_amdgcn_mfma_f32_16x16x32_bf16(af[i], bf[j], acc[i][j], 0, 0, 0);
    __syncthreads();
  }

  // C/D layout: col = lane&15, row = quad*4 + reg
  TC* Cp = C + coff;
  #pragma unroll
  for (int i = 0; i < FH; ++i){
    #pragma unroll
    for (int r = 0; r < 4; ++r){
      const int cm = m0 + wm + i * 16 + quad * 4 + r;
      #pragma unroll
      for (int j = 0; j < FH; ++j){
        const int cn = n0 + wn + j * 16 + fr;
        float v = acc[i][j][r];
        if (EPI == EPI_SCALE)    v *= scale;
        if (EPI == EPI_BIAS_RES) v = v + bias[cn] + loadE(&res[coff + (size_t)cm * ldc + cn]);
        if (EPI == EPI_SPLIT){
          const int half = N >> 1;
          if (cn < half) storeE(&C [(size_t)cm * half + cn],          v);
          else           storeE(&C2[(size_t)cm * half + (cn - half)], v);
        } else {
          storeE(&Cp[(size_t)cm * ldc + cn], v);
        }
      }
    }
  }
}

// ---------------------------------------------------------------------------
// Fused MLP1 + exact GeLU (MFMA): act = (A@w1T[a]+b1a) * gelu(A@w1T[g]+b1g).
// Same global_load_lds + XOR-swizzle staging as gemm_mfma.
// ---------------------------------------------------------------------------
__global__ __launch_bounds__(256, 1) void mlp1_mfma(
    const bfu* __restrict__ A, const bfu* __restrict__ B,  // B = w1T [4096][512]
    const float* __restrict__ b1, bfu* __restrict__ act)
{
  __shared__ __align__(16) short As[128 * 32];
  __shared__ __align__(16) short Ba[128 * 32];
  __shared__ __align__(16) short Bg[128 * 32];

  const int tid = threadIdx.x;
  const int lane = tid & 63, w = tid >> 6;
  const int wl = (w << 6) + lane;
  const int m0 = blockIdx.y * 128, n0 = blockIdx.x * 128;
  const int wm = (w & 1) * 64, wn = (w >> 1) * 64;
  const int fr = lane & 15, quad = lane >> 4;

  f32x4 acca[4][4], accg[4][4];
  #pragma unroll
  for (int i = 0; i < 4; ++i)
    #pragma unroll
    for (int j = 0; j < 4; ++j)
      #pragma unroll
      for (int r = 0; r < 4; ++r){ acca[i][j][r] = 0.f; accg[i][j][r] = 0.f; }

  for (int k0 = 0; k0 < 512; k0 += 32){
    #pragma unroll
    for (int i = 0; i < 2; ++i){
      const int ch = i * 256 + wl;
      const int r  = ch >> 2, cs = ch & 3;
      const int cg = cs ^ ((r >> 1) & 3);
      short* da = (short*)As + ((i * 256 + (w << 6)) << 3);
      short* db = (short*)Ba + ((i * 256 + (w << 6)) << 3);
      short* dg = (short*)Bg + ((i * 256 + (w << 6)) << 3);
      GLD16(A + (size_t)(m0 + r) * 512 + k0 + cg * 8, da);
      GLD16(B + (size_t)(n0 + r) * 512 + k0 + cg * 8, db);
      GLD16(B + (size_t)(n0 + 2048 + r) * 512 + k0 + cg * 8, dg);
    }
    __syncthreads();
    bf16x8 af[4], ba[4], bg[4];
    #pragma unroll
    for (int i = 0; i < 4; ++i){
      const int row = wm + i * 16 + fr;
      af[i] = *(const bf16x8*)&As[(row << 5) + ((quad ^ ((row >> 1) & 3)) << 3)];
    }
    #pragma unroll
    for (int j = 0; j < 4; ++j){
      const int row = wn + j * 16 + fr;
      const int co = (row << 5) + ((quad ^ ((row >> 1) & 3)) << 3);
      ba[j] = *(const bf16x8*)&Ba[co];
      bg[j] = *(const bf16x8*)&Bg[co];
    }
    #pragma unroll
    for (int i = 0; i < 4; ++i)
      #pragma unroll
      for (int j = 0; j < 4; ++j){
        acca[i][j] = __builtin_amdgcn_mfma_f32_16x16x32_bf16(af[i], ba[j], acca[i][j], 0, 0, 0);
        accg[i][j] = __builtin_amdgcn_mfma_f32_16x16x32_bf16(af[i], bg[j], accg[i][j], 0, 0, 0);
      }
    __syncthreads();
  }

  #pragma unroll
  for (int i = 0; i < 4; ++i){
    #pragma unroll
    for (int r = 0; r < 4; ++r){
      const int cm = m0 + wm + i * 16 + quad * 4 + r;
      #pragma unroll
      for (int j = 0; j < 4; ++j){
        const int cn = n0 + wn + j * 16 + fr;
        const float a = acca[i][j][r] + b1[cn];
        const float g = accg[i][j][r] + b1[cn + 2048];
        const float ge = g * 0.5f * (1.0f + erff(g * 0.70710678118654752f));
        act[(size_t)cm * 2048 + cn] = f2bf(a * ge);
      }
    }
  }
}

// ---------------------------------------------------------------------------
// Row softmax over 2048 bf16 logits, in place.
// ---------------------------------------------------------------------------
__global__ __launch_bounds__(256) void softmax_kernel(bfu* __restrict__ sc){
  __shared__ float red[4];
  const int tid = threadIdx.x;
  const int lane = tid & 63, wv = tid >> 6;
  bfu* rp = sc + (size_t)blockIdx.x * NCTX;
  float x[8];
  #pragma unroll
  for (int j = 0; j < 8; ++j) x[j] = bf2f(rp[tid + (j << 8)]);
  float mx = x[0];
  #pragma unroll
  for (int j = 1; j < 8; ++j) mx = fmaxf(mx, x[j]);
  for (int o = 32; o; o >>= 1) mx = fmaxf(mx, __shfl_xor(mx, o, 64));
  if (lane == 0) red[wv] = mx;
  __syncthreads();
  mx = fmaxf(fmaxf(red[0], red[1]), fmaxf(red[2], red[3]));
  float sum = 0.f;
  #pragma unroll
  for (int j = 0; j < 8; ++j){ x[j] = __expf(x[j] - mx); sum += x[j]; }
  for (int o = 32; o; o >>= 1) sum += __shfl_xor(sum, o, 64);
  __syncthreads();
  if (lane == 0) red[wv] = sum;
  __syncthreads();
  sum = red[0] + red[1] + red[2] + red[3];
  const float inv = 1.0f / sum;
  #pragma unroll
  for (int j = 0; j < 8; ++j) rp[tid + (j << 8)] = f2bf(x[j] * inv);
}

// ---------------------------------------------------------------------------
// LayerNorm rows of 512 fp32 -> bf16.
// ---------------------------------------------------------------------------
__global__ __launch_bounds__(256) void ln_kernel(const float* __restrict__ in,
                                                 const float* __restrict__ g,
                                                 const float* __restrict__ b,
                                                 bfu* __restrict__ out){
  const int tid = threadIdx.x, lane = tid & 63, wv = tid >> 6;
  const size_t row = (size_t)blockIdx.x * 4 + wv;
  const float* rp = in + row * DIMV;
  float x[8];
  #pragma unroll
  for (int j = 0; j < 8; ++j) x[j] = rp[lane + (j << 6)];
  float s = 0.f;
  #pragma unroll
  for (int j = 0; j < 8; ++j) s += x[j];
  for (int o = 32; o; o >>= 1) s += __shfl_xor(s, o, 64);
  const float m = s * (1.0f / 512.0f);
  float s2 = 0.f;
  #pragma unroll
  for (int j = 0; j < 8; ++j){ const float d = x[j] - m; s2 = fmaf(d, d, s2); }
  for (int o = 32; o; o >>= 1) s2 += __shfl_xor(s2, o, 64);
  const float inv = 1.0f / sqrtf(s2 * (1.0f / 512.0f) + 1e-5f);
  bfu* op = out + row * DIMV;
  #pragma unroll
  for (int j = 0; j < 8; ++j){
    const int c = lane + (j << 6);
    op[c] = f2bf((x[j] - m) * inv * g[c] + b[c]);
  }
}

// ---------------------------------------------------------------------------
// Workspace (peak 121,667,584 B < proven 125,861,888):
//   idx    @ 0          (32 KB)
//   emb_s  @ 32768      (25,165,824) \  act half (50,331,648) aliases
//   q_in   @ 25198592   (25,165,824) /  emb_s+q_in (both dead at MLP)
//          q_in -> attnout after q GEMM
//   c_grp  @ 50364416   (12,582,912) -> scores (GRP=6)
//   k_grp  @ 62947328   (12,582,912) -> vT (k dead after scores; group loop
//                                          order: ...scores, softmax, transp, pv)
//   v_grp  @ 75530240   (12,582,912)
//   qbuf   @ 88113152   (25,165,824) -> lnx
//   wT     @ 113278976  (8,388,608): wqT|wkvT|woT|w1T|w2T
// ---------------------------------------------------------------------------
extern "C" void kernel_launch(void* const* d_in, const int* in_sizes, int n_in,
                              void* d_out, int out_size, void* d_ws, size_t ws_size,
                              hipStream_t stream)
{
  (void)in_sizes; (void)n_in; (void)out_size;
  if (ws_size < 121667584ull) return;

  const float* pc    = (const float*)d_in[0];
  const float* pc2   = (const float*)d_in[1];
  const float* basis = (const float*)d_in[2];
  const float* pe_w  = (const float*)d_in[3];
  const float* pe_b  = (const float*)d_in[4];
  const float* lnq_g = (const float*)d_in[5];
  const float* lnq_b = (const float*)d_in[6];
  const float* lnc_g = (const float*)d_in[7];
  const float* lnc_b = (const float*)d_in[8];
  const float* wq    = (const float*)d_in[9];
  const float* wkv   = (const float*)d_in[10];
  const float* wo    = (const float*)d_in[11];
  const float* bo    = (const float*)d_in[12];
  const float* lnf_g = (const float*)d_in[13];
  const float* lnf_b = (const float*)d_in[14];
  const float* w1    = (const float*)d_in[15];
  const float* b1    = (const float*)d_in[16];
  const float* w2    = (const float*)d_in[17];
  const float* b2    = (const float*)d_in[18];
  float* xout = (float*)d_out;

  char* ws = (char*)d_ws;
  int* idxb   = (int*)(ws);
  bfu* emb_s  = (bfu*)(ws + 32768);
  bfu* q_in   = (bfu*)(ws + 25198592);
  bfu* c_grp  = (bfu*)(ws + 50364416);
  bfu* k_grp  = (bfu*)(ws + 62947328);
  bfu* v_grp  = (bfu*)(ws + 75530240);
  bfu* qbuf   = (bfu*)(ws + 88113152);
  bfu* wqT    = (bfu*)(ws + 113278976);
  bfu* wkvT   = (bfu*)(ws + 113803264);
  bfu* woT    = (bfu*)(ws + 114851840);
  bfu* w1T    = (bfu*)(ws + 115376128);
  bfu* w2T    = (bfu*)(ws + 119570432);
  bfu* scores  = c_grp;     // after c consumed by kv
  bfu* vT      = k_grp;     // after k consumed by scores
  bfu* attnout = q_in;      // after q GEMM consumed q_in
  bfu* lnx     = qbuf;      // after attention consumed q
  bfu* actb    = emb_s;     // spans emb_s+q_in (one MLP half at a time)

  // 0. weight transposes (fp32 [K][N] -> bf16 [N][K])
  transp_kernel<float><<<dim3(16, 16, 1),  256, 0, stream>>>(wq,  wqT,  512,  512, 0, 0);
  transp_kernel<float><<<dim3(32, 16, 1),  256, 0, stream>>>(wkv, wkvT, 512, 1024, 0, 0);
  transp_kernel<float><<<dim3(16, 16, 1),  256, 0, stream>>>(wo,  woT,  512,  512, 0, 0);
  transp_kernel<float><<<dim3(128, 16, 1), 256, 0, stream>>>(w1,  w1T,  512, 4096, 0, 0);
  transp_kernel<float><<<dim3(16, 64, 1),  256, 0, stream>>>(w2,  w2T, 2048,  512, 0, 0);

  // 1. FPS (2 waves per batch, register-resident coords, 1 barrier/step)
  fps_kernel<<<NB, 128, 0, stream>>>(pc, idxb);

  // 2. latent embed -> emb_s (raw) + q_in (LN'd)
  embed_kernel<true, true><<<MROWS/16, 256, 0, stream>>>(
      pc, pc2, idxb, basis, pe_w, pe_b, lnq_g, lnq_b, emb_s, q_in, NLAT);

  // 3. q = q_in @ wq
  gemm_mfma<4, bfu, float, EPI_NONE><<<dim3(4, 192, 1), 256, 0, stream>>>(
      q_in, wqT, qbuf, nullptr, nullptr, nullptr, 1.0f,
      512, 512, 512, 512, 512, 0, 0, 0);

  // 4. per-group context pipeline (GRP=6, 8 groups)
  for (int g = 0; g < NGRP; ++g){
    const int bt0 = g * GRP;
    embed_kernel<false, false><<<GROWS/16, 256, 0, stream>>>(
        pc + (size_t)bt0 * NCTX * 3, pc2 + (size_t)bt0 * NCTX * 3, nullptr,
        basis, pe_w, pe_b, lnc_g, lnc_b, nullptr, c_grp, NCTX);

    // kv = c @ wkv -> split k | v
    gemm_mfma<4, bfu, float, EPI_SPLIT><<<dim3(8, 96, 1), 256, 0, stream>>>(
        c_grp, wkvT, k_grp, v_grp, nullptr, nullptr, 1.0f,
        1024, 512, 512, 512, 512, 0, 0, 0);

    // scores = (q @ k^T) * scale (overwrites c_grp region)
    gemm_mfma<4, bfu, float, EPI_SCALE><<<dim3(16, 4, GRP), 256, 0, stream>>>(
        qbuf + (size_t)bt0 * 262144, k_grp, scores, nullptr, nullptr, nullptr,
        0.044194173824159216f,
        2048, 512, 512, 512, 2048, 262144, 1048576, 1048576);

    softmax_kernel<<<GRP * 512, 256, 0, stream>>>(scores);

    // vT = transpose(v) per bt (overwrites k_grp; k dead after scores)
    transp_kernel<bfu><<<dim3(16, 64, GRP), 256, 0, stream>>>(
        v_grp, vT, 2048, 512, 2048*512, 2048*512);

    // attnout = P @ V : 64x64 tiles -> (8,8,GRP) blocks for occupancy
    gemm_mfma<2, bfu, float, EPI_NONE><<<dim3(8, 8, GRP), 256, 0, stream>>>(
        scores, vT, attnout + (size_t)bt0 * 262144, nullptr, nullptr, nullptr, 1.0f,
        512, 2048, 2048, 2048, 512, 1048576, 1048576, 262144);
  }

  // 5. x = attnout @ wo + bo + emb_s -> d_out (fp32)
  gemm_mfma<4, float, bfu, EPI_BIAS_RES><<<dim3(4, 192, 1), 256, 0, stream>>>(
      attnout, woT, xout, nullptr, bo, emb_s, 1.0f,
      512, 512, 512, 512, 512, 0, 0, 0);

  // 6. lnx = LN(x)
  ln_kernel<<<MROWS/4, 256, 0, stream>>>(xout, lnf_g, lnf_b, lnx);

  // 7/8. MLP in two row-halves (act buffer holds one half)
  for (int h = 0; h < 2; ++h){
    const size_t ro = (size_t)h * 12288;
    mlp1_mfma<<<dim3(16, 96, 1), 256, 0, stream>>>(
        lnx + ro * 512, w1T, b1, actb);
    gemm_mfma<4, float, float, EPI_BIAS_RES><<<dim3(4, 96, 1), 256, 0, stream>>>(
        actb, w2T, xout + ro * 512, nullptr, b2, xout + ro * 512, 1.0f,
        512, 2048, 2048, 2048, 512, 0, 0, 0);
  }
}

// Round 8
// 1746.634 us; speedup vs baseline: 1.2923x; 1.0708x over previous
//
#include <hip/hip_runtime.h>

// Problem constants
#define NB    16
#define NT    3
#define NCTX  2048
#define NLAT  512
#define DIMV  512
#define HALFD 256
#define NFEAT 51
#define NBT   48
#define MROWS 24576    // NBT*NLAT
#define GRP   6        // bt per context group
#define NGRP  8
#define GROWS 12288    // GRP*NCTX

typedef unsigned short bfu;   // bf16 storage as raw bits
typedef short bf16x8 __attribute__((ext_vector_type(8)));   // 8 bf16 = 4 VGPR
typedef float f32x4  __attribute__((ext_vector_type(4)));   // MFMA 16x16 acc
typedef float f32x2  __attribute__((ext_vector_type(2)));   // packed fp32 pair

__device__ __forceinline__ float bf2f(bfu u){ return __uint_as_float(((unsigned int)u) << 16); }
__device__ __forceinline__ bfu f2bf(float f){
  unsigned int u = __float_as_uint(f);
  u += 0x7FFFu + ((u >> 16) & 1u);          // RNE
  return (bfu)(u >> 16);
}
__device__ __forceinline__ float loadE(const float* p){ return *p; }
__device__ __forceinline__ float loadE(const bfu* p){ return bf2f(*p); }
__device__ __forceinline__ void storeE(float* p, float v){ *p = v; }
__device__ __forceinline__ void storeE(bfu* p, float v){ *p = f2bf(v); }
__device__ __forceinline__ bfu to_bfu(float f){ return f2bf(f); }
__device__ __forceinline__ bfu to_bfu(bfu u){ return u; }

// Async 16B global->LDS DMA. LDS dest = wave-uniform base + lane*16 (linear!)
// so swizzled layouts are achieved by pre-swizzling the per-lane GLOBAL
// source address (m173 pattern), never the LDS dest.
#define GLD16(gp, lp) __builtin_amdgcn_global_load_lds(                       \
    (const __attribute__((address_space(1))) unsigned int*)(gp),              \
    (__attribute__((address_space(3))) unsigned int*)(lp), 16, 0, 0)

// XOR chunk swizzle key for a [*][KSTEP] bf16 LDS tile (16B chunks).
// KSTEP=32: row=64B (2 rows/bank-stripe) -> key r>>1, 4 chunks.
// KSTEP>=64: row covers all 32 banks -> key r, CPR chunks. 2-way worst case.
template<int KSTEP>
__device__ __forceinline__ int swzr(int r){
  constexpr int CPR = KSTEP / 8;
  return (KSTEP == 32) ? ((r >> 1) & 3) : (r & (CPR - 1));
}

// ---------------------------------------------------------------------------
// FPS: TWO waves per batch, coords REGISTER-resident (1024 pts/wave = 48
// VGPRs coords + 16 d2). Per step: pts[last] broadcast -> packed VALU dist
// update -> in-lane tree -> DPP wave argmax -> 8B lane-63 write, ONE
// barrier (parity dbuf), 16B merge read. Proven best FPS variant (R6:
// 390us vs 443-464 for 1-wave layouts -- allocator caps VGPRs at 132 so
// 1-wave coord residency always spilled/serialized).
// Tie-breaks: in-lane tree merges index-ordered ranges (strict > -> lowest
// index); DPP comparator carries global idx; cross-wave strict > prefers
// wave0 (smaller indices). numpy first-max semantics exactly. Distance
// expression, contract(off), fminf, 1e10f identical to the proven
// bit-exact version.
// ---------------------------------------------------------------------------
#define DPP_ARGMAX_STAGE(CTRL)                                                \
  {                                                                           \
    const int svb = __builtin_amdgcn_update_dpp(vb, vb, CTRL, 0xF, 0xF, false); \
    const int sib = __builtin_amdgcn_update_dpp(ib, ib, CTRL, 0xF, 0xF, false); \
    const float sv = __int_as_float(svb);                                     \
    const float cv = __int_as_float(vb);                                      \
    if (sv > cv || (sv == cv && sib < ib)){ vb = svb; ib = sib; }             \
  }

__global__ __attribute__((amdgpu_waves_per_eu(1, 1)))
__launch_bounds__(128) void fps_kernel(const float* __restrict__ pc,
                                       int* __restrict__ idx_out){
#pragma clang fp contract(off)
  __shared__ float4 pts[NCTX];            // broadcast table for "last" coords
  __shared__ __align__(16) int mbuf[2][4];// [parity][w*2 + {v,idx}]
  const int tid = threadIdx.x;
  const int lane = tid & 63, w = tid >> 6;
  const int wbase = w << 10;              // wave owns [1024w, 1024w+1024)
  const int b = blockIdx.x;
  const float* src = pc + (size_t)b * (NT * NCTX * 3);

  // Slot s (0..15) = point p = wbase + (s<<6) + lane. Coords + running
  // min-dists all register-resident; pair j holds slots 2j (lo), 2j+1 (hi).
  f32x2 x2[8], y2[8], z2[8], d2[8];
  #pragma unroll
  for (int j = 0; j < 8; ++j){
    #pragma unroll
    for (int h = 0; h < 2; ++h){
      const int p = wbase + ((2 * j + h) << 6) + lane;
      const float xx = src[p * 3 + 0];
      const float yy = src[p * 3 + 1];
      const float zz = src[p * 3 + 2];
      x2[j][h] = xx; y2[j][h] = yy; z2[j][h] = zz;
      pts[p] = make_float4(xx, yy, zz, 0.f);
    }
    d2[j][0] = 1e10f; d2[j][1] = 1e10f;
  }
  if (tid == 0) idx_out[b * NLAT] = 0;
  __syncthreads();                        // pts table ready

  int last = 0;
  for (int step = 1; step < NLAT; ++step){
    const float4 lp = pts[last];          // uniform addr -> LDS broadcast

    // distance update: pure packed VALU, identical op order to the proven
    // bit-exact version.
    #pragma unroll
    for (int j = 0; j < 8; ++j){
      const f32x2 dx = x2[j] - lp.x;
      const f32x2 dy = y2[j] - lp.y;
      const f32x2 dz = z2[j] - lp.z;
      const f32x2 dd = (dx * dx + dy * dy) + dz * dz;
      f32x2 nd;
      nd[0] = fminf(d2[j][0], dd[0]);
      nd[1] = fminf(d2[j][1], dd[1]);
      d2[j] = nd;
    }

    // in-lane argmax over 16 slots, adjacent-pair tree (index-ordered
    // merges: strict > keeps the lowest index on ties).
    float av[8]; int as_[8];
    #pragma unroll
    for (int j = 0; j < 8; ++j){
      const float lo = d2[j][0], hi = d2[j][1];
      const bool t = hi > lo;
      av[j]  = t ? hi : lo;
      as_[j] = t ? 2 * j + 1 : 2 * j;
    }
    #pragma unroll
    for (int wdt = 4; wdt; wdt >>= 1){
      #pragma unroll
      for (int j = 0; j < wdt; ++j){
        const float lv = av[2 * j], rv = av[2 * j + 1];
        const int   li = as_[2 * j], ri = as_[2 * j + 1];
        const bool t = rv > lv;
        av[j]  = t ? rv : lv;
        as_[j] = t ? ri : li;
      }
    }

    // cross-lane argmax on (value, GLOBAL index); ties -> lower index
    int vb = __float_as_int(av[0]);
    int ib = wbase + (as_[0] << 6) + lane;
    DPP_ARGMAX_STAGE(0x111)   // row_shr:1
    DPP_ARGMAX_STAGE(0x112)   // row_shr:2
    DPP_ARGMAX_STAGE(0x114)   // row_shr:4
    DPP_ARGMAX_STAGE(0x118)   // row_shr:8
    DPP_ARGMAX_STAGE(0x142)   // row_bcast:15
    DPP_ARGMAX_STAGE(0x143)   // row_bcast:31

    // cross-wave merge: 8B write (lane 63), one barrier, 16B broadcast read.
    // Parity buffer -> no second barrier needed.
    const int par = step & 1;
    if (lane == 63){ mbuf[par][w * 2] = vb; mbuf[par][w * 2 + 1] = ib; }
    __syncthreads();
    const int4 q = *(const int4*)&mbuf[par][0];
    const float f0 = __int_as_float(q.x), f1 = __int_as_float(q.z);
    last = (f1 > f0) ? q.w : q.y;         // wave0 indices all smaller: strict >
    if (tid == 0) idx_out[b * NLAT + step] = last;
  }
}

// ---------------------------------------------------------------------------
// Fused (gather) + point_embed x2 + layernorm -> bf16. 16 points / block.
// ---------------------------------------------------------------------------
template<bool GATHER, bool WRITE_EMB>
__global__ __launch_bounds__(256) void embed_kernel(
    const float* __restrict__ pc, const float* __restrict__ pc2,
    const int* __restrict__ idx,
    const float* __restrict__ basis, const float* __restrict__ pe_w,
    const float* __restrict__ pe_b,
    const float* __restrict__ ln_g, const float* __restrict__ ln_b,
    bfu* __restrict__ emb, bfu* __restrict__ lnout, int nppbt)
{
  __shared__ float feat[2][16][NFEAT + 1];
  __shared__ float outb[16][DIMV];
  const int tid = threadIdx.x;
  const int p0 = blockIdx.x << 4;

  if (tid < 32){
    const int s = tid >> 4, p = tid & 15;
    const int gp = p0 + p;
    const int bt = gp / nppbt;
    const int n  = gp - bt * nppbt;
    const int bb = bt / NT;
    const int srcn = GATHER ? idx[bb * NLAT + n] : n;
    const float* sp = (s ? pc2 : pc) + ((size_t)bt * NCTX + srcn) * 3;
    const float x0 = sp[0], x1 = sp[1], x2 = sp[2];
    #pragma unroll
    for (int e = 0; e < 24; ++e){
      const float pr = __fadd_rn(__fadd_rn(__fmul_rn(x0, basis[e]),
                                           __fmul_rn(x1, basis[24 + e])),
                                 __fmul_rn(x2, basis[48 + e]));
      feat[s][p][e]      = sinf(pr);
      feat[s][p][24 + e] = cosf(pr);
    }
    feat[s][p][48] = x0; feat[s][p][49] = x1; feat[s][p][50] = x2;
  }
  __syncthreads();

  {
    float w[NFEAT];
    #pragma unroll
    for (int k = 0; k < NFEAT; ++k) w[k] = pe_w[k * HALFD + tid];
    const float bv = pe_b[tid];
    #pragma unroll
    for (int half = 0; half < 2; ++half){
      for (int p = 0; p < 16; ++p){
        float acc = bv;
        #pragma unroll
        for (int k = 0; k < NFEAT; ++k) acc = fmaf(feat[half][p][k], w[k], acc);
        outb[p][half * HALFD + tid] = acc;
      }
    }
  }
  __syncthreads();

  const int lane = tid & 63, wv = tid >> 6;
  for (int pp = 0; pp < 4; ++pp){
    const int p = (wv << 2) + pp;
    const size_t gp = (size_t)p0 + p;
    float x[8];
    #pragma unroll
    for (int j = 0; j < 8; ++j) x[j] = outb[p][lane + (j << 6)];
    float s = 0.f;
    #pragma unroll
    for (int j = 0; j < 8; ++j) s += x[j];
    for (int o = 32; o; o >>= 1) s += __shfl_xor(s, o, 64);
    const float m = s * (1.0f / 512.0f);
    float s2 = 0.f;
    #pragma unroll
    for (int j = 0; j < 8; ++j){ const float d = x[j] - m; s2 = fmaf(d, d, s2); }
    for (int o = 32; o; o >>= 1) s2 += __shfl_xor(s2, o, 64);
    const float inv = 1.0f / sqrtf(s2 * (1.0f / 512.0f) + 1e-5f);
    #pragma unroll
    for (int j = 0; j < 8; ++j){
      const int c = lane + (j << 6);
      const float r = (x[j] - m) * inv * ln_g[c] + ln_b[c];
      const size_t o2 = gp * DIMV + c;
      if (WRITE_EMB) emb[o2] = f2bf(x[j]);
      lnout[o2] = f2bf(r);
    }
  }
}

// ---------------------------------------------------------------------------
// Tiled transpose: in [R][C] (fp32 or bf16) -> out bf16 [C][R]. 32x32 tiles.
// ---------------------------------------------------------------------------
template<typename TIN>
__global__ __launch_bounds__(256) void transp_kernel(
    const TIN* __restrict__ in, bfu* __restrict__ out, int R, int C,
    long long sIn, long long sOut)
{
  __shared__ bfu t[32][33];
  in  += (size_t)blockIdx.z * sIn;
  out += (size_t)blockIdx.z * sOut;
  const int c0 = blockIdx.x * 32, r0 = blockIdx.y * 32;
  const int tx = threadIdx.x & 31, ty = threadIdx.x >> 5;
  #pragma unroll
  for (int rr = ty; rr < 32; rr += 8)
    t[rr][tx] = to_bfu(in[(size_t)(r0 + rr) * C + c0 + tx]);
  __syncthreads();
  #pragma unroll
  for (int rr = ty; rr < 32; rr += 8)
    out[(size_t)(c0 + rr) * R + r0 + tx] = t[tx][rr];
}

// ---------------------------------------------------------------------------
// MFMA GEMM: C[M][N] = A[M][K] * B[N][K]^T, bf16 inputs.
// Tile = (FH*32)^2: FH=4 -> 128x128, FH=2 -> 64x64. 4 waves 2x2.
// Staging via global_load_lds width=16 (R6: +190us vs reg-staging).
// R7: KSTEP template param -- deeper K per staging round amortizes the
// vmcnt(0)+barrier drain (the dominant non-MFMA cost at KSTEP=32; PV's
// 64-round K-loop was 4x worse compute-per-barrier than the 128^2 GEMMs).
// LDS linear [BT][KSTEP]; 2-way-max bank conflicts via XOR chunk swizzle
// (inverse on per-lane GLOBAL source + same XOR on ds_read -- both sides).
// ---------------------------------------------------------------------------
#define EPI_NONE     0
#define EPI_SPLIT    1
#define EPI_SCALE    2
#define EPI_BIAS_RES 3

template<int FH, int KSTEP, typename TC, typename TR, int EPI>
__global__ __launch_bounds__(256, 2) void gemm_mfma(
    const bfu* __restrict__ A, const bfu* __restrict__ B,
    TC* __restrict__ C, TC* __restrict__ C2,
    const float* __restrict__ bias, const TR* __restrict__ res,
    float scale, int N, int K, int lda, int ldb, int ldc,
    long long sA, long long sB, long long sC)
{
  constexpr int BT  = FH * 32;             // block tile edge
  constexpr int CPR = KSTEP / 8;           // 16B chunks per row
  constexpr int NI  = (BT * CPR) / 256;    // chunk issues per wave per matrix
  const int bz = blockIdx.z;
  A += (size_t)bz * sA;
  B += (size_t)bz * sB;
  const size_t coff = (size_t)bz * sC;

  __shared__ __align__(16) short As[BT * KSTEP];
  __shared__ __align__(16) short Bs[BT * KSTEP];

  const int tid = threadIdx.x;
  const int lane = tid & 63, w = tid >> 6;
  const int wl = (w << 6) + lane;
  const int m0 = blockIdx.y * BT, n0 = blockIdx.x * BT;
  const int wm = (w & 1) * (FH * 16), wn = (w >> 1) * (FH * 16);
  const int fr = lane & 15, quad = lane >> 4;

  f32x4 acc[FH][FH];
  #pragma unroll
  for (int i = 0; i < FH; ++i)
    #pragma unroll
    for (int j = 0; j < FH; ++j)
      #pragma unroll
      for (int r = 0; r < 4; ++r) acc[i][j][r] = 0.f;

  for (int k0 = 0; k0 < K; k0 += KSTEP){
    #pragma unroll
    for (int i = 0; i < NI; ++i){
      const int ch = i * 256 + wl;         // stored chunk: row r, slot cs
      const int r  = ch / CPR, cs = ch & (CPR - 1);
      const int cg = cs ^ swzr<KSTEP>(r);  // global chunk (inverse swizzle)
      short* la = (short*)As + ((i * 256 + (w << 6)) << 3); // wave-uniform
      short* lb = (short*)Bs + ((i * 256 + (w << 6)) << 3);
      GLD16(A + (size_t)(m0 + r) * lda + k0 + cg * 8, la);
      GLD16(B + (size_t)(n0 + r) * ldb + k0 + cg * 8, lb);
    }
    __syncthreads();
    #pragma unroll
    for (int kk = 0; kk < KSTEP / 32; ++kk){
      bf16x8 af[FH], bf[FH];
      #pragma unroll
      for (int i = 0; i < FH; ++i){
        const int row = wm + i * 16 + fr;
        const int cl = (kk * 4 + quad) ^ swzr<KSTEP>(row);
        af[i] = *(const bf16x8*)&As[row * KSTEP + (cl << 3)];
      }
      #pragma unroll
      for (int j = 0; j < FH; ++j){
        const int row = wn + j * 16 + fr;
        const int cl = (kk * 4 + quad) ^ swzr<KSTEP>(row);
        bf[j] = *(const bf16x8*)&Bs[row * KSTEP + (cl << 3)];
      }
      #pragma unroll
      for (int i = 0; i < FH; ++i)
        #pragma unroll
        for (int j = 0; j < FH; ++j)
          acc[i][j] = __builtin_amdgcn_mfma_f32_16x16x32_bf16(af[i], bf[j], acc[i][j], 0, 0, 0);
    }
    __syncthreads();
  }

  // C/D layout: col = lane&15, row = quad*4 + reg
  TC* Cp = C + coff;
  #pragma unroll
  for (int i = 0; i < FH; ++i){
    #pragma unroll
    for (int r = 0; r < 4; ++r){
      const int cm = m0 + wm + i * 16 + quad * 4 + r;
      #pragma unroll
      for (int j = 0; j < FH; ++j){
        const int cn = n0 + wn + j * 16 + fr;
        float v = acc[i][j][r];
        if (EPI == EPI_SCALE)    v *= scale;
        if (EPI == EPI_BIAS_RES) v = v + bias[cn] + loadE(&res[coff + (size_t)cm * ldc + cn]);
        if (EPI == EPI_SPLIT){
          const int half = N >> 1;
          if (cn < half) storeE(&C [(size_t)cm * half + cn],          v);
          else           storeE(&C2[(size_t)cm * half + (cn - half)], v);
        } else {
          storeE(&Cp[(size_t)cm * ldc + cn], v);
        }
      }
    }
  }
}

// ---------------------------------------------------------------------------
// Fused MLP1 + exact GeLU (MFMA): act = (A@w1T[a]+b1a) * gelu(A@w1T[g]+b1g).
// Same global_load_lds + XOR-swizzle staging, KSTEP=64.
// ---------------------------------------------------------------------------
__global__ __launch_bounds__(256, 1) void mlp1_mfma(
    const bfu* __restrict__ A, const bfu* __restrict__ B,  // B = w1T [4096][512]
    const float* __restrict__ b1, bfu* __restrict__ act)
{
  constexpr int KSTEP = 64, CPR = 8, NI = 4;
  __shared__ __align__(16) short As[128 * KSTEP];
  __shared__ __align__(16) short Ba[128 * KSTEP];
  __shared__ __align__(16) short Bg[128 * KSTEP];

  const int tid = threadIdx.x;
  const int lane = tid & 63, w = tid >> 6;
  const int wl = (w << 6) + lane;
  const int m0 = blockIdx.y * 128, n0 = blockIdx.x * 128;
  const int wm = (w & 1) * 64, wn = (w >> 1) * 64;
  const int fr = lane & 15, quad = lane >> 4;

  f32x4 acca[4][4], accg[4][4];
  #pragma unroll
  for (int i = 0; i < 4; ++i)
    #pragma unroll
    for (int j = 0; j < 4; ++j)
      #pragma unroll
      for (int r = 0; r < 4; ++r){ acca[i][j][r] = 0.f; accg[i][j][r] = 0.f; }

  for (int k0 = 0; k0 < 512; k0 += KSTEP){
    #pragma unroll
    for (int i = 0; i < NI; ++i){
      const int ch = i * 256 + wl;
      const int r  = ch / CPR, cs = ch & (CPR - 1);
      const int cg = cs ^ swzr<KSTEP>(r);
      short* da = (short*)As + ((i * 256 + (w << 6)) << 3);
      short* db = (short*)Ba + ((i * 256 + (w << 6)) << 3);
      short* dg = (short*)Bg + ((i * 256 + (w << 6)) << 3);
      GLD16(A + (size_t)(m0 + r) * 512 + k0 + cg * 8, da);
      GLD16(B + (size_t)(n0 + r) * 512 + k0 + cg * 8, db);
      GLD16(B + (size_t)(n0 + 2048 + r) * 512 + k0 + cg * 8, dg);
    }
    __syncthreads();
    #pragma unroll
    for (int kk = 0; kk < KSTEP / 32; ++kk){
      bf16x8 af[4], ba[4], bg[4];
      #pragma unroll
      for (int i = 0; i < 4; ++i){
        const int row = wm + i * 16 + fr;
        const int cl = (kk * 4 + quad) ^ swzr<KSTEP>(row);
        af[i] = *(const bf16x8*)&As[row * KSTEP + (cl << 3)];
      }
      #pragma unroll
      for (int j = 0; j < 4; ++j){
        const int row = wn + j * 16 + fr;
        const int cl = (kk * 4 + quad) ^ swzr<KSTEP>(row);
        ba[j] = *(const bf16x8*)&Ba[row * KSTEP + (cl << 3)];
        bg[j] = *(const bf16x8*)&Bg[row * KSTEP + (cl << 3)];
      }
      #pragma unroll
      for (int i = 0; i < 4; ++i)
        #pragma unroll
        for (int j = 0; j < 4; ++j){
          acca[i][j] = __builtin_amdgcn_mfma_f32_16x16x32_bf16(af[i], ba[j], acca[i][j], 0, 0, 0);
          accg[i][j] = __builtin_amdgcn_mfma_f32_16x16x32_bf16(af[i], bg[j], accg[i][j], 0, 0, 0);
        }
    }
    __syncthreads();
  }

  #pragma unroll
  for (int i = 0; i < 4; ++i){
    #pragma unroll
    for (int r = 0; r < 4; ++r){
      const int cm = m0 + wm + i * 16 + quad * 4 + r;
      #pragma unroll
      for (int j = 0; j < 4; ++j){
        const int cn = n0 + wn + j * 16 + fr;
        const float a = acca[i][j][r] + b1[cn];
        const float g = accg[i][j][r] + b1[cn + 2048];
        const float ge = g * 0.5f * (1.0f + erff(g * 0.70710678118654752f));
        act[(size_t)cm * 2048 + cn] = f2bf(a * ge);
      }
    }
  }
}

// ---------------------------------------------------------------------------
// Row softmax over 2048 bf16 logits, in place.
// ---------------------------------------------------------------------------
__global__ __launch_bounds__(256) void softmax_kernel(bfu* __restrict__ sc){
  __shared__ float red[4];
  const int tid = threadIdx.x;
  const int lane = tid & 63, wv = tid >> 6;
  bfu* rp = sc + (size_t)blockIdx.x * NCTX;
  float x[8];
  #pragma unroll
  for (int j = 0; j < 8; ++j) x[j] = bf2f(rp[tid + (j << 8)]);
  float mx = x[0];
  #pragma unroll
  for (int j = 1; j < 8; ++j) mx = fmaxf(mx, x[j]);
  for (int o = 32; o; o >>= 1) mx = fmaxf(mx, __shfl_xor(mx, o, 64));
  if (lane == 0) red[wv] = mx;
  __syncthreads();
  mx = fmaxf(fmaxf(red[0], red[1]), fmaxf(red[2], red[3]));
  float sum = 0.f;
  #pragma unroll
  for (int j = 0; j < 8; ++j){ x[j] = __expf(x[j] - mx); sum += x[j]; }
  for (int o = 32; o; o >>= 1) sum += __shfl_xor(sum, o, 64);
  __syncthreads();
  if (lane == 0) red[wv] = sum;
  __syncthreads();
  sum = red[0] + red[1] + red[2] + red[3];
  const float inv = 1.0f / sum;
  #pragma unroll
  for (int j = 0; j < 8; ++j) rp[tid + (j << 8)] = f2bf(x[j] * inv);
}

// ---------------------------------------------------------------------------
// LayerNorm rows of 512 fp32 -> bf16.
// ---------------------------------------------------------------------------
__global__ __launch_bounds__(256) void ln_kernel(const float* __restrict__ in,
                                                 const float* __restrict__ g,
                                                 const float* __restrict__ b,
                                                 bfu* __restrict__ out){
  const int tid = threadIdx.x, lane = tid & 63, wv = tid >> 6;
  const size_t row = (size_t)blockIdx.x * 4 + wv;
  const float* rp = in + row * DIMV;
  float x[8];
  #pragma unroll
  for (int j = 0; j < 8; ++j) x[j] = rp[lane + (j << 6)];
  float s = 0.f;
  #pragma unroll
  for (int j = 0; j < 8; ++j) s += x[j];
  for (int o = 32; o; o >>= 1) s += __shfl_xor(s, o, 64);
  const float m = s * (1.0f / 512.0f);
  float s2 = 0.f;
  #pragma unroll
  for (int j = 0; j < 8; ++j){ const float d = x[j] - m; s2 = fmaf(d, d, s2); }
  for (int o = 32; o; o >>= 1) s2 += __shfl_xor(s2, o, 64);
  const float inv = 1.0f / sqrtf(s2 * (1.0f / 512.0f) + 1e-5f);
  bfu* op = out + row * DIMV;
  #pragma unroll
  for (int j = 0; j < 8; ++j){
    const int c = lane + (j << 6);
    op[c] = f2bf((x[j] - m) * inv * g[c] + b[c]);
  }
}

// ---------------------------------------------------------------------------
// Workspace (peak 121,667,584 B < proven 125,861,888):
//   idx    @ 0          (32 KB)
//   emb_s  @ 32768      (25,165,824) \  act half (50,331,648) aliases
//   q_in   @ 25198592   (25,165,824) /  emb_s+q_in (both dead at MLP)
//          q_in -> attnout after q GEMM
//   c_grp  @ 50364416   (12,582,912) -> scores (GRP=6)
//   k_grp  @ 62947328   (12,582,912) -> vT (k dead after scores; group loop
//                                          order: ...scores, softmax, transp, pv)
//   v_grp  @ 75530240   (12,582,912)
//   qbuf   @ 88113152   (25,165,824) -> lnx
//   wT     @ 113278976  (8,388,608): wqT|wkvT|woT|w1T|w2T
// ---------------------------------------------------------------------------
extern "C" void kernel_launch(void* const* d_in, const int* in_sizes, int n_in,
                              void* d_out, int out_size, void* d_ws, size_t ws_size,
                              hipStream_t stream)
{
  (void)in_sizes; (void)n_in; (void)out_size;
  if (ws_size < 121667584ull) return;

  const float* pc    = (const float*)d_in[0];
  const float* pc2   = (const float*)d_in[1];
  const float* basis = (const float*)d_in[2];
  const float* pe_w  = (const float*)d_in[3];
  const float* pe_b  = (const float*)d_in[4];
  const float* lnq_g = (const float*)d_in[5];
  const float* lnq_b = (const float*)d_in[6];
  const float* lnc_g = (const float*)d_in[7];
  const float* lnc_b = (const float*)d_in[8];
  const float* wq    = (const float*)d_in[9];
  const float* wkv   = (const float*)d_in[10];
  const float* wo    = (const float*)d_in[11];
  const float* bo    = (const float*)d_in[12];
  const float* lnf_g = (const float*)d_in[13];
  const float* lnf_b = (const float*)d_in[14];
  const float* w1    = (const float*)d_in[15];
  const float* b1    = (const float*)d_in[16];
  const float* w2    = (const float*)d_in[17];
  const float* b2    = (const float*)d_in[18];
  float* xout = (float*)d_out;

  char* ws = (char*)d_ws;
  int* idxb   = (int*)(ws);
  bfu* emb_s  = (bfu*)(ws + 32768);
  bfu* q_in   = (bfu*)(ws + 25198592);
  bfu* c_grp  = (bfu*)(ws + 50364416);
  bfu* k_grp  = (bfu*)(ws + 62947328);
  bfu* v_grp  = (bfu*)(ws + 75530240);
  bfu* qbuf   = (bfu*)(ws + 88113152);
  bfu* wqT    = (bfu*)(ws + 113278976);
  bfu* wkvT   = (bfu*)(ws + 113803264);
  bfu* woT    = (bfu*)(ws + 114851840);
  bfu* w1T    = (bfu*)(ws + 115376128);
  bfu* w2T    = (bfu*)(ws + 119570432);
  bfu* scores  = c_grp;     // after c consumed by kv
  bfu* vT      = k_grp;     // after k consumed by scores
  bfu* attnout = q_in;      // after q GEMM consumed q_in
  bfu* lnx     = qbuf;      // after attention consumed q
  bfu* actb    = emb_s;     // spans emb_s+q_in (one MLP half at a time)

  // 0. weight transposes (fp32 [K][N] -> bf16 [N][K])
  transp_kernel<float><<<dim3(16, 16, 1),  256, 0, stream>>>(wq,  wqT,  512,  512, 0, 0);
  transp_kernel<float><<<dim3(32, 16, 1),  256, 0, stream>>>(wkv, wkvT, 512, 1024, 0, 0);
  transp_kernel<float><<<dim3(16, 16, 1),  256, 0, stream>>>(wo,  woT,  512,  512, 0, 0);
  transp_kernel<float><<<dim3(128, 16, 1), 256, 0, stream>>>(w1,  w1T,  512, 4096, 0, 0);
  transp_kernel<float><<<dim3(16, 64, 1),  256, 0, stream>>>(w2,  w2T, 2048,  512, 0, 0);

  // 1. FPS (2 waves per batch, register-resident coords, 1 barrier/step)
  fps_kernel<<<NB, 128, 0, stream>>>(pc, idxb);

  // 2. latent embed -> emb_s (raw) + q_in (LN'd)
  embed_kernel<true, true><<<MROWS/16, 256, 0, stream>>>(
      pc, pc2, idxb, basis, pe_w, pe_b, lnq_g, lnq_b, emb_s, q_in, NLAT);

  // 3. q = q_in @ wq
  gemm_mfma<4, 64, bfu, float, EPI_NONE><<<dim3(4, 192, 1), 256, 0, stream>>>(
      q_in, wqT, qbuf, nullptr, nullptr, nullptr, 1.0f,
      512, 512, 512, 512, 512, 0, 0, 0);

  // 4. per-group context pipeline (GRP=6, 8 groups)
  for (int g = 0; g < NGRP; ++g){
    const int bt0 = g * GRP;
    embed_kernel<false, false><<<GROWS/16, 256, 0, stream>>>(
        pc + (size_t)bt0 * NCTX * 3, pc2 + (size_t)bt0 * NCTX * 3, nullptr,
        basis, pe_w, pe_b, lnc_g, lnc_b, nullptr, c_grp, NCTX);

    // kv = c @ wkv -> split k | v
    gemm_mfma<4, 64, bfu, float, EPI_SPLIT><<<dim3(8, 96, 1), 256, 0, stream>>>(
        c_grp, wkvT, k_grp, v_grp, nullptr, nullptr, 1.0f,
        1024, 512, 512, 512, 512, 0, 0, 0);

    // scores = (q @ k^T) * scale (overwrites c_grp region)
    gemm_mfma<4, 64, bfu, float, EPI_SCALE><<<dim3(16, 4, GRP), 256, 0, stream>>>(
        qbuf + (size_t)bt0 * 262144, k_grp, scores, nullptr, nullptr, nullptr,
        0.044194173824159216f,
        2048, 512, 512, 512, 2048, 262144, 1048576, 1048576);

    softmax_kernel<<<GRP * 512, 256, 0, stream>>>(scores);

    // vT = transpose(v) per bt (overwrites k_grp; k dead after scores)
    transp_kernel<bfu><<<dim3(16, 64, GRP), 256, 0, stream>>>(
        v_grp, vT, 2048, 512, 2048*512, 2048*512);

    // attnout = P @ V : 64x64 tiles, KSTEP=128 (16 staging rounds vs 64)
    gemm_mfma<2, 128, bfu, float, EPI_NONE><<<dim3(8, 8, GRP), 256, 0, stream>>>(
        scores, vT, attnout + (size_t)bt0 * 262144, nullptr, nullptr, nullptr, 1.0f,
        512, 2048, 2048, 2048, 512, 1048576, 1048576, 262144);
  }

  // 5. x = attnout @ wo + bo + emb_s -> d_out (fp32)
  gemm_mfma<4, 64, float, bfu, EPI_BIAS_RES><<<dim3(4, 192, 1), 256, 0, stream>>>(
      attnout, woT, xout, nullptr, bo, emb_s, 1.0f,
      512, 512, 512, 512, 512, 0, 0, 0);

  // 6. lnx = LN(x)
  ln_kernel<<<MROWS/4, 256, 0, stream>>>(xout, lnf_g, lnf_b, lnx);

  // 7/8. MLP in two row-halves (act buffer holds one half)
  for (int h = 0; h < 2; ++h){
    const size_t ro = (size_t)h * 12288;
    mlp1_mfma<<<dim3(16, 96, 1), 256, 0, stream>>>(
        lnx + ro * 512, w1T, b1, actb);
    gemm_mfma<4, 64, float, float, EPI_BIAS_RES><<<dim3(4, 96, 1), 256, 0, stream>>>(
        actb, w2T, xout + ro * 512, nullptr, b2, xout + ro * 512, 1.0f,
        512, 2048, 2048, 2048, 512, 0, 0, 0);
  }
}

// Round 9
// 1702.663 us; speedup vs baseline: 1.3257x; 1.0258x over previous
//
#include <hip/hip_runtime.h>

// Problem constants
#define NB    16
#define NT    3
#define NCTX  2048
#define NLAT  512
#define DIMV  512
#define HALFD 256
#define NFEAT 51
#define NBT   48
#define MROWS 24576    // NBT*NLAT
#define GRP   6        // bt per context group
#define NGRP  8
#define GROWS 12288    // GRP*NCTX
#define FUSED_BLKS (NB + GROWS/16 + 4096)   // fps + g0 embed + 5 transposes

typedef unsigned short bfu;   // bf16 storage as raw bits
typedef short bf16x8 __attribute__((ext_vector_type(8)));   // 8 bf16 = 4 VGPR
typedef float f32x4  __attribute__((ext_vector_type(4)));   // MFMA 16x16 acc
typedef float f32x2  __attribute__((ext_vector_type(2)));   // packed fp32 pair

__device__ __forceinline__ float bf2f(bfu u){ return __uint_as_float(((unsigned int)u) << 16); }
__device__ __forceinline__ bfu f2bf(float f){
  unsigned int u = __float_as_uint(f);
  u += 0x7FFFu + ((u >> 16) & 1u);          // RNE
  return (bfu)(u >> 16);
}
__device__ __forceinline__ float loadE(const float* p){ return *p; }
__device__ __forceinline__ float loadE(const bfu* p){ return bf2f(*p); }
__device__ __forceinline__ void storeE(float* p, float v){ *p = v; }
__device__ __forceinline__ void storeE(bfu* p, float v){ *p = f2bf(v); }
__device__ __forceinline__ bfu to_bfu(float f){ return f2bf(f); }
__device__ __forceinline__ bfu to_bfu(bfu u){ return u; }

// Async 16B global->LDS DMA. LDS dest = wave-uniform base + lane*16 (linear!)
// so swizzled layouts are achieved by pre-swizzling the per-lane GLOBAL
// source address (m173 pattern), never the LDS dest.
#define GLD16(gp, lp) __builtin_amdgcn_global_load_lds(                       \
    (const __attribute__((address_space(1))) unsigned int*)(gp),              \
    (__attribute__((address_space(3))) unsigned int*)(lp), 16, 0, 0)

// XOR chunk swizzle key for a [*][KSTEP] bf16 LDS tile (16B chunks).
template<int KSTEP>
__device__ __forceinline__ int swzr(int r){
  constexpr int CPR = KSTEP / 8;
  return (KSTEP == 32) ? ((r >> 1) & 3) : (r & (CPR - 1));
}

// ---------------------------------------------------------------------------
// FPS core: TWO waves per batch, coords REGISTER-resident. Proven best
// (R6: 390us). Tie-breaks preserve numpy first-max exactly; distance
// expression bit-exact (contract(off) applied by the caller's scope).
// Waves 2-3 of the 256-thread fused block spin on 512 matching barriers.
// ---------------------------------------------------------------------------
#define DPP_ARGMAX_STAGE(CTRL)                                                \
  {                                                                           \
    const int svb = __builtin_amdgcn_update_dpp(vb, vb, CTRL, 0xF, 0xF, false); \
    const int sib = __builtin_amdgcn_update_dpp(ib, ib, CTRL, 0xF, 0xF, false); \
    const float sv = __int_as_float(svb);                                     \
    const float cv = __int_as_float(vb);                                      \
    if (sv > cv || (sv == cv && sib < ib)){ vb = svb; ib = sib; }             \
  }

__device__ __forceinline__ void fps_body(int b, int tid, const float* __restrict__ pc,
                                         int* __restrict__ idx_out,
                                         float4* pts, int (*mbuf)[4]){
  const int lane = tid & 63, w = tid >> 6;
  const int wbase = w << 10;              // wave owns [1024w, 1024w+1024)
  const float* src = pc + (size_t)b * (NT * NCTX * 3);

  f32x2 x2[8], y2[8], z2[8], d2[8];
  #pragma unroll
  for (int j = 0; j < 8; ++j){
    #pragma unroll
    for (int h = 0; h < 2; ++h){
      const int p = wbase + ((2 * j + h) << 6) + lane;
      const float xx = src[p * 3 + 0];
      const float yy = src[p * 3 + 1];
      const float zz = src[p * 3 + 2];
      x2[j][h] = xx; y2[j][h] = yy; z2[j][h] = zz;
      pts[p] = make_float4(xx, yy, zz, 0.f);
    }
    d2[j][0] = 1e10f; d2[j][1] = 1e10f;
  }
  if (tid == 0) idx_out[b * NLAT] = 0;
  __syncthreads();                        // barrier #1

  int last = 0;
  for (int step = 1; step < NLAT; ++step){
    const float4 lp = pts[last];          // uniform addr -> LDS broadcast

    #pragma unroll
    for (int j = 0; j < 8; ++j){
      const f32x2 dx = x2[j] - lp.x;
      const f32x2 dy = y2[j] - lp.y;
      const f32x2 dz = z2[j] - lp.z;
      const f32x2 dd = (dx * dx + dy * dy) + dz * dz;
      f32x2 nd;
      nd[0] = fminf(d2[j][0], dd[0]);
      nd[1] = fminf(d2[j][1], dd[1]);
      d2[j] = nd;
    }

    float av[8]; int as_[8];
    #pragma unroll
    for (int j = 0; j < 8; ++j){
      const float lo = d2[j][0], hi = d2[j][1];
      const bool t = hi > lo;
      av[j]  = t ? hi : lo;
      as_[j] = t ? 2 * j + 1 : 2 * j;
    }
    #pragma unroll
    for (int wdt = 4; wdt; wdt >>= 1){
      #pragma unroll
      for (int j = 0; j < wdt; ++j){
        const float lv = av[2 * j], rv = av[2 * j + 1];
        const int   li = as_[2 * j], ri = as_[2 * j + 1];
        const bool t = rv > lv;
        av[j]  = t ? rv : lv;
        as_[j] = t ? ri : li;
      }
    }

    int vb = __float_as_int(av[0]);
    int ib = wbase + (as_[0] << 6) + lane;
    DPP_ARGMAX_STAGE(0x111)   // row_shr:1
    DPP_ARGMAX_STAGE(0x112)   // row_shr:2
    DPP_ARGMAX_STAGE(0x114)   // row_shr:4
    DPP_ARGMAX_STAGE(0x118)   // row_shr:8
    DPP_ARGMAX_STAGE(0x142)   // row_bcast:15
    DPP_ARGMAX_STAGE(0x143)   // row_bcast:31

    const int par = step & 1;
    if (lane == 63){ mbuf[par][w * 2] = vb; mbuf[par][w * 2 + 1] = ib; }
    __syncthreads();                      // barriers #2..#512
    const int4 q = *(const int4*)&mbuf[par][0];
    const float f0 = __int_as_float(q.x), f1 = __int_as_float(q.z);
    last = (f1 > f0) ? q.w : q.y;         // wave0 indices all smaller: strict >
    if (tid == 0) idx_out[b * NLAT + step] = last;
  }
}

// ---------------------------------------------------------------------------
// Embed body: gather + point_embed x2 + layernorm -> bf16. 16 points/block.
// R8: phase-1 trig parallelized over all 256 threads (3 sin/cos pairs each,
// was 24 pairs on 32 threads with 224 idle). Bit-exact: identical
// __fmul_rn/__fadd_rn chain and sinf/cosf calls, just redistributed; coords
// staged through feat[s][p][48..50] (same fp32 bits).
// ---------------------------------------------------------------------------
template<bool GATHER, bool WRITE_EMB>
__device__ __forceinline__ void embed_body(
    int bid, int tid,
    const float* __restrict__ pc, const float* __restrict__ pc2,
    const int* __restrict__ idx,
    const float* __restrict__ basis, const float* __restrict__ pe_w,
    const float* __restrict__ pe_b,
    const float* __restrict__ ln_g, const float* __restrict__ ln_b,
    bfu* __restrict__ emb, bfu* __restrict__ lnout, int nppbt,
    float (*feat)[16][NFEAT + 1], float (*outb)[DIMV])
{
  const int p0 = bid << 4;

  if (tid < 32){
    const int s = tid >> 4, p = tid & 15;
    const int gp = p0 + p;
    const int bt = gp / nppbt;
    const int n  = gp - bt * nppbt;
    const int bb = bt / NT;
    const int srcn = GATHER ? idx[bb * NLAT + n] : n;
    const float* sp = (s ? pc2 : pc) + ((size_t)bt * NCTX + srcn) * 3;
    feat[s][p][48] = sp[0]; feat[s][p][49] = sp[1]; feat[s][p][50] = sp[2];
  }
  __syncthreads();

  #pragma unroll
  for (int t = 0; t < 3; ++t){
    const int wk  = tid * 3 + t;          // [0,768): (s*16+p)*24 + e
    const int spq = wk / 24;
    const int e   = wk - spq * 24;
    const int s = spq >> 4, p = spq & 15;
    const float x0 = feat[s][p][48], x1 = feat[s][p][49], x2 = feat[s][p][50];
    const float pr = __fadd_rn(__fadd_rn(__fmul_rn(x0, basis[e]),
                                         __fmul_rn(x1, basis[24 + e])),
                               __fmul_rn(x2, basis[48 + e]));
    feat[s][p][e]      = sinf(pr);
    feat[s][p][24 + e] = cosf(pr);
  }
  __syncthreads();

  {
    float w[NFEAT];
    #pragma unroll
    for (int k = 0; k < NFEAT; ++k) w[k] = pe_w[k * HALFD + tid];
    const float bv = pe_b[tid];
    #pragma unroll
    for (int half = 0; half < 2; ++half){
      for (int p = 0; p < 16; ++p){
        float acc = bv;
        #pragma unroll
        for (int k = 0; k < NFEAT; ++k) acc = fmaf(feat[half][p][k], w[k], acc);
        outb[p][half * HALFD + tid] = acc;
      }
    }
  }
  __syncthreads();

  const int lane = tid & 63, wv = tid >> 6;
  for (int pp = 0; pp < 4; ++pp){
    const int p = (wv << 2) + pp;
    const size_t gp = (size_t)p0 + p;
    float x[8];
    #pragma unroll
    for (int j = 0; j < 8; ++j) x[j] = outb[p][lane + (j << 6)];
    float s = 0.f;
    #pragma unroll
    for (int j = 0; j < 8; ++j) s += x[j];
    for (int o = 32; o; o >>= 1) s += __shfl_xor(s, o, 64);
    const float m = s * (1.0f / 512.0f);
    float s2 = 0.f;
    #pragma unroll
    for (int j = 0; j < 8; ++j){ const float d = x[j] - m; s2 = fmaf(d, d, s2); }
    for (int o = 32; o; o >>= 1) s2 += __shfl_xor(s2, o, 64);
    const float inv = 1.0f / sqrtf(s2 * (1.0f / 512.0f) + 1e-5f);
    #pragma unroll
    for (int j = 0; j < 8; ++j){
      const int c = lane + (j << 6);
      const float r = (x[j] - m) * inv * ln_g[c] + ln_b[c];
      const size_t o2 = gp * DIMV + c;
      if (WRITE_EMB) emb[o2] = f2bf(x[j]);
      lnout[o2] = f2bf(r);
    }
  }
}

template<bool GATHER, bool WRITE_EMB>
__global__ __launch_bounds__(256) void embed_kernel(
    const float* __restrict__ pc, const float* __restrict__ pc2,
    const int* __restrict__ idx,
    const float* __restrict__ basis, const float* __restrict__ pe_w,
    const float* __restrict__ pe_b,
    const float* __restrict__ ln_g, const float* __restrict__ ln_b,
    bfu* __restrict__ emb, bfu* __restrict__ lnout, int nppbt)
{
  __shared__ float feat[2][16][NFEAT + 1];
  __shared__ float outb[16][DIMV];
  embed_body<GATHER, WRITE_EMB>(blockIdx.x, threadIdx.x, pc, pc2, idx, basis,
      pe_w, pe_b, ln_g, ln_b, emb, lnout, nppbt, feat, outb);
}

// ---------------------------------------------------------------------------
// Transpose body: in [R][C] (fp32 or bf16) -> out bf16 [C][R]. 32x32 tiles.
// ---------------------------------------------------------------------------
template<typename TIN>
__device__ __forceinline__ void transp_body(
    const TIN* __restrict__ in, bfu* __restrict__ out, int R, int C,
    int bx, int by, bfu (*t)[33])
{
  const int c0 = bx * 32, r0 = by * 32;
  const int tx = threadIdx.x & 31, ty = threadIdx.x >> 5;
  #pragma unroll
  for (int rr = ty; rr < 32; rr += 8)
    t[rr][tx] = to_bfu(in[(size_t)(r0 + rr) * C + c0 + tx]);
  __syncthreads();
  #pragma unroll
  for (int rr = ty; rr < 32; rr += 8)
    out[(size_t)(c0 + rr) * R + r0 + tx] = t[tx][rr];
}

template<typename TIN>
__global__ __launch_bounds__(256) void transp_kernel(
    const TIN* __restrict__ in, bfu* __restrict__ out, int R, int C,
    long long sIn, long long sOut)
{
  __shared__ bfu t[32][33];
  transp_body<TIN>(in + (size_t)blockIdx.z * sIn, out + (size_t)blockIdx.z * sOut,
                   R, C, blockIdx.x, blockIdx.y, t);
}

// ---------------------------------------------------------------------------
// fused_pre: one launch hiding FPS-independent work under FPS's 389us
// shadow on the 240 idle CUs. Blocks [0,16): FPS (waves 2-3 spin 512
// matching barriers). [16,784): context embed group 0 -> c_grp. [784,4880):
// the 5 weight transposes. waves_per_eu(1,1) keeps the fps path's VGPR
// grant (132, R3-R6); embed/transp blocks run 1 block/CU but only need to
// finish within fps's shadow (~50us worst case << 389us).
// ---------------------------------------------------------------------------
__global__ __attribute__((amdgpu_waves_per_eu(1, 1)))
__launch_bounds__(256) void fused_pre(
    const float* __restrict__ pc, const float* __restrict__ pc2,
    int* __restrict__ idx_out,
    const float* __restrict__ basis, const float* __restrict__ pe_w,
    const float* __restrict__ pe_b,
    const float* __restrict__ lnc_g, const float* __restrict__ lnc_b,
    bfu* __restrict__ c_grp,
    const float* __restrict__ wq, const float* __restrict__ wkv,
    const float* __restrict__ wo, const float* __restrict__ w1,
    const float* __restrict__ w2,
    bfu* __restrict__ wqT, bfu* __restrict__ wkvT, bfu* __restrict__ woT,
    bfu* __restrict__ w1T, bfu* __restrict__ w2T)
{
  __shared__ __align__(16) char smem[39424];  // max(fps 32800, embed 39424, transp 2112)
  const int bid = blockIdx.x, tid = threadIdx.x;

  if (bid < NB){
    #pragma clang fp contract(off)
    float4* pts = (float4*)smem;
    int (*mbuf)[4] = (int(*)[4])(smem + 32768);
    if (tid < 128){
      fps_body(bid, tid, pc, idx_out, pts, mbuf);
    } else {
      for (int i = 0; i < NLAT; ++i) __syncthreads();  // match fps's 512 barriers
    }
    return;
  }
  const int rb = bid - NB;
  if (rb < GROWS / 16){
    embed_body<false, false>(rb, tid, pc, pc2, nullptr, basis, pe_w, pe_b,
                             lnc_g, lnc_b, nullptr, c_grp, NCTX,
                             (float(*)[16][NFEAT + 1])smem,
                             (float(*)[DIMV])(smem + 6656));
    return;
  }
  int tb = rb - GROWS / 16;
  bfu (*tile)[33] = (bfu(*)[33])smem;
  if (tb < 256){ transp_body<float>(wq,  wqT,  512,  512, tb & 15,  tb >> 4, tile); return; }
  tb -= 256;
  if (tb < 512){ transp_body<float>(wkv, wkvT, 512, 1024, tb & 31,  tb >> 5, tile); return; }
  tb -= 512;
  if (tb < 256){ transp_body<float>(wo,  woT,  512,  512, tb & 15,  tb >> 4, tile); return; }
  tb -= 256;
  if (tb < 2048){ transp_body<float>(w1, w1T,  512, 4096, tb & 127, tb >> 7, tile); return; }
  tb -= 2048;
  transp_body<float>(w2, w2T, 2048, 512, tb & 15, tb >> 4, tile);
}

// ---------------------------------------------------------------------------
// MFMA GEMM: C[M][N] = A[M][K] * B[N][K]^T, bf16 inputs.
// Tile = (FH*32)^2: FH=4 -> 128x128, FH=2 -> 64x64. 4 waves 2x2.
// global_load_lds width=16 staging (R6) + KSTEP-deep barrier amortization
// (R7). LDS linear [BT][KSTEP]; 2-way-max bank conflicts via XOR chunk
// swizzle (inverse on per-lane GLOBAL source + same XOR on ds_read).
// ---------------------------------------------------------------------------
#define EPI_NONE     0
#define EPI_SPLIT    1
#define EPI_SCALE    2
#define EPI_BIAS_RES 3

template<int FH, int KSTEP, typename TC, typename TR, int EPI>
__global__ __launch_bounds__(256, 2) void gemm_mfma(
    const bfu* __restrict__ A, const bfu* __restrict__ B,
    TC* __restrict__ C, TC* __restrict__ C2,
    const float* __restrict__ bias, const TR* __restrict__ res,
    float scale, int N, int K, int lda, int ldb, int ldc,
    long long sA, long long sB, long long sC)
{
  constexpr int BT  = FH * 32;             // block tile edge
  constexpr int CPR = KSTEP / 8;           // 16B chunks per row
  constexpr int NI  = (BT * CPR) / 256;    // chunk issues per wave per matrix
  const int bz = blockIdx.z;
  A += (size_t)bz * sA;
  B += (size_t)bz * sB;
  const size_t coff = (size_t)bz * sC;

  __shared__ __align__(16) short As[BT * KSTEP];
  __shared__ __align__(16) short Bs[BT * KSTEP];

  const int tid = threadIdx.x;
  const int lane = tid & 63, w = tid >> 6;
  const int wl = (w << 6) + lane;
  const int m0 = blockIdx.y * BT, n0 = blockIdx.x * BT;
  const int wm = (w & 1) * (FH * 16), wn = (w >> 1) * (FH * 16);
  const int fr = lane & 15, quad = lane >> 4;

  f32x4 acc[FH][FH];
  #pragma unroll
  for (int i = 0; i < FH; ++i)
    #pragma unroll
    for (int j = 0; j < FH; ++j)
      #pragma unroll
      for (int r = 0; r < 4; ++r) acc[i][j][r] = 0.f;

  for (int k0 = 0; k0 < K; k0 += KSTEP){
    #pragma unroll
    for (int i = 0; i < NI; ++i){
      const int ch = i * 256 + wl;         // stored chunk: row r, slot cs
      const int r  = ch / CPR, cs = ch & (CPR - 1);
      const int cg = cs ^ swzr<KSTEP>(r);  // global chunk (inverse swizzle)
      short* la = (short*)As + ((i * 256 + (w << 6)) << 3); // wave-uniform
      short* lb = (short*)Bs + ((i * 256 + (w << 6)) << 3);
      GLD16(A + (size_t)(m0 + r) * lda + k0 + cg * 8, la);
      GLD16(B + (size_t)(n0 + r) * ldb + k0 + cg * 8, lb);
    }
    __syncthreads();
    #pragma unroll
    for (int kk = 0; kk < KSTEP / 32; ++kk){
      bf16x8 af[FH], bf[FH];
      #pragma unroll
      for (int i = 0; i < FH; ++i){
        const int row = wm + i * 16 + fr;
        const int cl = (kk * 4 + quad) ^ swzr<KSTEP>(row);
        af[i] = *(const bf16x8*)&As[row * KSTEP + (cl << 3)];
      }
      #pragma unroll
      for (int j = 0; j < FH; ++j){
        const int row = wn + j * 16 + fr;
        const int cl = (kk * 4 + quad) ^ swzr<KSTEP>(row);
        bf[j] = *(const bf16x8*)&Bs[row * KSTEP + (cl << 3)];
      }
      #pragma unroll
      for (int i = 0; i < FH; ++i)
        #pragma unroll
        for (int j = 0; j < FH; ++j)
          acc[i][j] = __builtin_amdgcn_mfma_f32_16x16x32_bf16(af[i], bf[j], acc[i][j], 0, 0, 0);
    }
    __syncthreads();
  }

  // C/D layout: col = lane&15, row = quad*4 + reg
  TC* Cp = C + coff;
  #pragma unroll
  for (int i = 0; i < FH; ++i){
    #pragma unroll
    for (int r = 0; r < 4; ++r){
      const int cm = m0 + wm + i * 16 + quad * 4 + r;
      #pragma unroll
      for (int j = 0; j < FH; ++j){
        const int cn = n0 + wn + j * 16 + fr;
        float v = acc[i][j][r];
        if (EPI == EPI_SCALE)    v *= scale;
        if (EPI == EPI_BIAS_RES) v = v + bias[cn] + loadE(&res[coff + (size_t)cm * ldc + cn]);
        if (EPI == EPI_SPLIT){
          const int half = N >> 1;
          if (cn < half) storeE(&C [(size_t)cm * half + cn],          v);
          else           storeE(&C2[(size_t)cm * half + (cn - half)], v);
        } else {
          storeE(&Cp[(size_t)cm * ldc + cn], v);
        }
      }
    }
  }
}

// ---------------------------------------------------------------------------
// Fused MLP1 + exact GeLU (MFMA): act = (A@w1T[a]+b1a) * gelu(A@w1T[g]+b1g).
// Same global_load_lds + XOR-swizzle staging, KSTEP=64.
// ---------------------------------------------------------------------------
__global__ __launch_bounds__(256, 1) void mlp1_mfma(
    const bfu* __restrict__ A, const bfu* __restrict__ B,  // B = w1T [4096][512]
    const float* __restrict__ b1, bfu* __restrict__ act)
{
  constexpr int KSTEP = 64, CPR = 8, NI = 4;
  __shared__ __align__(16) short As[128 * KSTEP];
  __shared__ __align__(16) short Ba[128 * KSTEP];
  __shared__ __align__(16) short Bg[128 * KSTEP];

  const int tid = threadIdx.x;
  const int lane = tid & 63, w = tid >> 6;
  const int wl = (w << 6) + lane;
  const int m0 = blockIdx.y * 128, n0 = blockIdx.x * 128;
  const int wm = (w & 1) * 64, wn = (w >> 1) * 64;
  const int fr = lane & 15, quad = lane >> 4;

  f32x4 acca[4][4], accg[4][4];
  #pragma unroll
  for (int i = 0; i < 4; ++i)
    #pragma unroll
    for (int j = 0; j < 4; ++j)
      #pragma unroll
      for (int r = 0; r < 4; ++r){ acca[i][j][r] = 0.f; accg[i][j][r] = 0.f; }

  for (int k0 = 0; k0 < 512; k0 += KSTEP){
    #pragma unroll
    for (int i = 0; i < NI; ++i){
      const int ch = i * 256 + wl;
      const int r  = ch / CPR, cs = ch & (CPR - 1);
      const int cg = cs ^ swzr<KSTEP>(r);
      short* da = (short*)As + ((i * 256 + (w << 6)) << 3);
      short* db = (short*)Ba + ((i * 256 + (w << 6)) << 3);
      short* dg = (short*)Bg + ((i * 256 + (w << 6)) << 3);
      GLD16(A + (size_t)(m0 + r) * 512 + k0 + cg * 8, da);
      GLD16(B + (size_t)(n0 + r) * 512 + k0 + cg * 8, db);
      GLD16(B + (size_t)(n0 + 2048 + r) * 512 + k0 + cg * 8, dg);
    }
    __syncthreads();
    #pragma unroll
    for (int kk = 0; kk < KSTEP / 32; ++kk){
      bf16x8 af[4], ba[4], bg[4];
      #pragma unroll
      for (int i = 0; i < 4; ++i){
        const int row = wm + i * 16 + fr;
        const int cl = (kk * 4 + quad) ^ swzr<KSTEP>(row);
        af[i] = *(const bf16x8*)&As[row * KSTEP + (cl << 3)];
      }
      #pragma unroll
      for (int j = 0; j < 4; ++j){
        const int row = wn + j * 16 + fr;
        const int cl = (kk * 4 + quad) ^ swzr<KSTEP>(row);
        ba[j] = *(const bf16x8*)&Ba[row * KSTEP + (cl << 3)];
        bg[j] = *(const bf16x8*)&Bg[row * KSTEP + (cl << 3)];
      }
      #pragma unroll
      for (int i = 0; i < 4; ++i)
        #pragma unroll
        for (int j = 0; j < 4; ++j){
          acca[i][j] = __builtin_amdgcn_mfma_f32_16x16x32_bf16(af[i], ba[j], acca[i][j], 0, 0, 0);
          accg[i][j] = __builtin_amdgcn_mfma_f32_16x16x32_bf16(af[i], bg[j], accg[i][j], 0, 0, 0);
        }
    }
    __syncthreads();
  }

  #pragma unroll
  for (int i = 0; i < 4; ++i){
    #pragma unroll
    for (int r = 0; r < 4; ++r){
      const int cm = m0 + wm + i * 16 + quad * 4 + r;
      #pragma unroll
      for (int j = 0; j < 4; ++j){
        const int cn = n0 + wn + j * 16 + fr;
        const float a = acca[i][j][r] + b1[cn];
        const float g = accg[i][j][r] + b1[cn + 2048];
        const float ge = g * 0.5f * (1.0f + erff(g * 0.70710678118654752f));
        act[(size_t)cm * 2048 + cn] = f2bf(a * ge);
      }
    }
  }
}

// ---------------------------------------------------------------------------
// Row softmax over 2048 bf16 logits, in place.
// ---------------------------------------------------------------------------
__global__ __launch_bounds__(256) void softmax_kernel(bfu* __restrict__ sc){
  __shared__ float red[4];
  const int tid = threadIdx.x;
  const int lane = tid & 63, wv = tid >> 6;
  bfu* rp = sc + (size_t)blockIdx.x * NCTX;
  float x[8];
  #pragma unroll
  for (int j = 0; j < 8; ++j) x[j] = bf2f(rp[tid + (j << 8)]);
  float mx = x[0];
  #pragma unroll
  for (int j = 1; j < 8; ++j) mx = fmaxf(mx, x[j]);
  for (int o = 32; o; o >>= 1) mx = fmaxf(mx, __shfl_xor(mx, o, 64));
  if (lane == 0) red[wv] = mx;
  __syncthreads();
  mx = fmaxf(fmaxf(red[0], red[1]), fmaxf(red[2], red[3]));
  float sum = 0.f;
  #pragma unroll
  for (int j = 0; j < 8; ++j){ x[j] = __expf(x[j] - mx); sum += x[j]; }
  for (int o = 32; o; o >>= 1) sum += __shfl_xor(sum, o, 64);
  __syncthreads();
  if (lane == 0) red[wv] = sum;
  __syncthreads();
  sum = red[0] + red[1] + red[2] + red[3];
  const float inv = 1.0f / sum;
  #pragma unroll
  for (int j = 0; j < 8; ++j) rp[tid + (j << 8)] = f2bf(x[j] * inv);
}

// ---------------------------------------------------------------------------
// LayerNorm rows of 512 fp32 -> bf16.
// ---------------------------------------------------------------------------
__global__ __launch_bounds__(256) void ln_kernel(const float* __restrict__ in,
                                                 const float* __restrict__ g,
                                                 const float* __restrict__ b,
                                                 bfu* __restrict__ out){
  const int tid = threadIdx.x, lane = tid & 63, wv = tid >> 6;
  const size_t row = (size_t)blockIdx.x * 4 + wv;
  const float* rp = in + row * DIMV;
  float x[8];
  #pragma unroll
  for (int j = 0; j < 8; ++j) x[j] = rp[lane + (j << 6)];
  float s = 0.f;
  #pragma unroll
  for (int j = 0; j < 8; ++j) s += x[j];
  for (int o = 32; o; o >>= 1) s += __shfl_xor(s, o, 64);
  const float m = s * (1.0f / 512.0f);
  float s2 = 0.f;
  #pragma unroll
  for (int j = 0; j < 8; ++j){ const float d = x[j] - m; s2 = fmaf(d, d, s2); }
  for (int o = 32; o; o >>= 1) s2 += __shfl_xor(s2, o, 64);
  const float inv = 1.0f / sqrtf(s2 * (1.0f / 512.0f) + 1e-5f);
  bfu* op = out + row * DIMV;
  #pragma unroll
  for (int j = 0; j < 8; ++j){
    const int c = lane + (j << 6);
    op[c] = f2bf((x[j] - m) * inv * g[c] + b[c]);
  }
}

// ---------------------------------------------------------------------------
// Workspace (peak 121,667,584 B < proven 125,861,888):
//   idx    @ 0          (32 KB)
//   emb_s  @ 32768      (25,165,824) \  act half (50,331,648) aliases
//   q_in   @ 25198592   (25,165,824) /  emb_s+q_in (both dead at MLP)
//          q_in -> attnout after q GEMM
//   c_grp  @ 50364416   (12,582,912) -> scores (GRP=6)
//   k_grp  @ 62947328   (12,582,912) -> vT
//   v_grp  @ 75530240   (12,582,912)
//   qbuf   @ 88113152   (25,165,824) -> lnx
//   wT     @ 113278976  (8,388,608): wqT|wkvT|woT|w1T|w2T
// ---------------------------------------------------------------------------
extern "C" void kernel_launch(void* const* d_in, const int* in_sizes, int n_in,
                              void* d_out, int out_size, void* d_ws, size_t ws_size,
                              hipStream_t stream)
{
  (void)in_sizes; (void)n_in; (void)out_size;
  if (ws_size < 121667584ull) return;

  const float* pc    = (const float*)d_in[0];
  const float* pc2   = (const float*)d_in[1];
  const float* basis = (const float*)d_in[2];
  const float* pe_w  = (const float*)d_in[3];
  const float* pe_b  = (const float*)d_in[4];
  const float* lnq_g = (const float*)d_in[5];
  const float* lnq_b = (const float*)d_in[6];
  const float* lnc_g = (const float*)d_in[7];
  const float* lnc_b = (const float*)d_in[8];
  const float* wq    = (const float*)d_in[9];
  const float* wkv   = (const float*)d_in[10];
  const float* wo    = (const float*)d_in[11];
  const float* bo    = (const float*)d_in[12];
  const float* lnf_g = (const float*)d_in[13];
  const float* lnf_b = (const float*)d_in[14];
  const float* w1    = (const float*)d_in[15];
  const float* b1    = (const float*)d_in[16];
  const float* w2    = (const float*)d_in[17];
  const float* b2    = (const float*)d_in[18];
  float* xout = (float*)d_out;

  char* ws = (char*)d_ws;
  int* idxb   = (int*)(ws);
  bfu* emb_s  = (bfu*)(ws + 32768);
  bfu* q_in   = (bfu*)(ws + 25198592);
  bfu* c_grp  = (bfu*)(ws + 50364416);
  bfu* k_grp  = (bfu*)(ws + 62947328);
  bfu* v_grp  = (bfu*)(ws + 75530240);
  bfu* qbuf   = (bfu*)(ws + 88113152);
  bfu* wqT    = (bfu*)(ws + 113278976);
  bfu* wkvT   = (bfu*)(ws + 113803264);
  bfu* woT    = (bfu*)(ws + 114851840);
  bfu* w1T    = (bfu*)(ws + 115376128);
  bfu* w2T    = (bfu*)(ws + 119570432);
  bfu* scores  = c_grp;     // after c consumed by kv
  bfu* vT      = k_grp;     // after k consumed by scores
  bfu* attnout = q_in;      // after q GEMM consumed q_in
  bfu* lnx     = qbuf;      // after attention consumed q
  bfu* actb    = emb_s;     // spans emb_s+q_in (one MLP half at a time)

  // 0+1. fused: FPS || {weight transposes, group-0 context embed}
  fused_pre<<<FUSED_BLKS, 256, 0, stream>>>(
      pc, pc2, idxb, basis, pe_w, pe_b, lnc_g, lnc_b, c_grp,
      wq, wkv, wo, w1, w2, wqT, wkvT, woT, w1T, w2T);

  // 2. latent embed -> emb_s (raw) + q_in (LN'd)   [needs idxb]
  embed_kernel<true, true><<<MROWS/16, 256, 0, stream>>>(
      pc, pc2, idxb, basis, pe_w, pe_b, lnq_g, lnq_b, emb_s, q_in, NLAT);

  // 3. q = q_in @ wq
  gemm_mfma<4, 64, bfu, float, EPI_NONE><<<dim3(4, 192, 1), 256, 0, stream>>>(
      q_in, wqT, qbuf, nullptr, nullptr, nullptr, 1.0f,
      512, 512, 512, 512, 512, 0, 0, 0);

  // 4. per-group context pipeline (GRP=6, 8 groups; g0 embed done in fused_pre)
  for (int g = 0; g < NGRP; ++g){
    const int bt0 = g * GRP;
    if (g > 0){
      embed_kernel<false, false><<<GROWS/16, 256, 0, stream>>>(
          pc + (size_t)bt0 * NCTX * 3, pc2 + (size_t)bt0 * NCTX * 3, nullptr,
          basis, pe_w, pe_b, lnc_g, lnc_b, nullptr, c_grp, NCTX);
    }

    // kv = c @ wkv -> split k | v
    gemm_mfma<4, 64, bfu, float, EPI_SPLIT><<<dim3(8, 96, 1), 256, 0, stream>>>(
        c_grp, wkvT, k_grp, v_grp, nullptr, nullptr, 1.0f,
        1024, 512, 512, 512, 512, 0, 0, 0);

    // scores = (q @ k^T) * scale (overwrites c_grp region)
    gemm_mfma<4, 64, bfu, float, EPI_SCALE><<<dim3(16, 4, GRP), 256, 0, stream>>>(
        qbuf + (size_t)bt0 * 262144, k_grp, scores, nullptr, nullptr, nullptr,
        0.044194173824159216f,
        2048, 512, 512, 512, 2048, 262144, 1048576, 1048576);

    softmax_kernel<<<GRP * 512, 256, 0, stream>>>(scores);

    // vT = transpose(v) per bt (overwrites k_grp; k dead after scores)
    transp_kernel<bfu><<<dim3(16, 64, GRP), 256, 0, stream>>>(
        v_grp, vT, 2048, 512, 2048*512, 2048*512);

    // attnout = P @ V : 64x64 tiles, KSTEP=128
    gemm_mfma<2, 128, bfu, float, EPI_NONE><<<dim3(8, 8, GRP), 256, 0, stream>>>(
        scores, vT, attnout + (size_t)bt0 * 262144, nullptr, nullptr, nullptr, 1.0f,
        512, 2048, 2048, 2048, 512, 1048576, 1048576, 262144);
  }

  // 5. x = attnout @ wo + bo + emb_s -> d_out (fp32)
  gemm_mfma<4, 64, float, bfu, EPI_BIAS_RES><<<dim3(4, 192, 1), 256, 0, stream>>>(
      attnout, woT, xout, nullptr, bo, emb_s, 1.0f,
      512, 512, 512, 512, 512, 0, 0, 0);

  // 6. lnx = LN(x)
  ln_kernel<<<MROWS/4, 256, 0, stream>>>(xout, lnf_g, lnf_b, lnx);

  // 7/8. MLP in two row-halves (act buffer holds one half)
  for (int h = 0; h < 2; ++h){
    const size_t ro = (size_t)h * 12288;
    mlp1_mfma<<<dim3(16, 96, 1), 256, 0, stream>>>(
        lnx + ro * 512, w1T, b1, actb);
    gemm_mfma<4, 64, float, float, EPI_BIAS_RES><<<dim3(4, 96, 1), 256, 0, stream>>>(
        actb, w2T, xout + ro * 512, nullptr, b2, xout + ro * 512, 1.0f,
        512, 2048, 2048, 2048, 512, 0, 0, 0);
  }
}

// Round 10
// 1527.374 us; speedup vs baseline: 1.4778x; 1.1148x over previous
//
#include <hip/hip_runtime.h>

// Problem constants
#define NB    16
#define NT    3
#define NCTX  2048
#define NLAT  512
#define DIMV  512
#define HALFD 256
#define NFEAT 51
#define NBT   48
#define MROWS 24576    // NBT*NLAT
#define GRP   6        // bt per context group
#define NGRP  8
#define GROWS 12288    // GRP*NCTX
#define FUSED_BLKS (NB + GROWS/16 + 4096)   // fps + g0 embed + 5 transposes

typedef unsigned short bfu;   // bf16 storage as raw bits
typedef short bf16x8 __attribute__((ext_vector_type(8)));   // 8 bf16 = 4 VGPR
typedef float f32x4  __attribute__((ext_vector_type(4)));   // MFMA 16x16 acc
typedef float f32x2  __attribute__((ext_vector_type(2)));   // packed fp32 pair

__device__ __forceinline__ float bf2f(bfu u){ return __uint_as_float(((unsigned int)u) << 16); }
__device__ __forceinline__ bfu f2bf(float f){
  unsigned int u = __float_as_uint(f);
  u += 0x7FFFu + ((u >> 16) & 1u);          // RNE
  return (bfu)(u >> 16);
}
__device__ __forceinline__ float loadE(const float* p){ return *p; }
__device__ __forceinline__ float loadE(const bfu* p){ return bf2f(*p); }
__device__ __forceinline__ void storeE(float* p, float v){ *p = v; }
__device__ __forceinline__ void storeE(bfu* p, float v){ *p = f2bf(v); }
__device__ __forceinline__ bfu to_bfu(float f){ return f2bf(f); }
__device__ __forceinline__ bfu to_bfu(bfu u){ return u; }

// Async 16B global->LDS DMA. LDS dest = wave-uniform base + lane*16 (linear!)
// so swizzled layouts are achieved by pre-swizzling the per-lane GLOBAL
// source address (m173 pattern), never the LDS dest.
#define GLD16(gp, lp) __builtin_amdgcn_global_load_lds(                       \
    (const __attribute__((address_space(1))) unsigned int*)(gp),              \
    (__attribute__((address_space(3))) unsigned int*)(lp), 16, 0, 0)

// XOR chunk swizzle key for a [*][KSTEP] bf16 LDS tile (16B chunks).
template<int KSTEP>
__device__ __forceinline__ int swzr(int r){
  constexpr int CPR = KSTEP / 8;
  return (KSTEP == 32) ? ((r >> 1) & 3) : (r & (CPR - 1));
}

// ---------------------------------------------------------------------------
// FPS core: FOUR waves per batch (R9: halves per-wave issue count vs 2-wave;
// issue is parallel across SIMDs while the serial chain grows by only one
// merge compare). 512 pts/wave register-resident (24 VGPR coords + 8 d2).
// Per step: pts[last] broadcast -> packed VALU dist update -> in-lane tree
// (8 slots) -> 6-stage DPP wave argmax -> lane-63 8B record, ONE barrier
// (parity dbuf), 32B merge read, sequential strict-> select.
// Tie-breaks preserve numpy first-max exactly: index-ordered in-lane merges,
// DPP carries global idx (tie -> lower), wave ranges ascending so strict >
// keeps the lowest index. Distance expression, fminf, 1e10f identical to
// the proven bit-exact version (contract(off) at the caller, as in R8/R9
// passing builds).
// ---------------------------------------------------------------------------
#define DPP_ARGMAX_STAGE(CTRL)                                                \
  {                                                                           \
    const int svb = __builtin_amdgcn_update_dpp(vb, vb, CTRL, 0xF, 0xF, false); \
    const int sib = __builtin_amdgcn_update_dpp(ib, ib, CTRL, 0xF, 0xF, false); \
    const float sv = __int_as_float(svb);                                     \
    const float cv = __int_as_float(vb);                                      \
    if (sv > cv || (sv == cv && sib < ib)){ vb = svb; ib = sib; }             \
  }

__device__ __forceinline__ void fps_body(int b, int tid, const float* __restrict__ pc,
                                         int* __restrict__ idx_out,
                                         float4* pts, int (*mbuf)[8]){
  const int lane = tid & 63, w = tid >> 6;
  const int wbase = w << 9;               // wave owns [512w, 512w+512)
  const float* src = pc + (size_t)b * (NT * NCTX * 3);

  // Slot s (0..7) = point p = wbase + (s<<6) + lane. Coords + running
  // min-dists all register-resident; pair j holds slots 2j (lo), 2j+1 (hi).
  f32x2 x2[4], y2[4], z2[4], d2[4];
  #pragma unroll
  for (int j = 0; j < 4; ++j){
    #pragma unroll
    for (int h = 0; h < 2; ++h){
      const int p = wbase + ((2 * j + h) << 6) + lane;
      const float xx = src[p * 3 + 0];
      const float yy = src[p * 3 + 1];
      const float zz = src[p * 3 + 2];
      x2[j][h] = xx; y2[j][h] = yy; z2[j][h] = zz;
      pts[p] = make_float4(xx, yy, zz, 0.f);
    }
    d2[j][0] = 1e10f; d2[j][1] = 1e10f;
  }
  if (tid == 0) idx_out[b * NLAT] = 0;
  __syncthreads();                        // pts table ready

  int last = 0;
  for (int step = 1; step < NLAT; ++step){
    const float4 lp = pts[last];          // uniform addr -> LDS broadcast

    // distance update: pure packed VALU, identical op order to the proven
    // bit-exact version.
    #pragma unroll
    for (int j = 0; j < 4; ++j){
      const f32x2 dx = x2[j] - lp.x;
      const f32x2 dy = y2[j] - lp.y;
      const f32x2 dz = z2[j] - lp.z;
      const f32x2 dd = (dx * dx + dy * dy) + dz * dz;
      f32x2 nd;
      nd[0] = fminf(d2[j][0], dd[0]);
      nd[1] = fminf(d2[j][1], dd[1]);
      d2[j] = nd;
    }

    // in-lane argmax over 8 slots, adjacent-pair tree (index-ordered
    // merges: strict > keeps the lowest index on ties).
    float av[4]; int as_[4];
    #pragma unroll
    for (int j = 0; j < 4; ++j){
      const float lo = d2[j][0], hi = d2[j][1];
      const bool t = hi > lo;
      av[j]  = t ? hi : lo;
      as_[j] = t ? 2 * j + 1 : 2 * j;
    }
    #pragma unroll
    for (int wdt = 2; wdt; wdt >>= 1){
      #pragma unroll
      for (int j = 0; j < wdt; ++j){
        const float lv = av[2 * j], rv = av[2 * j + 1];
        const int   li = as_[2 * j], ri = as_[2 * j + 1];
        const bool t = rv > lv;
        av[j]  = t ? rv : lv;
        as_[j] = t ? ri : li;
      }
    }

    // cross-lane argmax on (value, GLOBAL index); ties -> lower index
    int vb = __float_as_int(av[0]);
    int ib = wbase + (as_[0] << 6) + lane;
    DPP_ARGMAX_STAGE(0x111)   // row_shr:1
    DPP_ARGMAX_STAGE(0x112)   // row_shr:2
    DPP_ARGMAX_STAGE(0x114)   // row_shr:4
    DPP_ARGMAX_STAGE(0x118)   // row_shr:8
    DPP_ARGMAX_STAGE(0x142)   // row_bcast:15
    DPP_ARGMAX_STAGE(0x143)   // row_bcast:31

    // cross-wave merge: 8B record (lane 63), one barrier, 32B broadcast
    // read, sequential strict-> select (wave ranges ascending -> numpy
    // tie-break). Parity buffer -> no second barrier.
    const int par = step & 1;
    if (lane == 63){ mbuf[par][w * 2] = vb; mbuf[par][w * 2 + 1] = ib; }
    __syncthreads();
    const int4 q0 = *(const int4*)&mbuf[par][0];
    const int4 q1 = *(const int4*)&mbuf[par][4];
    float bv = __int_as_float(q0.x); int bi = q0.y;
    { const float v1 = __int_as_float(q0.z); if (v1 > bv){ bv = v1; bi = q0.w; } }
    { const float v2 = __int_as_float(q1.x); if (v2 > bv){ bv = v2; bi = q1.y; } }
    { const float v3 = __int_as_float(q1.z); if (v3 > bv){ bv = v3; bi = q1.w; } }
    last = bi;
    if (tid == 0) idx_out[b * NLAT + step] = last;
  }
}

// ---------------------------------------------------------------------------
// Embed body: gather + point_embed x2 + layernorm -> bf16. 16 points/block.
// Phase-1 trig parallelized over all 256 threads (bit-exact redistribution).
// ---------------------------------------------------------------------------
template<bool GATHER, bool WRITE_EMB>
__device__ __forceinline__ void embed_body(
    int bid, int tid,
    const float* __restrict__ pc, const float* __restrict__ pc2,
    const int* __restrict__ idx,
    const float* __restrict__ basis, const float* __restrict__ pe_w,
    const float* __restrict__ pe_b,
    const float* __restrict__ ln_g, const float* __restrict__ ln_b,
    bfu* __restrict__ emb, bfu* __restrict__ lnout, int nppbt,
    float (*feat)[16][NFEAT + 1], float (*outb)[DIMV])
{
  const int p0 = bid << 4;

  if (tid < 32){
    const int s = tid >> 4, p = tid & 15;
    const int gp = p0 + p;
    const int bt = gp / nppbt;
    const int n  = gp - bt * nppbt;
    const int bb = bt / NT;
    const int srcn = GATHER ? idx[bb * NLAT + n] : n;
    const float* sp = (s ? pc2 : pc) + ((size_t)bt * NCTX + srcn) * 3;
    feat[s][p][48] = sp[0]; feat[s][p][49] = sp[1]; feat[s][p][50] = sp[2];
  }
  __syncthreads();

  #pragma unroll
  for (int t = 0; t < 3; ++t){
    const int wk  = tid * 3 + t;          // [0,768): (s*16+p)*24 + e
    const int spq = wk / 24;
    const int e   = wk - spq * 24;
    const int s = spq >> 4, p = spq & 15;
    const float x0 = feat[s][p][48], x1 = feat[s][p][49], x2 = feat[s][p][50];
    const float pr = __fadd_rn(__fadd_rn(__fmul_rn(x0, basis[e]),
                                         __fmul_rn(x1, basis[24 + e])),
                               __fmul_rn(x2, basis[48 + e]));
    feat[s][p][e]      = sinf(pr);
    feat[s][p][24 + e] = cosf(pr);
  }
  __syncthreads();

  {
    float w[NFEAT];
    #pragma unroll
    for (int k = 0; k < NFEAT; ++k) w[k] = pe_w[k * HALFD + tid];
    const float bv = pe_b[tid];
    #pragma unroll
    for (int half = 0; half < 2; ++half){
      for (int p = 0; p < 16; ++p){
        float acc = bv;
        #pragma unroll
        for (int k = 0; k < NFEAT; ++k) acc = fmaf(feat[half][p][k], w[k], acc);
        outb[p][half * HALFD + tid] = acc;
      }
    }
  }
  __syncthreads();

  const int lane = tid & 63, wv = tid >> 6;
  for (int pp = 0; pp < 4; ++pp){
    const int p = (wv << 2) + pp;
    const size_t gp = (size_t)p0 + p;
    float x[8];
    #pragma unroll
    for (int j = 0; j < 8; ++j) x[j] = outb[p][lane + (j << 6)];
    float s = 0.f;
    #pragma unroll
    for (int j = 0; j < 8; ++j) s += x[j];
    for (int o = 32; o; o >>= 1) s += __shfl_xor(s, o, 64);
    const float m = s * (1.0f / 512.0f);
    float s2 = 0.f;
    #pragma unroll
    for (int j = 0; j < 8; ++j){ const float d = x[j] - m; s2 = fmaf(d, d, s2); }
    for (int o = 32; o; o >>= 1) s2 += __shfl_xor(s2, o, 64);
    const float inv = 1.0f / sqrtf(s2 * (1.0f / 512.0f) + 1e-5f);
    #pragma unroll
    for (int j = 0; j < 8; ++j){
      const int c = lane + (j << 6);
      const float r = (x[j] - m) * inv * ln_g[c] + ln_b[c];
      const size_t o2 = gp * DIMV + c;
      if (WRITE_EMB) emb[o2] = f2bf(x[j]);
      lnout[o2] = f2bf(r);
    }
  }
}

template<bool GATHER, bool WRITE_EMB>
__global__ __launch_bounds__(256) void embed_kernel(
    const float* __restrict__ pc, const float* __restrict__ pc2,
    const int* __restrict__ idx,
    const float* __restrict__ basis, const float* __restrict__ pe_w,
    const float* __restrict__ pe_b,
    const float* __restrict__ ln_g, const float* __restrict__ ln_b,
    bfu* __restrict__ emb, bfu* __restrict__ lnout, int nppbt)
{
  __shared__ float feat[2][16][NFEAT + 1];
  __shared__ float outb[16][DIMV];
  embed_body<GATHER, WRITE_EMB>(blockIdx.x, threadIdx.x, pc, pc2, idx, basis,
      pe_w, pe_b, ln_g, ln_b, emb, lnout, nppbt, feat, outb);
}

// ---------------------------------------------------------------------------
// Transpose body (weights only now): in [R][C] fp32 -> out bf16 [C][R].
// ---------------------------------------------------------------------------
template<typename TIN>
__device__ __forceinline__ void transp_body(
    const TIN* __restrict__ in, bfu* __restrict__ out, int R, int C,
    int bx, int by, bfu (*t)[33])
{
  const int c0 = bx * 32, r0 = by * 32;
  const int tx = threadIdx.x & 31, ty = threadIdx.x >> 5;
  #pragma unroll
  for (int rr = ty; rr < 32; rr += 8)
    t[rr][tx] = to_bfu(in[(size_t)(r0 + rr) * C + c0 + tx]);
  __syncthreads();
  #pragma unroll
  for (int rr = ty; rr < 32; rr += 8)
    out[(size_t)(c0 + rr) * R + r0 + tx] = t[tx][rr];
}

// ---------------------------------------------------------------------------
// fused_pre: one launch hiding FPS-independent work under FPS's shadow.
// Blocks [0,16): FPS (all 4 waves participate). [16,784): context embed
// group 0 -> c_grp. [784,4880): the 5 weight transposes.
// ---------------------------------------------------------------------------
__global__ __attribute__((amdgpu_waves_per_eu(1, 1)))
__launch_bounds__(256) void fused_pre(
    const float* __restrict__ pc, const float* __restrict__ pc2,
    int* __restrict__ idx_out,
    const float* __restrict__ basis, const float* __restrict__ pe_w,
    const float* __restrict__ pe_b,
    const float* __restrict__ lnc_g, const float* __restrict__ lnc_b,
    bfu* __restrict__ c_grp,
    const float* __restrict__ wq, const float* __restrict__ wkv,
    const float* __restrict__ wo, const float* __restrict__ w1,
    const float* __restrict__ w2,
    bfu* __restrict__ wqT, bfu* __restrict__ wkvT, bfu* __restrict__ woT,
    bfu* __restrict__ w1T, bfu* __restrict__ w2T)
{
  __shared__ __align__(16) char smem[39424];  // max(fps 32832, embed 39424, transp 2112)
  const int bid = blockIdx.x, tid = threadIdx.x;

  if (bid < NB){
    #pragma clang fp contract(off)
    float4* pts = (float4*)smem;
    int (*mbuf)[8] = (int(*)[8])(smem + 32768);
    fps_body(bid, tid, pc, idx_out, pts, mbuf);
    return;
  }
  const int rb = bid - NB;
  if (rb < GROWS / 16){
    embed_body<false, false>(rb, tid, pc, pc2, nullptr, basis, pe_w, pe_b,
                             lnc_g, lnc_b, nullptr, c_grp, NCTX,
                             (float(*)[16][NFEAT + 1])smem,
                             (float(*)[DIMV])(smem + 6656));
    return;
  }
  int tb = rb - GROWS / 16;
  bfu (*tile)[33] = (bfu(*)[33])smem;
  if (tb < 256){ transp_body<float>(wq,  wqT,  512,  512, tb & 15,  tb >> 4, tile); return; }
  tb -= 256;
  if (tb < 512){ transp_body<float>(wkv, wkvT, 512, 1024, tb & 31,  tb >> 5, tile); return; }
  tb -= 512;
  if (tb < 256){ transp_body<float>(wo,  woT,  512,  512, tb & 15,  tb >> 4, tile); return; }
  tb -= 256;
  if (tb < 2048){ transp_body<float>(w1, w1T,  512, 4096, tb & 127, tb >> 7, tile); return; }
  tb -= 2048;
  transp_body<float>(w2, w2T, 2048, 512, tb & 15, tb >> 4, tile);
}

// ---------------------------------------------------------------------------
// MFMA GEMM: C[M][N] = A[M][K] * B[N][K]^T, bf16 inputs.
// Tile = (FH*32)^2: FH=4 -> 128x128, FH=2 -> 64x64. 4 waves 2x2.
// global_load_lds width=16 staging (R6) + KSTEP-deep barrier amortization
// (R7). LDS linear [BT][KSTEP]; 2-way-max bank conflicts via XOR chunk
// swizzle (inverse on per-lane GLOBAL source + same XOR on ds_read).
// ---------------------------------------------------------------------------
#define EPI_NONE     0
#define EPI_SPLIT    1
#define EPI_SCALE    2
#define EPI_BIAS_RES 3

template<int FH, int KSTEP, typename TC, typename TR, int EPI>
__global__ __launch_bounds__(256, 2) void gemm_mfma(
    const bfu* __restrict__ A, const bfu* __restrict__ B,
    TC* __restrict__ C, TC* __restrict__ C2,
    const float* __restrict__ bias, const TR* __restrict__ res,
    float scale, int N, int K, int lda, int ldb, int ldc,
    long long sA, long long sB, long long sC)
{
  constexpr int BT  = FH * 32;             // block tile edge
  constexpr int CPR = KSTEP / 8;           // 16B chunks per row
  constexpr int NI  = (BT * CPR) / 256;    // chunk issues per wave per matrix
  const int bz = blockIdx.z;
  A += (size_t)bz * sA;
  B += (size_t)bz * sB;
  const size_t coff = (size_t)bz * sC;

  __shared__ __align__(16) short As[BT * KSTEP];
  __shared__ __align__(16) short Bs[BT * KSTEP];

  const int tid = threadIdx.x;
  const int lane = tid & 63, w = tid >> 6;
  const int wl = (w << 6) + lane;
  const int m0 = blockIdx.y * BT, n0 = blockIdx.x * BT;
  const int wm = (w & 1) * (FH * 16), wn = (w >> 1) * (FH * 16);
  const int fr = lane & 15, quad = lane >> 4;

  f32x4 acc[FH][FH];
  #pragma unroll
  for (int i = 0; i < FH; ++i)
    #pragma unroll
    for (int j = 0; j < FH; ++j)
      #pragma unroll
      for (int r = 0; r < 4; ++r) acc[i][j][r] = 0.f;

  for (int k0 = 0; k0 < K; k0 += KSTEP){
    #pragma unroll
    for (int i = 0; i < NI; ++i){
      const int ch = i * 256 + wl;         // stored chunk: row r, slot cs
      const int r  = ch / CPR, cs = ch & (CPR - 1);
      const int cg = cs ^ swzr<KSTEP>(r);  // global chunk (inverse swizzle)
      short* la = (short*)As + ((i * 256 + (w << 6)) << 3); // wave-uniform
      short* lb = (short*)Bs + ((i * 256 + (w << 6)) << 3);
      GLD16(A + (size_t)(m0 + r) * lda + k0 + cg * 8, la);
      GLD16(B + (size_t)(n0 + r) * ldb + k0 + cg * 8, lb);
    }
    __syncthreads();
    #pragma unroll
    for (int kk = 0; kk < KSTEP / 32; ++kk){
      bf16x8 af[FH], bf[FH];
      #pragma unroll
      for (int i = 0; i < FH; ++i){
        const int row = wm + i * 16 + fr;
        const int cl = (kk * 4 + quad) ^ swzr<KSTEP>(row);
        af[i] = *(const bf16x8*)&As[row * KSTEP + (cl << 3)];
      }
      #pragma unroll
      for (int j = 0; j < FH; ++j){
        const int row = wn + j * 16 + fr;
        const int cl = (kk * 4 + quad) ^ swzr<KSTEP>(row);
        bf[j] = *(const bf16x8*)&Bs[row * KSTEP + (cl << 3)];
      }
      #pragma unroll
      for (int i = 0; i < FH; ++i)
        #pragma unroll
        for (int j = 0; j < FH; ++j)
          acc[i][j] = __builtin_amdgcn_mfma_f32_16x16x32_bf16(af[i], bf[j], acc[i][j], 0, 0, 0);
    }
    __syncthreads();
  }

  // C/D layout: col = lane&15, row = quad*4 + reg
  TC* Cp = C + coff;
  #pragma unroll
  for (int i = 0; i < FH; ++i){
    #pragma unroll
    for (int r = 0; r < 4; ++r){
      const int cm = m0 + wm + i * 16 + quad * 4 + r;
      #pragma unroll
      for (int j = 0; j < FH; ++j){
        const int cn = n0 + wn + j * 16 + fr;
        float v = acc[i][j][r];
        if (EPI == EPI_SCALE)    v *= scale;
        if (EPI == EPI_BIAS_RES) v = v + bias[cn] + loadE(&res[coff + (size_t)cm * ldc + cn]);
        if (EPI == EPI_SPLIT){
          const int half = N >> 1;
          if (cn < half) storeE(&C [(size_t)cm * half + cn],          v);
          else           storeE(&C2[(size_t)cm * half + (cn - half)], v);
        } else {
          storeE(&Cp[(size_t)cm * ldc + cn], v);
        }
      }
    }
  }
}

// ---------------------------------------------------------------------------
// Fused MLP1 + exact GeLU (MFMA): act = (A@w1T[a]+b1a) * gelu(A@w1T[g]+b1g).
// Same global_load_lds + XOR-swizzle staging, KSTEP=64.
// ---------------------------------------------------------------------------
__global__ __launch_bounds__(256, 1) void mlp1_mfma(
    const bfu* __restrict__ A, const bfu* __restrict__ B,  // B = w1T [4096][512]
    const float* __restrict__ b1, bfu* __restrict__ act)
{
  constexpr int KSTEP = 64, CPR = 8, NI = 4;
  __shared__ __align__(16) short As[128 * KSTEP];
  __shared__ __align__(16) short Ba[128 * KSTEP];
  __shared__ __align__(16) short Bg[128 * KSTEP];

  const int tid = threadIdx.x;
  const int lane = tid & 63, w = tid >> 6;
  const int wl = (w << 6) + lane;
  const int m0 = blockIdx.y * 128, n0 = blockIdx.x * 128;
  const int wm = (w & 1) * 64, wn = (w >> 1) * 64;
  const int fr = lane & 15, quad = lane >> 4;

  f32x4 acca[4][4], accg[4][4];
  #pragma unroll
  for (int i = 0; i < 4; ++i)
    #pragma unroll
    for (int j = 0; j < 4; ++j)
      #pragma unroll
      for (int r = 0; r < 4; ++r){ acca[i][j][r] = 0.f; accg[i][j][r] = 0.f; }

  for (int k0 = 0; k0 < 512; k0 += KSTEP){
    #pragma unroll
    for (int i = 0; i < NI; ++i){
      const int ch = i * 256 + wl;
      const int r  = ch / CPR, cs = ch & (CPR - 1);
      const int cg = cs ^ swzr<KSTEP>(r);
      short* da = (short*)As + ((i * 256 + (w << 6)) << 3);
      short* db = (short*)Ba + ((i * 256 + (w << 6)) << 3);
      short* dg = (short*)Bg + ((i * 256 + (w << 6)) << 3);
      GLD16(A + (size_t)(m0 + r) * 512 + k0 + cg * 8, da);
      GLD16(B + (size_t)(n0 + r) * 512 + k0 + cg * 8, db);
      GLD16(B + (size_t)(n0 + 2048 + r) * 512 + k0 + cg * 8, dg);
    }
    __syncthreads();
    #pragma unroll
    for (int kk = 0; kk < KSTEP / 32; ++kk){
      bf16x8 af[4], ba[4], bg[4];
      #pragma unroll
      for (int i = 0; i < 4; ++i){
        const int row = wm + i * 16 + fr;
        const int cl = (kk * 4 + quad) ^ swzr<KSTEP>(row);
        af[i] = *(const bf16x8*)&As[row * KSTEP + (cl << 3)];
      }
      #pragma unroll
      for (int j = 0; j < 4; ++j){
        const int row = wn + j * 16 + fr;
        const int cl = (kk * 4 + quad) ^ swzr<KSTEP>(row);
        ba[j] = *(const bf16x8*)&Ba[row * KSTEP + (cl << 3)];
        bg[j] = *(const bf16x8*)&Bg[row * KSTEP + (cl << 3)];
      }
      #pragma unroll
      for (int i = 0; i < 4; ++i)
        #pragma unroll
        for (int j = 0; j < 4; ++j){
          acca[i][j] = __builtin_amdgcn_mfma_f32_16x16x32_bf16(af[i], ba[j], acca[i][j], 0, 0, 0);
          accg[i][j] = __builtin_amdgcn_mfma_f32_16x16x32_bf16(af[i], bg[j], accg[i][j], 0, 0, 0);
        }
    }
    __syncthreads();
  }

  #pragma unroll
  for (int i = 0; i < 4; ++i){
    #pragma unroll
    for (int r = 0; r < 4; ++r){
      const int cm = m0 + wm + i * 16 + quad * 4 + r;
      #pragma unroll
      for (int j = 0; j < 4; ++j){
        const int cn = n0 + wn + j * 16 + fr;
        const float a = acca[i][j][r] + b1[cn];
        const float g = accg[i][j][r] + b1[cn + 2048];
        const float ge = g * 0.5f * (1.0f + erff(g * 0.70710678118654752f));
        act[(size_t)cm * 2048 + cn] = f2bf(a * ge);
      }
    }
  }
}

// ---------------------------------------------------------------------------
// Row softmax over 2048 bf16 logits, in place.
// ---------------------------------------------------------------------------
__global__ __launch_bounds__(256) void softmax_kernel(bfu* __restrict__ sc){
  __shared__ float red[4];
  const int tid = threadIdx.x;
  const int lane = tid & 63, wv = tid >> 6;
  bfu* rp = sc + (size_t)blockIdx.x * NCTX;
  float x[8];
  #pragma unroll
  for (int j = 0; j < 8; ++j) x[j] = bf2f(rp[tid + (j << 8)]);
  float mx = x[0];
  #pragma unroll
  for (int j = 1; j < 8; ++j) mx = fmaxf(mx, x[j]);
  for (int o = 32; o; o >>= 1) mx = fmaxf(mx, __shfl_xor(mx, o, 64));
  if (lane == 0) red[wv] = mx;
  __syncthreads();
  mx = fmaxf(fmaxf(red[0], red[1]), fmaxf(red[2], red[3]));
  float sum = 0.f;
  #pragma unroll
  for (int j = 0; j < 8; ++j){ x[j] = __expf(x[j] - mx); sum += x[j]; }
  for (int o = 32; o; o >>= 1) sum += __shfl_xor(sum, o, 64);
  __syncthreads();
  if (lane == 0) red[wv] = sum;
  __syncthreads();
  sum = red[0] + red[1] + red[2] + red[3];
  const float inv = 1.0f / sum;
  #pragma unroll
  for (int j = 0; j < 8; ++j) rp[tid + (j << 8)] = f2bf(x[j] * inv);
}

// ---------------------------------------------------------------------------
// LayerNorm rows of 512 fp32 -> bf16.
// ---------------------------------------------------------------------------
__global__ __launch_bounds__(256) void ln_kernel(const float* __restrict__ in,
                                                 const float* __restrict__ g,
                                                 const float* __restrict__ b,
                                                 bfu* __restrict__ out){
  const int tid = threadIdx.x, lane = tid & 63, wv = tid >> 6;
  const size_t row = (size_t)blockIdx.x * 4 + wv;
  const float* rp = in + row * DIMV;
  float x[8];
  #pragma unroll
  for (int j = 0; j < 8; ++j) x[j] = rp[lane + (j << 6)];
  float s = 0.f;
  #pragma unroll
  for (int j = 0; j < 8; ++j) s += x[j];
  for (int o = 32; o; o >>= 1) s += __shfl_xor(s, o, 64);
  const float m = s * (1.0f / 512.0f);
  float s2 = 0.f;
  #pragma unroll
  for (int j = 0; j < 8; ++j){ const float d = x[j] - m; s2 = fmaf(d, d, s2); }
  for (int o = 32; o; o >>= 1) s2 += __shfl_xor(s2, o, 64);
  const float inv = 1.0f / sqrtf(s2 * (1.0f / 512.0f) + 1e-5f);
  bfu* op = out + row * DIMV;
  #pragma unroll
  for (int j = 0; j < 8; ++j){
    const int c = lane + (j << 6);
    op[c] = f2bf((x[j] - m) * inv * g[c] + b[c]);
  }
}

// ---------------------------------------------------------------------------
// Workspace (peak 121,667,584 B < proven 125,861,888):
//   idx    @ 0          (32 KB)
//   emb_s  @ 32768      (25,165,824) \  act half (50,331,648) aliases
//   q_in   @ 25198592   (25,165,824) /  emb_s+q_in (both dead at MLP)
//          q_in -> attnout after q GEMM
//   c_grp  @ 50364416   (12,582,912) -> scores (GRP=6)
//   k_grp  @ 62947328   (12,582,912)
//   v_grp  @ 75530240   (12,582,912) = vT directly (R9: kv split, no transp)
//   qbuf   @ 88113152   (25,165,824) -> lnx
//   wT     @ 113278976  (8,388,608): wqT|wkvT|woT|w1T|w2T
// ---------------------------------------------------------------------------
extern "C" void kernel_launch(void* const* d_in, const int* in_sizes, int n_in,
                              void* d_out, int out_size, void* d_ws, size_t ws_size,
                              hipStream_t stream)
{
  (void)in_sizes; (void)n_in; (void)out_size;
  if (ws_size < 121667584ull) return;

  const float* pc    = (const float*)d_in[0];
  const float* pc2   = (const float*)d_in[1];
  const float* basis = (const float*)d_in[2];
  const float* pe_w  = (const float*)d_in[3];
  const float* pe_b  = (const float*)d_in[4];
  const float* lnq_g = (const float*)d_in[5];
  const float* lnq_b = (const float*)d_in[6];
  const float* lnc_g = (const float*)d_in[7];
  const float* lnc_b = (const float*)d_in[8];
  const float* wq    = (const float*)d_in[9];
  const float* wkv   = (const float*)d_in[10];
  const float* wo    = (const float*)d_in[11];
  const float* bo    = (const float*)d_in[12];
  const float* lnf_g = (const float*)d_in[13];
  const float* lnf_b = (const float*)d_in[14];
  const float* w1    = (const float*)d_in[15];
  const float* b1    = (const float*)d_in[16];
  const float* w2    = (const float*)d_in[17];
  const float* b2    = (const float*)d_in[18];
  float* xout = (float*)d_out;

  char* ws = (char*)d_ws;
  int* idxb   = (int*)(ws);
  bfu* emb_s  = (bfu*)(ws + 32768);
  bfu* q_in   = (bfu*)(ws + 25198592);
  bfu* c_grp  = (bfu*)(ws + 50364416);
  bfu* k_grp  = (bfu*)(ws + 62947328);
  bfu* v_grp  = (bfu*)(ws + 75530240);
  bfu* qbuf   = (bfu*)(ws + 88113152);
  bfu* wqT    = (bfu*)(ws + 113278976);
  bfu* wkvT   = (bfu*)(ws + 113803264);
  bfu* woT    = (bfu*)(ws + 114851840);
  bfu* w1T    = (bfu*)(ws + 115376128);
  bfu* w2T    = (bfu*)(ws + 119570432);
  bfu* scores  = c_grp;     // after c consumed by k/vT GEMMs
  bfu* vT      = v_grp;     // written transposed directly (R9)
  bfu* attnout = q_in;      // after q GEMM consumed q_in
  bfu* lnx     = qbuf;      // after attention consumed q
  bfu* actb    = emb_s;     // spans emb_s+q_in (one MLP half at a time)

  // 0+1. fused: FPS || {weight transposes, group-0 context embed}
  fused_pre<<<FUSED_BLKS, 256, 0, stream>>>(
      pc, pc2, idxb, basis, pe_w, pe_b, lnc_g, lnc_b, c_grp,
      wq, wkv, wo, w1, w2, wqT, wkvT, woT, w1T, w2T);

  // 2. latent embed -> emb_s (raw) + q_in (LN'd)   [needs idxb]
  embed_kernel<true, true><<<MROWS/16, 256, 0, stream>>>(
      pc, pc2, idxb, basis, pe_w, pe_b, lnq_g, lnq_b, emb_s, q_in, NLAT);

  // 3. q = q_in @ wq
  gemm_mfma<4, 64, bfu, float, EPI_NONE><<<dim3(4, 192, 1), 256, 0, stream>>>(
      q_in, wqT, qbuf, nullptr, nullptr, nullptr, 1.0f,
      512, 512, 512, 512, 512, 0, 0, 0);

  // 4. per-group context pipeline (GRP=6, 8 groups; g0 embed done in fused_pre)
  for (int g = 0; g < NGRP; ++g){
    const int bt0 = g * GRP;
    if (g > 0){
      embed_kernel<false, false><<<GROWS/16, 256, 0, stream>>>(
          pc + (size_t)bt0 * NCTX * 3, pc2 + (size_t)bt0 * NCTX * 3, nullptr,
          basis, pe_w, pe_b, lnc_g, lnc_b, nullptr, c_grp, NCTX);
    }

    // k = c @ wkT  (wkvT rows 0..511)
    gemm_mfma<4, 64, bfu, float, EPI_NONE><<<dim3(4, 96, 1), 256, 0, stream>>>(
        c_grp, wkvT, k_grp, nullptr, nullptr, nullptr, 1.0f,
        512, 512, 512, 512, 512, 0, 0, 0);

    // vT = wvT @ cT  (A = wkvT rows 512..1023, B = c_grp per bt)
    // -> v_grp holds vT[bt][feat][ctx], coalesced writes, no transpose pass.
    // Bit-exact vs old v: same products, same MFMA reduction order.
    gemm_mfma<4, 64, bfu, float, EPI_NONE><<<dim3(16, 4, GRP), 256, 0, stream>>>(
        wkvT + 512 * 512, c_grp, v_grp, nullptr, nullptr, nullptr, 1.0f,
        2048, 512, 512, 512, 2048, 0, 1048576, 1048576);

    // scores = (q @ k^T) * scale (overwrites c_grp region)
    gemm_mfma<4, 64, bfu, float, EPI_SCALE><<<dim3(16, 4, GRP), 256, 0, stream>>>(
        qbuf + (size_t)bt0 * 262144, k_grp, scores, nullptr, nullptr, nullptr,
        0.044194173824159216f,
        2048, 512, 512, 512, 2048, 262144, 1048576, 1048576);

    softmax_kernel<<<GRP * 512, 256, 0, stream>>>(scores);

    // attnout = P @ V : 64x64 tiles, KSTEP=128
    gemm_mfma<2, 128, bfu, float, EPI_NONE><<<dim3(8, 8, GRP), 256, 0, stream>>>(
        scores, vT, attnout + (size_t)bt0 * 262144, nullptr, nullptr, nullptr, 1.0f,
        512, 2048, 2048, 2048, 512, 1048576, 1048576, 262144);
  }

  // 5. x = attnout @ wo + bo + emb_s -> d_out (fp32)
  gemm_mfma<4, 64, float, bfu, EPI_BIAS_RES><<<dim3(4, 192, 1), 256, 0, stream>>>(
      attnout, woT, xout, nullptr, bo, emb_s, 1.0f,
      512, 512, 512, 512, 512, 0, 0, 0);

  // 6. lnx = LN(x)
  ln_kernel<<<MROWS/4, 256, 0, stream>>>(xout, lnf_g, lnf_b, lnx);

  // 7/8. MLP in two row-halves (act buffer holds one half)
  for (int h = 0; h < 2; ++h){
    const size_t ro = (size_t)h * 12288;
    mlp1_mfma<<<dim3(16, 96, 1), 256, 0, stream>>>(
        lnx + ro * 512, w1T, b1, actb);
    gemm_mfma<4, 64, float, float, EPI_BIAS_RES><<<dim3(4, 96, 1), 256, 0, stream>>>(
        actb, w2T, xout + ro * 512, nullptr, b2, xout + ro * 512, 1.0f,
        512, 2048, 2048, 2048, 512, 0, 0, 0);
  }
}